// Round 6
// baseline (181.204 us; speedup 1.0000x reference)
//
#include <hip/hip_runtime.h>
#include <math.h>

#define NB_B   2
#define NB_S   1024
#define NB_D   1024
#define NB_NH  8
#define NB_DQK 64
#define NB_DH  128
#define NCH    8
#define CL     128

typedef __attribute__((ext_vector_type(8))) short  short8v;   // 8 x bf16
typedef __attribute__((ext_vector_type(4))) float  f32x4;
typedef __attribute__((ext_vector_type(8))) unsigned short ushort8v;
typedef __attribute__((ext_vector_type(4))) unsigned short ushort4v;

__device__ __forceinline__ unsigned short f2bf(float f) {
  unsigned u = __float_as_uint(f);
  unsigned r = (u + 0x7FFFu + ((u >> 16) & 1u)) >> 16;
  return (unsigned short)r;
}
__device__ __forceinline__ float bf2f(unsigned short h) {
  return __uint_as_float(((unsigned)h) << 16);
}

#define GLD_LDS16(g, l) __builtin_amdgcn_global_load_lds( \
    (const __attribute__((address_space(1))) void*)(g),   \
    (__attribute__((address_space(3))) void*)(l), 16, 0, 0)

// ---------------- workspace offsets (floats) ----------------
constexpr size_t OFF_PQK = 0;                            // Pqk fp32 [2048][1024] = 2,097,152
constexpr size_t OFF_PVX = OFF_PQK + 2097152;            // Pvx fp32 [2048][2048] = 4,194,304
constexpr size_t OFF_XH  = OFF_PVX + 4194304;            // xh bf16 [2048][1024] -> 1,048,576 f
constexpr size_t OFF_XL  = OFF_XH  + 1048576;            // xl bf16 [2048][1024] -> 1,048,576 f
constexpr size_t OFF_WHI = OFF_XL  + 1048576;            // Whi bf16 [3072][1024] -> 1,572,864 f
constexpr size_t OFF_WLO = OFF_WHI + 1572864;            // Wlo bf16 [1024][1024] -> 524,288 f
constexpr size_t OFF_IV  = OFF_WLO + 524288;
constexpr size_t OFF_FV  = OFF_IV  + 16384;
constexpr size_t OFF_G   = OFF_FV  + 16384;
constexpr size_t OFF_GM  = OFF_G   + 16384;
// total 10,551,296 floats = 42.2 MB (same proven footprint)
// aliases (dead after gemm_proj):
constexpr size_t OFF_DL  = OFF_XH;                       // Dloc fp32 1,048,576
constexpr size_t OFF_HNG = OFF_XL;                       // hng bf16 [2048][1024] -> 1,048,576 f
constexpr size_t OFF_CB  = OFF_WHI;                      // Cbef fp32 1,048,576 (<= Whi region)
constexpr size_t OFF_WTO = OFF_WLO;                      // WtO bf16 [1024][1024]

// ---------------- fp32 -> (hi,lo) bf16 split ----------------
__global__ __launch_bounds__(256) void conv_split(
    const float* __restrict__ src,
    unsigned short* __restrict__ hi, unsigned short* __restrict__ lo, int n)
{
  int i = (blockIdx.x * 256 + threadIdx.x) * 8;
  if (i >= n) return;
  float4 a = *(const float4*)(src + i);
  float4 b = *(const float4*)(src + i + 4);
  float v[8] = { a.x, a.y, a.z, a.w, b.x, b.y, b.z, b.w };
  ushort8v rh, rl;
  #pragma unroll
  for (int j = 0; j < 8; ++j) {
    unsigned short h = f2bf(v[j]);
    rh[j] = h;
    rl[j] = f2bf(v[j] - bf2f(h));
  }
  *(ushort8v*)(hi + i) = rh;
  *(ushort8v*)(lo + i) = rl;
}

// ---------------- transpose + convert core ----------------
__device__ __forceinline__ void transp_body(
    const float* __restrict__ src,
    unsigned short* __restrict__ hi, unsigned short* __restrict__ lo,
    int N, int nt, int kt, int tid, float (*Ls)[65])
{
  #pragma unroll
  for (int p = 0; p < 16; ++p) {
    int lin = p * 256 + tid;
    int kr = lin >> 6, nc = lin & 63;
    Ls[kr][nc] = src[(size_t)(kt*64 + kr) * N + nt*64 + nc];
  }
  __syncthreads();
  #pragma unroll
  for (int p = 0; p < 16; ++p) {
    int lin = p * 256 + tid;
    int nr = lin >> 6, kc = lin & 63;
    float v = Ls[kc][nr];
    unsigned short h = f2bf(v);
    size_t di = (size_t)(nt*64 + nr) * 1024 + kt*64 + kc;
    hi[di] = h;
    if (lo) lo[di] = f2bf(v - bf2f(h));
  }
}

// merged transpose of Wq,Wk,Wv,Wog (grid.x = 8+8+16+16 = 48)
__global__ __launch_bounds__(256) void transp4(
    const float* __restrict__ Wq, const float* __restrict__ Wk,
    const float* __restrict__ Wv, const float* __restrict__ Wog,
    unsigned short* __restrict__ Whi, unsigned short* __restrict__ Wlo)
{
  __shared__ float Ls[64][65];
  const int x = blockIdx.x, kt = blockIdx.y, tid = threadIdx.x;
  if (x < 8)       transp_body(Wq,  Whi,              Wlo,            512,  x,      kt, tid, Ls);
  else if (x < 16) transp_body(Wk,  Whi +  512*1024,  Wlo + 512*1024, 512,  x - 8,  kt, tid, Ls);
  else if (x < 32) transp_body(Wv,  Whi + 1024*1024,  nullptr,        1024, x - 16, kt, tid, Ls);
  else             transp_body(Wog, Whi + 2048*1024,  nullptr,        1024, x - 32, kt, tid, Ls);
}

// single transpose (Wout, runs after gemm_proj frees Wlo space)
__global__ __launch_bounds__(256) void transp_hl(
    const float* __restrict__ src,
    unsigned short* __restrict__ hi, int N)
{
  __shared__ float Ls[64][65];
  transp_body(src, hi, nullptr, N, blockIdx.x, blockIdx.y, threadIdx.x, Ls);
}

// ---------------- fused projection GEMM, uniform 16-kt blocks ----------------
// grid.x = 40: ct 0..7  : xh*Whi  -> Pqk (atomic)
//              ct 8..23 : xh*Whi  -> Pvx (store)   [v: 8..15, xog: 16..23]
//              ct 24..31: xl*Whi  -> Pqk (atomic)
//              ct 32..39: xh*Wlo  -> Pqk (atomic)
__global__ __launch_bounds__(256) void gemm_proj(
    const unsigned short* __restrict__ xh,
    const unsigned short* __restrict__ xl,
    const unsigned short* __restrict__ Whi,
    const unsigned short* __restrict__ Wlo,
    float* __restrict__ Pqk, float* __restrict__ Pvx)
{
  __shared__ __align__(16) unsigned short As[128*64];
  __shared__ __align__(16) unsigned short Bs[128*64];
  const int tid  = threadIdx.x;
  const int ct   = blockIdx.x, bm = blockIdx.y;
  const int wid  = tid >> 6, lane = tid & 63;
  const int wm   = wid >> 1, wn = wid & 1;
  const int lrow = lane & 15;
  const int lk   = (lane >> 4) * 16;

  const unsigned short* Ap; const unsigned short* Bp;
  float* Cp; int ldc, colb; bool atom;
  if (ct < 8)       { Ap=xh; Bp=Whi + (size_t)ct*128*1024;      Cp=Pqk; ldc=1024; colb=ct*128;      atom=true;  }
  else if (ct < 24) { Ap=xh; Bp=Whi + (size_t)ct*128*1024;      Cp=Pvx; ldc=2048; colb=(ct-8)*128;  atom=false; }
  else if (ct < 32) { Ap=xl; Bp=Whi + (size_t)(ct-24)*128*1024; Cp=Pqk; ldc=1024; colb=(ct-24)*128; atom=true;  }
  else              { Ap=xh; Bp=Wlo + (size_t)(ct-32)*128*1024; Cp=Pqk; ldc=1024; colb=(ct-32)*128; atom=true;  }

  f32x4 acc[4][4];
  const f32x4 z4 = { 0.f, 0.f, 0.f, 0.f };
  #pragma unroll
  for (int m = 0; m < 4; ++m)
    #pragma unroll
    for (int n = 0; n < 4; ++n) acc[m][n] = z4;

  const int srow = tid >> 3;
  const int scb  = (tid & 7) << 4;
  size_t gAo[4], gBo[4];
  #pragma unroll
  for (int i = 0; i < 4; ++i) {
    int row = i * 32 + srow;
    int cbs = scb ^ ((row & 7) << 4);
    gAo[i] = (size_t)(bm*128 + row) * 2048 + cbs;
    gBo[i] = (size_t)row * 2048 + cbs;
  }
  const int ldsW = wid * 1024;
  const char* Ab = (const char*)Ap;
  const char* Bb = (const char*)Bp;

  for (int kt = 0; kt < 16; ++kt) {
    __syncthreads();
    #pragma unroll
    for (int i = 0; i < 4; ++i)
      GLD_LDS16(Ab + gAo[i] + kt*128, (char*)As + i*4096 + ldsW);
    #pragma unroll
    for (int i = 0; i < 4; ++i)
      GLD_LDS16(Bb + gBo[i] + kt*128, (char*)Bs + i*4096 + ldsW);
    __syncthreads();

    #pragma unroll
    for (int kk = 0; kk < 2; ++kk) {
      short8v a[4], b[4];
      #pragma unroll
      for (int m = 0; m < 4; ++m) {
        int row = wm*64 + m*16 + lrow;
        int kb  = (kk*64 + lk) ^ ((row & 7) << 4);
        a[m] = *(const short8v*)((const char*)As + row*128 + kb);
      }
      #pragma unroll
      for (int n = 0; n < 4; ++n) {
        int row = wn*64 + n*16 + lrow;
        int kb  = (kk*64 + lk) ^ ((row & 7) << 4);
        b[n] = *(const short8v*)((const char*)Bs + row*128 + kb);
      }
      #pragma unroll
      for (int m = 0; m < 4; ++m)
        #pragma unroll
        for (int n = 0; n < 4; ++n)
          acc[m][n] = __builtin_amdgcn_mfma_f32_16x16x32_bf16(a[m], b[n], acc[m][n], 0, 0, 0);
    }
  }

  const int crow0 = bm*128 + wm*64 + ((lane >> 4) << 2);
  const int ccol0 = colb + wn*64 + (lane & 15);
  if (atom) {
    #pragma unroll
    for (int m = 0; m < 4; ++m)
      #pragma unroll
      for (int n = 0; n < 4; ++n)
        #pragma unroll
        for (int r = 0; r < 4; ++r)
          unsafeAtomicAdd(&Cp[(size_t)(crow0 + m*16 + r) * ldc + ccol0 + n*16], acc[m][n][r]);
  } else {
    #pragma unroll
    for (int m = 0; m < 4; ++m)
      #pragma unroll
      for (int n = 0; n < 4; ++n)
        #pragma unroll
        for (int r = 0; r < 4; ++r)
          Cp[(size_t)(crow0 + m*16 + r) * ldc + ccol0 + n*16] = acc[m][n][r];
  }
}

// ---------------- output GEMM: 128x64 tiles ----------------
__global__ __launch_bounds__(256) void gemm_out64(
    const unsigned short* __restrict__ A,
    const unsigned short* __restrict__ Bt,
    float* __restrict__ C, int ldc)
{
  __shared__ __align__(16) unsigned short As[128*64];
  __shared__ __align__(16) unsigned short Bs[64*64];
  const int tid  = threadIdx.x;
  const int bm   = blockIdx.y, cn = blockIdx.x;
  const int wid  = tid >> 6, lane = tid & 63;
  const int wm   = wid >> 1, wn = wid & 1;
  const int lrow = lane & 15;
  const int lk   = (lane >> 4) * 16;

  f32x4 acc[4][2];
  const f32x4 z4 = { 0.f, 0.f, 0.f, 0.f };
  #pragma unroll
  for (int m = 0; m < 4; ++m)
    #pragma unroll
    for (int n = 0; n < 2; ++n) acc[m][n] = z4;

  const int srow = tid >> 3;
  const int scb  = (tid & 7) << 4;
  const char* Ab = (const char*)A;
  const char* Bb = (const char*)Bt;
  size_t gA[4], gB[2];
  #pragma unroll
  for (int i = 0; i < 4; ++i) {
    int row = i * 32 + srow;
    int cbs = scb ^ ((row & 7) << 4);
    gA[i] = (size_t)(bm*128 + row) * 2048 + cbs;
  }
  #pragma unroll
  for (int i = 0; i < 2; ++i) {
    int row = i * 32 + srow;
    int cbs = scb ^ ((row & 7) << 4);
    gB[i] = (size_t)(cn*64 + row) * 2048 + cbs;
  }
  const int ldsW = wid * 1024;

  for (int kt = 0; kt < 16; ++kt) {
    __syncthreads();
    #pragma unroll
    for (int i = 0; i < 4; ++i)
      GLD_LDS16(Ab + gA[i] + kt*128, (char*)As + i*4096 + ldsW);
    #pragma unroll
    for (int i = 0; i < 2; ++i)
      GLD_LDS16(Bb + gB[i] + kt*128, (char*)Bs + i*4096 + ldsW);
    __syncthreads();

    #pragma unroll
    for (int kk = 0; kk < 2; ++kk) {
      short8v a[4], b[2];
      #pragma unroll
      for (int m = 0; m < 4; ++m) {
        int row = wm*64 + m*16 + lrow;
        int kb  = (kk*64 + lk) ^ ((row & 7) << 4);
        a[m] = *(const short8v*)((const char*)As + row*128 + kb);
      }
      #pragma unroll
      for (int n = 0; n < 2; ++n) {
        int row = wn*32 + n*16 + lrow;
        int kb  = (kk*64 + lk) ^ ((row & 7) << 4);
        b[n] = *(const short8v*)((const char*)Bs + row*128 + kb);
      }
      #pragma unroll
      for (int m = 0; m < 4; ++m)
        #pragma unroll
        for (int n = 0; n < 2; ++n)
          acc[m][n] = __builtin_amdgcn_mfma_f32_16x16x32_bf16(a[m], b[n], acc[m][n], 0, 0, 0);
    }
  }

  const int crow0 = bm*128 + wm*64 + ((lane >> 4) << 2);
  const int ccol0 = cn*64 + wn*32 + (lane & 15);
  #pragma unroll
  for (int m = 0; m < 4; ++m)
    #pragma unroll
    for (int n = 0; n < 2; ++n)
      #pragma unroll
      for (int r = 0; r < 4; ++r)
        C[(size_t)(crow0 + m*16 + r) * ldc + ccol0 + n*16] = acc[m][n][r];
}

// ---------------- i/f projections (fp32, skinny N=8) ----------------
__global__ __launch_bounds__(64) void proj_if(
    const float* __restrict__ x,
    const float* __restrict__ Wi, const float* __restrict__ bi,
    const float* __restrict__ Wf, const float* __restrict__ bf,
    float* __restrict__ iv, float* __restrict__ fv)
{
  const int row = blockIdx.x, l = threadIdx.x;
  const float* xr = x + (size_t)row * NB_D;
  float ai[8] = {}, af[8] = {};
  for (int p = 0; p < 16; ++p) {
    int kk = l + p * 64;
    float xv = xr[kk];
    const float* wi = Wi + (size_t)kk * NB_NH;
    const float* wf = Wf + (size_t)kk * NB_NH;
    #pragma unroll
    for (int cc = 0; cc < 8; ++cc) { ai[cc] += xv*wi[cc]; af[cc] += xv*wf[cc]; }
  }
  #pragma unroll
  for (int off = 1; off < 64; off <<= 1) {
    #pragma unroll
    for (int cc = 0; cc < 8; ++cc) {
      ai[cc] += __shfl_xor(ai[cc], off);
      af[cc] += __shfl_xor(af[cc], off);
    }
  }
  if (l == 0) {
    int b = row >> 10, s = row & (NB_S - 1);
    #pragma unroll
    for (int cc = 0; cc < 8; ++cc) {
      iv[(size_t)(b*NB_NH + cc) * NB_S + s] = ai[cc] + bi[cc];
      fv[(size_t)(b*NB_NH + cc) * NB_S + s] = af[cc] + bf[cc];
    }
  }
}

// ---------------- gate scan ----------------
__global__ __launch_bounds__(64) void gate_scan(
    const float* __restrict__ iv, const float* __restrict__ fv,
    float* __restrict__ gv, float* __restrict__ Gv)
{
  const int bh = blockIdx.x, l = threadIdx.x;
  const int base = bh * NB_S + l * 16;
  float fl[16];
  float run = 0.f;
  #pragma unroll
  for (int u = 0; u < 16; ++u) {
    float fr = fv[base + u];
    float flog = (fr >= 0.f) ? -log1pf(expf(-fr)) : (fr - log1pf(expf(fr)));
    run += flog; fl[u] = run;
  }
  float tot = run, sc = tot;
  #pragma unroll
  for (int off = 1; off < 64; off <<= 1) {
    float t = __shfl_up(sc, off);
    if (l >= off) sc += t;
  }
  float excl = sc - tot;
  float gm[16]; float rmax = -1e30f;
  #pragma unroll
  for (int u = 0; u < 16; ++u) {
    float bt = excl + fl[u];
    float g = iv[base + u] - bt;
    gv[base + u] = g;
    rmax = fmaxf(rmax, g); gm[u] = rmax;
  }
  float mx = rmax;
  #pragma unroll
  for (int off = 1; off < 64; off <<= 1) {
    float t = __shfl_up(mx, off);
    if (l >= off) mx = fmaxf(mx, t);
  }
  float em = __shfl_up(mx, 1);
  if (l == 0) em = -1e30f;
  #pragma unroll
  for (int u = 0; u < 16; ++u)
    Gv[base + u] = fmaxf(0.f, fmaxf(em, gm[u]));
}

// ---------------- per-chunk local KV state ----------------
__global__ __launch_bounds__(128) void chunk_local(
    const float* __restrict__ Pqk, const float* __restrict__ Pvx,
    const float* __restrict__ gv, const float* __restrict__ Gv,
    float* __restrict__ Dloc)
{
  __shared__ float ks[16][68];
  __shared__ float vs[16][132];
  __shared__ float wsg[16];
  const int bx = blockIdx.x, bh = bx >> 3, c = bx & 7;
  const int b = bh >> 3, h = bh & 7;
  const int tid = threadIdx.x;
  const int rg = tid >> 3, cg = tid & 7;
  const int i0 = rg * 4;
  float acc[4][16] = {};
  const float Gend = Gv[bh*NB_S + c*CL + CL - 1];
  const float* kbp = Pqk + ((size_t)b*NB_S + c*CL) * 1024 + 512 + h*NB_DQK;
  const float* vbp = Pvx + ((size_t)b*NB_S + c*CL) * 2048 + h*NB_DH;
  const float* gbp = gv + bh*NB_S + c*CL;
  for (int sb = 0; sb < 8; ++sb) {
    __syncthreads();
    #pragma unroll
    for (int p = 0; p < 2; ++p) {
      int qd = tid + p*128; int r = qd >> 4, cq = qd & 15;
      *(float4*)(&ks[r][cq*4]) = *(const float4*)(kbp + (size_t)(sb*16 + r)*1024 + cq*4);
    }
    #pragma unroll
    for (int p = 0; p < 4; ++p) {
      int qd = tid + p*128; int r = qd >> 5, cq = qd & 31;
      *(float4*)(&vs[r][cq*4]) = *(const float4*)(vbp + (size_t)(sb*16 + r)*2048 + cq*4);
    }
    if (tid < 16) wsg[tid] = expf(gbp[sb*16 + tid] - Gend);
    __syncthreads();
    #pragma unroll
    for (int s = 0; s < 16; ++s) {
      float w = wsg[s];
      float4 kq = *(const float4*)(&ks[s][i0]);
      float wk[4] = { w*kq.x, w*kq.y, w*kq.z, w*kq.w };
      #pragma unroll
      for (int m = 0; m < 4; ++m) {
        float4 vq = *(const float4*)(&vs[s][cg*4 + m*32]);
        #pragma unroll
        for (int u = 0; u < 4; ++u) {
          acc[u][m*4+0] += wk[u]*vq.x;
          acc[u][m*4+1] += wk[u]*vq.y;
          acc[u][m*4+2] += wk[u]*vq.z;
          acc[u][m*4+3] += wk[u]*vq.w;
        }
      }
    }
  }
  float* dst = Dloc + ((size_t)bh*NCH + c) * (NB_DQK*NB_DH);
  #pragma unroll
  for (int u = 0; u < 4; ++u)
    #pragma unroll
    for (int m = 0; m < 4; ++m) {
      float4 o4 = { acc[u][m*4+0], acc[u][m*4+1], acc[u][m*4+2], acc[u][m*4+3] };
      *(float4*)(dst + (size_t)(i0+u)*NB_DH + cg*4 + m*32) = o4;
    }
}

// ---------------- sequential chunk-state combine ----------------
__global__ __launch_bounds__(256) void chunk_combine(
    const float* __restrict__ Dloc, const float* __restrict__ Gv,
    float* __restrict__ Cbef)
{
  const int bh = blockIdx.x, tid = threadIdx.x;
  float4 acc[8];
  #pragma unroll
  for (int p = 0; p < 8; ++p) acc[p] = float4{0.f,0.f,0.f,0.f};
  float Gprev = 0.f;
  for (int c = 0; c < NCH; ++c) {
    const float4* dl = (const float4*)(Dloc + ((size_t)bh*NCH + c)*8192);
    float4* cb = (float4*)(Cbef + ((size_t)bh*NCH + c)*8192);
    float Gend = Gv[bh*NB_S + c*CL + CL - 1];
    float decay = (c == 0) ? 0.f : expf(Gprev - Gend);
    #pragma unroll
    for (int p = 0; p < 8; ++p) {
      int idx = tid + p*256;
      cb[idx] = acc[p];
      float4 d = dl[idx];
      acc[p].x = acc[p].x*decay + d.x;
      acc[p].y = acc[p].y*decay + d.y;
      acc[p].z = acc[p].z*decay + d.z;
      acc[p].w = acc[p].w*decay + d.w;
    }
    Gprev = Gend;
  }
}

// ---------------- chunked attention + state + LN + gate -> hng (bf16) ----------------
// grid 256: bh(16) x c(8) x half(2); each block computes 64 t-rows of one chunk.
__global__ __launch_bounds__(256,1) void chunk_out(
    const float* __restrict__ Pqk, const float* __restrict__ Pvx,
    const float* __restrict__ gv, const float* __restrict__ Gv,
    const float* __restrict__ Cbef,
    const float* __restrict__ lnw, const float* __restrict__ lnb,
    unsigned short* __restrict__ hng)
{
  __shared__ float attT[128][132];
  __shared__ float buf[128][132];
  __shared__ float gsh[128], Gsh[128], rsh[128];

  const int bx = blockIdx.x;
  const int half = bx & 1, c = (bx >> 1) & 7, bh = bx >> 4;
  const int b = bh >> 3, h = bh & 7;
  const int tid = threadIdx.x;
  const int tr = tid >> 4, tc = tid & 15;
  const int t0 = half*64 + tr*4;
  const size_t rowbase = (size_t)b*NB_S + (size_t)c*CL;
  const int sgbase = bh*NB_S + c*CL;

  #pragma unroll
  for (int p = 0; p < 8; ++p) {
    int qd = tid + p*256;
    int t = qd >> 4, iq = qd & 15;
    float4 q4 = *(const float4*)(Pqk + (rowbase + t)*1024 + h*NB_DQK + iq*4);
    buf[iq*4+0][t]=q4.x; buf[iq*4+1][t]=q4.y; buf[iq*4+2][t]=q4.z; buf[iq*4+3][t]=q4.w;
    float4 k4 = *(const float4*)(Pqk + (rowbase + t)*1024 + 512 + h*NB_DQK + iq*4);
    buf[64+iq*4+0][t]=k4.x; buf[64+iq*4+1][t]=k4.y; buf[64+iq*4+2][t]=k4.z; buf[64+iq*4+3][t]=k4.w;
  }
  if (tid < 128) {
    float gval = gv[sgbase + tid];
    float Gval = Gv[sgbase + tid];
    gsh[tid] = gval; Gsh[tid] = Gval;
    float Gprev = (c > 0) ? Gv[sgbase - 1] : 0.f;
    rsh[tid] = 0.125f * expf(Gprev - Gval);
  }
  __syncthreads();

  auto mm = [&](float (&accR)[4][8], float (*Am)[132], int ar0,
                float (*Bm)[132], int br0, int nq) {
    for (int iq = 0; iq < nq; ++iq) {
      float a[4][4], bq[4][8];
      #pragma unroll
      for (int w = 0; w < 4; ++w) {
        const float* ap = Am[ar0 + iq*4 + w];
        *(float4*)(&a[w][0]) = *(const float4*)(ap + t0);
        const float* bp = Bm[br0 + iq*4 + w];
        *(float4*)(&bq[w][0]) = *(const float4*)(bp + tc*4);
        *(float4*)(&bq[w][4]) = *(const float4*)(bp + tc*4 + 64);
      }
      #pragma unroll
      for (int w = 0; w < 4; ++w)
        #pragma unroll
        for (int u = 0; u < 4; ++u)
          #pragma unroll
          for (int x = 0; x < 8; ++x)
            accR[u][x] += a[w][u]*bq[w][x];
    }
  };

  { // att = Q K^T, weight, mask, store transposed (all 128 s rows written)
    float accA[4][8] = {};
    mm(accA, buf, 0, buf, 64, 16);
    float gtv[4];
    #pragma unroll
    for (int u = 0; u < 4; ++u) gtv[u] = Gsh[t0 + u];
    #pragma unroll
    for (int x = 0; x < 8; ++x) {
      int s = tc*4 + (x>>2)*64 + (x&3);
      float gs = gsh[s];
      float vv[4];
      #pragma unroll
      for (int u = 0; u < 4; ++u) {
        int t = t0 + u;
        float w = 0.125f * expf(gs - gtv[u]);
        vv[u] = (s <= t) ? accA[u][x]*w : 0.f;
      }
      float4 lo = {vv[0],vv[1],vv[2],vv[3]};
      *(float4*)(&attT[s][t0]) = lo;
    }
  }
  __syncthreads();

  { // load Cbefore into buf rows 64..127
    const float* Cbp = Cbef + ((size_t)bh*NCH + c)*(NB_DQK*NB_DH);
    #pragma unroll
    for (int p = 0; p < 8; ++p) {
      int qd = tid + p*256;
      int i = qd >> 5, jq = qd & 31;
      *(float4*)(&buf[64+i][jq*4]) = *(const float4*)(Cbp + (size_t)i*NB_DH + jq*4);
    }
  }
  __syncthreads();
  float acc2[4][8] = {};
  mm(acc2, buf, 0, buf, 64, 16);
  __syncthreads();

  { // load V into buf
    #pragma unroll
    for (int p = 0; p < 16; ++p) {
      int qd = tid + p*256;
      int sv = qd >> 5, jq = qd & 31;
      *(float4*)(&buf[sv][jq*4]) =
        *(const float4*)(Pvx + (rowbase + sv)*2048 + h*NB_DH + jq*4);
    }
  }
  __syncthreads();
  float hacc[4][8] = {};
  mm(hacc, attT, 0, buf, 0, 32);

  float lw[8], lb[8];
  {
    float4 a0 = *(const float4*)(lnw + h*NB_DH + tc*4);
    float4 a1 = *(const float4*)(lnw + h*NB_DH + tc*4 + 64);
    lw[0]=a0.x; lw[1]=a0.y; lw[2]=a0.z; lw[3]=a0.w;
    lw[4]=a1.x; lw[5]=a1.y; lw[6]=a1.z; lw[7]=a1.w;
    float4 b0 = *(const float4*)(lnb + h*NB_DH + tc*4);
    float4 b1 = *(const float4*)(lnb + h*NB_DH + tc*4 + 64);
    lb[0]=b0.x; lb[1]=b0.y; lb[2]=b0.z; lb[3]=b0.w;
    lb[4]=b1.x; lb[5]=b1.y; lb[6]=b1.z; lb[7]=b1.w;
  }
  #pragma unroll
  for (int u = 0; u < 4; ++u) {
    int t = t0 + u;
    float r = rsh[t];
    float hrow[8];
    #pragma unroll
    for (int x = 0; x < 8; ++x) hrow[x] = hacc[u][x] + r*acc2[u][x];
    float sum = 0.f, ssq = 0.f;
    #pragma unroll
    for (int x = 0; x < 8; ++x) { sum += hrow[x]; ssq += hrow[x]*hrow[x]; }
    #pragma unroll
    for (int off = 1; off < 16; off <<= 1) {
      sum += __shfl_xor(sum, off);
      ssq += __shfl_xor(ssq, off);
    }
    float mean = sum * (1.f/NB_DH);
    float var  = ssq * (1.f/NB_DH) - mean*mean;
    float rstd = rsqrtf(var + 1e-6f);
    #pragma unroll
    for (int m = 0; m < 2; ++m) {
      float4 xo = *(const float4*)(Pvx + (rowbase + t)*2048 + 1024 + h*NB_DH + tc*4 + m*64);
      float xov[4] = {xo.x, xo.y, xo.z, xo.w};
      unsigned short res[4];
      #pragma unroll
      for (int w = 0; w < 4; ++w) {
        int x = m*4 + w;
        float hn = (hrow[x] - mean)*rstd*lw[x] + lb[x];
        float tt = tanhf(xov[w]*(1.f/15.f))*15.f;
        float o = 1.f/(1.f + expf(-tt));
        res[w] = f2bf(hn*o);
      }
      ushort4v r4 = {res[0],res[1],res[2],res[3]};
      *(ushort4v*)(hng + (rowbase + t)*1024 + h*NB_DH + tc*4 + m*64) = r4;
    }
  }
}

extern "C" void kernel_launch(void* const* d_in, const int* in_sizes, int n_in,
                              void* d_out, int out_size, void* d_ws, size_t ws_size,
                              hipStream_t stream)
{
  (void)in_sizes; (void)n_in; (void)out_size; (void)ws_size;
  const float* x   = (const float*)d_in[0];
  const float* Wq  = (const float*)d_in[1];
  const float* Wk  = (const float*)d_in[2];
  const float* Wv  = (const float*)d_in[3];
  const float* Wi  = (const float*)d_in[4];
  const float* bi  = (const float*)d_in[5];
  const float* Wf  = (const float*)d_in[6];
  const float* bf  = (const float*)d_in[7];
  const float* Wog = (const float*)d_in[8];
  const float* lnw = (const float*)d_in[9];
  const float* lnb = (const float*)d_in[10];
  const float* Wout= (const float*)d_in[11];
  float* out = (float*)d_out;
  float* ws  = (float*)d_ws;

  float*          Pqk = ws + OFF_PQK;
  float*          Pvx = ws + OFF_PVX;
  unsigned short* xh  = (unsigned short*)(ws + OFF_XH);
  unsigned short* xl  = (unsigned short*)(ws + OFF_XL);
  unsigned short* Whi = (unsigned short*)(ws + OFF_WHI);
  unsigned short* Wlo = (unsigned short*)(ws + OFF_WLO);
  unsigned short* WtO = (unsigned short*)(ws + OFF_WTO);   // alias of Wlo (after proj)
  float*          iv  = ws + OFF_IV;
  float*          fv  = ws + OFF_FV;
  float*          g   = ws + OFF_G;
  float*          G   = ws + OFF_GM;
  float*          Dl  = ws + OFF_DL;                        // alias of xh
  float*          Cb  = ws + OFF_CB;                        // alias of Whi
  unsigned short* hng = (unsigned short*)(ws + OFF_HNG);    // alias of xl

  // zero the atomic-accumulated q,k buffer (graph-capturable, replay-safe)
  hipMemsetAsync(Pqk, 0, 2048ull*1024*sizeof(float), stream);

  conv_split<<<1024, 256, 0, stream>>>(x, xh, xl, 2048*1024);
  transp4   <<<dim3(48,16), 256, 0, stream>>>(Wq, Wk, Wv, Wog, Whi, Wlo);

  proj_if  <<<2048, 64, 0, stream>>>(x, Wi, bi, Wf, bf, iv, fv);
  gate_scan<<<16, 64, 0, stream>>>(iv, fv, g, G);

  // uniform-cost fused projection (atomic split-bf16 accumulation for q,k)
  gemm_proj<<<dim3(40,16), 256, 0, stream>>>(xh, xl, Whi, Wlo, Pqk, Pvx);

  // Wout transpose reuses Wlo space (gemm_proj already consumed it)
  transp_hl<<<dim3(16,16), 256, 0, stream>>>(Wout, WtO, 1024);

  chunk_local  <<<128, 128, 0, stream>>>(Pqk, Pvx, g, G, Dl);
  chunk_combine<<<16, 256, 0, stream>>>(Dl, G, Cb);
  chunk_out    <<<256, 256, 0, stream>>>(Pqk, Pvx, g, G, Cb, lnw, lnb, hng);

  // out = hng[2048x1024] x Wout[1024x1024]
  gemm_out64<<<dim3(16,16), 256, 0, stream>>>(hng, WtO, out, 1024);
}

// Round 7
// 154.770 us; speedup vs baseline: 1.1708x; 1.1708x over previous
//
#include <hip/hip_runtime.h>
#include <math.h>

#define NB_B   2
#define NB_S   1024
#define NB_D   1024
#define NB_NH  8
#define NB_DQK 64
#define NB_DH  128
#define NCH    8
#define CL     128

typedef __attribute__((ext_vector_type(8))) short  short8v;   // 8 x bf16
typedef __attribute__((ext_vector_type(4))) float  f32x4;
typedef __attribute__((ext_vector_type(8))) unsigned short ushort8v;
typedef __attribute__((ext_vector_type(4))) unsigned short ushort4v;

__device__ __forceinline__ unsigned short f2bf(float f) {
  unsigned u = __float_as_uint(f);
  unsigned r = (u + 0x7FFFu + ((u >> 16) & 1u)) >> 16;
  return (unsigned short)r;
}
__device__ __forceinline__ float bf2f(unsigned short h) {
  return __uint_as_float(((unsigned)h) << 16);
}

#define GLD_LDS16(g, l) __builtin_amdgcn_global_load_lds( \
    (const __attribute__((address_space(1))) void*)(g),   \
    (__attribute__((address_space(3))) void*)(l), 16, 0, 0)

// ---------------- workspace offsets (floats) ----------------
constexpr size_t OFF_PQK = 0;                            // Pqk fp32 [2048][1024] = 2,097,152
constexpr size_t OFF_PVX = OFF_PQK + 2097152;            // Pvx fp32 [2048][2048] = 4,194,304
constexpr size_t OFF_XH  = OFF_PVX + 4194304;            // xh bf16 [2048][1024] -> 1,048,576 f
constexpr size_t OFF_XL  = OFF_XH  + 1048576;            // xl bf16 [2048][1024] -> 1,048,576 f
constexpr size_t OFF_WHI = OFF_XL  + 1048576;            // Whi bf16 [3072][1024] -> 1,572,864 f
constexpr size_t OFF_WLO = OFF_WHI + 1572864;            // Wlo bf16 [1024][1024] -> 524,288 f
constexpr size_t OFF_IV  = OFF_WLO + 524288;
constexpr size_t OFF_FV  = OFF_IV  + 16384;
constexpr size_t OFF_G   = OFF_FV  + 16384;
constexpr size_t OFF_GM  = OFF_G   + 16384;
// total 10,551,296 floats = 42.2 MB (same proven footprint)
// aliases (dead after gemm_proj):
constexpr size_t OFF_DL  = OFF_XH;                       // Dloc fp32 1,048,576
constexpr size_t OFF_HNG = OFF_XL;                       // hng bf16 [2048][1024] -> 1,048,576 f
constexpr size_t OFF_CB  = OFF_WHI;                      // Cbef fp32 1,048,576 (<= Whi region)
constexpr size_t OFF_WTO = OFF_WLO;                      // WtO bf16 [1024][1024]

// ---------------- fp32 -> (hi,lo) bf16 split ----------------
__global__ __launch_bounds__(256) void conv_split(
    const float* __restrict__ src,
    unsigned short* __restrict__ hi, unsigned short* __restrict__ lo, int n)
{
  int i = (blockIdx.x * 256 + threadIdx.x) * 8;
  if (i >= n) return;
  float4 a = *(const float4*)(src + i);
  float4 b = *(const float4*)(src + i + 4);
  float v[8] = { a.x, a.y, a.z, a.w, b.x, b.y, b.z, b.w };
  ushort8v rh, rl;
  #pragma unroll
  for (int j = 0; j < 8; ++j) {
    unsigned short h = f2bf(v[j]);
    rh[j] = h;
    rl[j] = f2bf(v[j] - bf2f(h));
  }
  *(ushort8v*)(hi + i) = rh;
  *(ushort8v*)(lo + i) = rl;
}

// ---------------- transpose + convert core ----------------
__device__ __forceinline__ void transp_body(
    const float* __restrict__ src,
    unsigned short* __restrict__ hi, unsigned short* __restrict__ lo,
    int N, int nt, int kt, int tid, float (*Ls)[65])
{
  #pragma unroll
  for (int p = 0; p < 16; ++p) {
    int lin = p * 256 + tid;
    int kr = lin >> 6, nc = lin & 63;
    Ls[kr][nc] = src[(size_t)(kt*64 + kr) * N + nt*64 + nc];
  }
  __syncthreads();
  #pragma unroll
  for (int p = 0; p < 16; ++p) {
    int lin = p * 256 + tid;
    int nr = lin >> 6, kc = lin & 63;
    float v = Ls[kc][nr];
    unsigned short h = f2bf(v);
    size_t di = (size_t)(nt*64 + nr) * 1024 + kt*64 + kc;
    hi[di] = h;
    if (lo) lo[di] = f2bf(v - bf2f(h));
  }
}

// merged transpose of Wq,Wk,Wv,Wog (grid.x = 8+8+16+16 = 48)
__global__ __launch_bounds__(256) void transp4(
    const float* __restrict__ Wq, const float* __restrict__ Wk,
    const float* __restrict__ Wv, const float* __restrict__ Wog,
    unsigned short* __restrict__ Whi, unsigned short* __restrict__ Wlo)
{
  __shared__ float Ls[64][65];
  const int x = blockIdx.x, kt = blockIdx.y, tid = threadIdx.x;
  if (x < 8)       transp_body(Wq,  Whi,              Wlo,            512,  x,      kt, tid, Ls);
  else if (x < 16) transp_body(Wk,  Whi +  512*1024,  Wlo + 512*1024, 512,  x - 8,  kt, tid, Ls);
  else if (x < 32) transp_body(Wv,  Whi + 1024*1024,  nullptr,        1024, x - 16, kt, tid, Ls);
  else             transp_body(Wog, Whi + 2048*1024,  nullptr,        1024, x - 32, kt, tid, Ls);
}

// single transpose (Wout, runs after gemm_proj frees Wlo space)
__global__ __launch_bounds__(256) void transp_hl(
    const float* __restrict__ src,
    unsigned short* __restrict__ hi, int N)
{
  __shared__ float Ls[64][65];
  transp_body(src, hi, nullptr, N, blockIdx.x, blockIdx.y, threadIdx.x, Ls);
}

// ---------------- fused projection GEMM, balanced heavy/light blocks ----------------
// 512 blocks, parity-decoded:
//  even bid -> HEAVY (q,k): idx h = bid>>1 (0..255); ct = h&7 (col-tile of 1024),
//      bm = h>>3 (0..31, M=64). 3-pass split-bf16 accumulate, plain store -> Pqk.
//  odd bid  -> LIGHT (v,xog): idx l = bid>>1 (0..255); ct = l&15, bm = l>>4 (M=128).
//      single pass xh*Whi -> Pvx.
__global__ __launch_bounds__(256) void gemm_proj(
    const unsigned short* __restrict__ xh,
    const unsigned short* __restrict__ xl,
    const unsigned short* __restrict__ Whi,
    const unsigned short* __restrict__ Wlo,
    float* __restrict__ Pqk, float* __restrict__ Pvx)
{
  __shared__ __align__(16) char smem[49152];
  const int tid  = threadIdx.x;
  const int bid  = blockIdx.x;
  const int wid  = tid >> 6, lane = tid & 63;
  const int wm   = wid >> 1, wn = wid & 1;
  const int lrow = lane & 15;
  const int lk   = (lane >> 4) * 16;
  const int srow = tid >> 3;            // 0..31
  const int scb  = (tid & 7) << 4;      // 0..112 B
  const int ldsW = wid * 1024;

  if (!(bid & 1)) {
    // ---------------- HEAVY: q,k with split-bf16, M=64 ----------------
    const int h  = bid >> 1;
    const int ct = h & 7, bm = h >> 3;
    char* Ah = smem;                 // xh tile 64x64  (8 KB)
    char* Al = smem + 8192;          // xl tile 64x64  (8 KB)
    char* Bh = smem + 16384;         // Whi tile 128x64 (16 KB)
    char* Bl = smem + 32768;         // Wlo tile 128x64 (16 KB)
    const char* xhB = (const char*)xh;
    const char* xlB = (const char*)xl;
    const char* whB = (const char*)(Whi + (size_t)ct*128*1024);
    const char* wlB = (const char*)(Wlo + (size_t)ct*128*1024);

    size_t gA[2], gB[4];
    #pragma unroll
    for (int i = 0; i < 2; ++i) {
      int row = i * 32 + srow;
      int cbs = scb ^ ((row & 7) << 4);
      gA[i] = (size_t)(bm*64 + row) * 2048 + cbs;
    }
    #pragma unroll
    for (int i = 0; i < 4; ++i) {
      int row = i * 32 + srow;
      int cbs = scb ^ ((row & 7) << 4);
      gB[i] = (size_t)row * 2048 + cbs;
    }

    f32x4 acc[2][4];
    const f32x4 z4 = { 0.f, 0.f, 0.f, 0.f };
    #pragma unroll
    for (int m = 0; m < 2; ++m)
      #pragma unroll
      for (int n = 0; n < 4; ++n) acc[m][n] = z4;

    for (int kt = 0; kt < 16; ++kt) {
      __syncthreads();
      #pragma unroll
      for (int i = 0; i < 2; ++i) GLD_LDS16(xhB + gA[i] + kt*128, Ah + i*4096 + ldsW);
      #pragma unroll
      for (int i = 0; i < 2; ++i) GLD_LDS16(xlB + gA[i] + kt*128, Al + i*4096 + ldsW);
      #pragma unroll
      for (int i = 0; i < 4; ++i) GLD_LDS16(whB + gB[i] + kt*128, Bh + i*4096 + ldsW);
      #pragma unroll
      for (int i = 0; i < 4; ++i) GLD_LDS16(wlB + gB[i] + kt*128, Bl + i*4096 + ldsW);
      __syncthreads();

      #pragma unroll
      for (int kk = 0; kk < 2; ++kk) {
        short8v ah[2], al[2], bh[4], bl[4];
        #pragma unroll
        for (int m = 0; m < 2; ++m) {
          int row = wm*32 + m*16 + lrow;
          int kb  = (kk*64 + lk) ^ ((row & 7) << 4);
          ah[m] = *(const short8v*)(Ah + row*128 + kb);
          al[m] = *(const short8v*)(Al + row*128 + kb);
        }
        #pragma unroll
        for (int n = 0; n < 4; ++n) {
          int row = wn*64 + n*16 + lrow;
          int kb  = (kk*64 + lk) ^ ((row & 7) << 4);
          bh[n] = *(const short8v*)(Bh + row*128 + kb);
          bl[n] = *(const short8v*)(Bl + row*128 + kb);
        }
        #pragma unroll
        for (int m = 0; m < 2; ++m)
          #pragma unroll
          for (int n = 0; n < 4; ++n) {
            acc[m][n] = __builtin_amdgcn_mfma_f32_16x16x32_bf16(ah[m], bh[n], acc[m][n], 0, 0, 0);
            acc[m][n] = __builtin_amdgcn_mfma_f32_16x16x32_bf16(al[m], bh[n], acc[m][n], 0, 0, 0);
            acc[m][n] = __builtin_amdgcn_mfma_f32_16x16x32_bf16(ah[m], bl[n], acc[m][n], 0, 0, 0);
          }
      }
    }

    const int crow0 = bm*64 + wm*32 + ((lane >> 4) << 2);
    const int ccol0 = ct*128 + wn*64 + lrow;
    #pragma unroll
    for (int m = 0; m < 2; ++m)
      #pragma unroll
      for (int n = 0; n < 4; ++n)
        #pragma unroll
        for (int r = 0; r < 4; ++r)
          Pqk[(size_t)(crow0 + m*16 + r) * 1024 + ccol0 + n*16] = acc[m][n][r];
  } else {
    // ---------------- LIGHT: v,xog plain bf16, M=128 ----------------
    const int l  = bid >> 1;
    const int ct = l & 15, bm = l >> 4;
    char* As = smem;                 // xh tile 128x64 (16 KB)
    char* Bs = smem + 16384;         // W tile 128x64 (16 KB)
    const char* xhB = (const char*)xh;
    const char* wB  = (const char*)(Whi + (size_t)(8 + ct)*128*1024);

    size_t gA[4], gB[4];
    #pragma unroll
    for (int i = 0; i < 4; ++i) {
      int row = i * 32 + srow;
      int cbs = scb ^ ((row & 7) << 4);
      gA[i] = (size_t)(bm*128 + row) * 2048 + cbs;
      gB[i] = (size_t)row * 2048 + cbs;
    }

    f32x4 acc[4][4];
    const f32x4 z4 = { 0.f, 0.f, 0.f, 0.f };
    #pragma unroll
    for (int m = 0; m < 4; ++m)
      #pragma unroll
      for (int n = 0; n < 4; ++n) acc[m][n] = z4;

    for (int kt = 0; kt < 16; ++kt) {
      __syncthreads();
      #pragma unroll
      for (int i = 0; i < 4; ++i) GLD_LDS16(xhB + gA[i] + kt*128, As + i*4096 + ldsW);
      #pragma unroll
      for (int i = 0; i < 4; ++i) GLD_LDS16(wB  + gB[i] + kt*128, Bs + i*4096 + ldsW);
      __syncthreads();

      #pragma unroll
      for (int kk = 0; kk < 2; ++kk) {
        short8v a[4], b[4];
        #pragma unroll
        for (int m = 0; m < 4; ++m) {
          int row = wm*64 + m*16 + lrow;
          int kb  = (kk*64 + lk) ^ ((row & 7) << 4);
          a[m] = *(const short8v*)(As + row*128 + kb);
        }
        #pragma unroll
        for (int n = 0; n < 4; ++n) {
          int row = wn*64 + n*16 + lrow;
          int kb  = (kk*64 + lk) ^ ((row & 7) << 4);
          b[n] = *(const short8v*)(Bs + row*128 + kb);
        }
        #pragma unroll
        for (int m = 0; m < 4; ++m)
          #pragma unroll
          for (int n = 0; n < 4; ++n)
            acc[m][n] = __builtin_amdgcn_mfma_f32_16x16x32_bf16(a[m], b[n], acc[m][n], 0, 0, 0);
      }
    }

    const int crow0 = bm*128 + wm*64 + ((lane >> 4) << 2);
    const int ccol0 = ct*128 + wn*64 + lrow;
    #pragma unroll
    for (int m = 0; m < 4; ++m)
      #pragma unroll
      for (int n = 0; n < 4; ++n)
        #pragma unroll
        for (int r = 0; r < 4; ++r)
          Pvx[(size_t)(crow0 + m*16 + r) * 2048 + ccol0 + n*16] = acc[m][n][r];
  }
}

// ---------------- output GEMM: 128x64 tiles ----------------
__global__ __launch_bounds__(256) void gemm_out64(
    const unsigned short* __restrict__ A,
    const unsigned short* __restrict__ Bt,
    float* __restrict__ C, int ldc)
{
  __shared__ __align__(16) unsigned short As[128*64];
  __shared__ __align__(16) unsigned short Bs[64*64];
  const int tid  = threadIdx.x;
  const int bm   = blockIdx.y, cn = blockIdx.x;
  const int wid  = tid >> 6, lane = tid & 63;
  const int wm   = wid >> 1, wn = wid & 1;
  const int lrow = lane & 15;
  const int lk   = (lane >> 4) * 16;

  f32x4 acc[4][2];
  const f32x4 z4 = { 0.f, 0.f, 0.f, 0.f };
  #pragma unroll
  for (int m = 0; m < 4; ++m)
    #pragma unroll
    for (int n = 0; n < 2; ++n) acc[m][n] = z4;

  const int srow = tid >> 3;
  const int scb  = (tid & 7) << 4;
  const char* Ab = (const char*)A;
  const char* Bb = (const char*)Bt;
  size_t gA[4], gB[2];
  #pragma unroll
  for (int i = 0; i < 4; ++i) {
    int row = i * 32 + srow;
    int cbs = scb ^ ((row & 7) << 4);
    gA[i] = (size_t)(bm*128 + row) * 2048 + cbs;
  }
  #pragma unroll
  for (int i = 0; i < 2; ++i) {
    int row = i * 32 + srow;
    int cbs = scb ^ ((row & 7) << 4);
    gB[i] = (size_t)(cn*64 + row) * 2048 + cbs;
  }
  const int ldsW = wid * 1024;

  for (int kt = 0; kt < 16; ++kt) {
    __syncthreads();
    #pragma unroll
    for (int i = 0; i < 4; ++i)
      GLD_LDS16(Ab + gA[i] + kt*128, (char*)As + i*4096 + ldsW);
    #pragma unroll
    for (int i = 0; i < 2; ++i)
      GLD_LDS16(Bb + gB[i] + kt*128, (char*)Bs + i*4096 + ldsW);
    __syncthreads();

    #pragma unroll
    for (int kk = 0; kk < 2; ++kk) {
      short8v a[4], b[2];
      #pragma unroll
      for (int m = 0; m < 4; ++m) {
        int row = wm*64 + m*16 + lrow;
        int kb  = (kk*64 + lk) ^ ((row & 7) << 4);
        a[m] = *(const short8v*)((const char*)As + row*128 + kb);
      }
      #pragma unroll
      for (int n = 0; n < 2; ++n) {
        int row = wn*32 + n*16 + lrow;
        int kb  = (kk*64 + lk) ^ ((row & 7) << 4);
        b[n] = *(const short8v*)((const char*)Bs + row*128 + kb);
      }
      #pragma unroll
      for (int m = 0; m < 4; ++m)
        #pragma unroll
        for (int n = 0; n < 2; ++n)
          acc[m][n] = __builtin_amdgcn_mfma_f32_16x16x32_bf16(a[m], b[n], acc[m][n], 0, 0, 0);
    }
  }

  const int crow0 = bm*128 + wm*64 + ((lane >> 4) << 2);
  const int ccol0 = cn*64 + wn*32 + (lane & 15);
  #pragma unroll
  for (int m = 0; m < 4; ++m)
    #pragma unroll
    for (int n = 0; n < 2; ++n)
      #pragma unroll
      for (int r = 0; r < 4; ++r)
        C[(size_t)(crow0 + m*16 + r) * ldc + ccol0 + n*16] = acc[m][n][r];
}

// ---------------- i/f projections (fp32, skinny N=8, float4-vectorized) ----------------
__global__ __launch_bounds__(64) void proj_if(
    const float* __restrict__ x,
    const float* __restrict__ Wi, const float* __restrict__ bi,
    const float* __restrict__ Wf, const float* __restrict__ bf,
    float* __restrict__ iv, float* __restrict__ fv)
{
  const int row = blockIdx.x, l = threadIdx.x;
  const float4* xr4 = (const float4*)(x + (size_t)row * NB_D);
  float ai[8] = {}, af[8] = {};
  #pragma unroll
  for (int p = 0; p < 4; ++p) {
    float4 xv = xr4[l + p*64];
    int k0 = (l + p*64) * 4;
    const float* xs = (const float*)&xv;
    #pragma unroll
    for (int j = 0; j < 4; ++j) {
      float xsv = xs[j];
      const float4* wi4 = (const float4*)(Wi + (size_t)(k0 + j) * 8);
      const float4* wf4 = (const float4*)(Wf + (size_t)(k0 + j) * 8);
      float4 w0 = wi4[0], w1 = wi4[1];
      float4 v0 = wf4[0], v1 = wf4[1];
      ai[0] += xsv*w0.x; ai[1] += xsv*w0.y; ai[2] += xsv*w0.z; ai[3] += xsv*w0.w;
      ai[4] += xsv*w1.x; ai[5] += xsv*w1.y; ai[6] += xsv*w1.z; ai[7] += xsv*w1.w;
      af[0] += xsv*v0.x; af[1] += xsv*v0.y; af[2] += xsv*v0.z; af[3] += xsv*v0.w;
      af[4] += xsv*v1.x; af[5] += xsv*v1.y; af[6] += xsv*v1.z; af[7] += xsv*v1.w;
    }
  }
  #pragma unroll
  for (int off = 1; off < 64; off <<= 1) {
    #pragma unroll
    for (int cc = 0; cc < 8; ++cc) {
      ai[cc] += __shfl_xor(ai[cc], off);
      af[cc] += __shfl_xor(af[cc], off);
    }
  }
  if (l == 0) {
    int b = row >> 10, s = row & (NB_S - 1);
    #pragma unroll
    for (int cc = 0; cc < 8; ++cc) {
      iv[(size_t)(b*NB_NH + cc) * NB_S + s] = ai[cc] + bi[cc];
      fv[(size_t)(b*NB_NH + cc) * NB_S + s] = af[cc] + bf[cc];
    }
  }
}

// ---------------- gate scan ----------------
__global__ __launch_bounds__(64) void gate_scan(
    const float* __restrict__ iv, const float* __restrict__ fv,
    float* __restrict__ gv, float* __restrict__ Gv)
{
  const int bh = blockIdx.x, l = threadIdx.x;
  const int base = bh * NB_S + l * 16;
  float fl[16];
  float run = 0.f;
  #pragma unroll
  for (int u = 0; u < 16; ++u) {
    float fr = fv[base + u];
    float flog = (fr >= 0.f) ? -log1pf(expf(-fr)) : (fr - log1pf(expf(fr)));
    run += flog; fl[u] = run;
  }
  float tot = run, sc = tot;
  #pragma unroll
  for (int off = 1; off < 64; off <<= 1) {
    float t = __shfl_up(sc, off);
    if (l >= off) sc += t;
  }
  float excl = sc - tot;
  float gm[16]; float rmax = -1e30f;
  #pragma unroll
  for (int u = 0; u < 16; ++u) {
    float bt = excl + fl[u];
    float g = iv[base + u] - bt;
    gv[base + u] = g;
    rmax = fmaxf(rmax, g); gm[u] = rmax;
  }
  float mx = rmax;
  #pragma unroll
  for (int off = 1; off < 64; off <<= 1) {
    float t = __shfl_up(mx, off);
    if (l >= off) mx = fmaxf(mx, t);
  }
  float em = __shfl_up(mx, 1);
  if (l == 0) em = -1e30f;
  #pragma unroll
  for (int u = 0; u < 16; ++u)
    Gv[base + u] = fmaxf(0.f, fmaxf(em, gm[u]));
}

// ---------------- per-chunk local KV state ----------------
__global__ __launch_bounds__(128) void chunk_local(
    const float* __restrict__ Pqk, const float* __restrict__ Pvx,
    const float* __restrict__ gv, const float* __restrict__ Gv,
    float* __restrict__ Dloc)
{
  __shared__ float ks[16][68];
  __shared__ float vs[16][132];
  __shared__ float wsg[16];
  const int bx = blockIdx.x, bh = bx >> 3, c = bx & 7;
  const int b = bh >> 3, h = bh & 7;
  const int tid = threadIdx.x;
  const int rg = tid >> 3, cg = tid & 7;
  const int i0 = rg * 4;
  float acc[4][16] = {};
  const float Gend = Gv[bh*NB_S + c*CL + CL - 1];
  const float* kbp = Pqk + ((size_t)b*NB_S + c*CL) * 1024 + 512 + h*NB_DQK;
  const float* vbp = Pvx + ((size_t)b*NB_S + c*CL) * 2048 + h*NB_DH;
  const float* gbp = gv + bh*NB_S + c*CL;
  for (int sb = 0; sb < 8; ++sb) {
    __syncthreads();
    #pragma unroll
    for (int p = 0; p < 2; ++p) {
      int qd = tid + p*128; int r = qd >> 4, cq = qd & 15;
      *(float4*)(&ks[r][cq*4]) = *(const float4*)(kbp + (size_t)(sb*16 + r)*1024 + cq*4);
    }
    #pragma unroll
    for (int p = 0; p < 4; ++p) {
      int qd = tid + p*128; int r = qd >> 5, cq = qd & 31;
      *(float4*)(&vs[r][cq*4]) = *(const float4*)(vbp + (size_t)(sb*16 + r)*2048 + cq*4);
    }
    if (tid < 16) wsg[tid] = expf(gbp[sb*16 + tid] - Gend);
    __syncthreads();
    #pragma unroll
    for (int s = 0; s < 16; ++s) {
      float w = wsg[s];
      float4 kq = *(const float4*)(&ks[s][i0]);
      float wk[4] = { w*kq.x, w*kq.y, w*kq.z, w*kq.w };
      #pragma unroll
      for (int m = 0; m < 4; ++m) {
        float4 vq = *(const float4*)(&vs[s][cg*4 + m*32]);
        #pragma unroll
        for (int u = 0; u < 4; ++u) {
          acc[u][m*4+0] += wk[u]*vq.x;
          acc[u][m*4+1] += wk[u]*vq.y;
          acc[u][m*4+2] += wk[u]*vq.z;
          acc[u][m*4+3] += wk[u]*vq.w;
        }
      }
    }
  }
  float* dst = Dloc + ((size_t)bh*NCH + c) * (NB_DQK*NB_DH);
  #pragma unroll
  for (int u = 0; u < 4; ++u)
    #pragma unroll
    for (int m = 0; m < 4; ++m) {
      float4 o4 = { acc[u][m*4+0], acc[u][m*4+1], acc[u][m*4+2], acc[u][m*4+3] };
      *(float4*)(dst + (size_t)(i0+u)*NB_DH + cg*4 + m*32) = o4;
    }
}

// ---------------- sequential chunk-state combine ----------------
__global__ __launch_bounds__(256) void chunk_combine(
    const float* __restrict__ Dloc, const float* __restrict__ Gv,
    float* __restrict__ Cbef)
{
  const int bh = blockIdx.x, tid = threadIdx.x;
  float4 acc[8];
  #pragma unroll
  for (int p = 0; p < 8; ++p) acc[p] = float4{0.f,0.f,0.f,0.f};
  float Gprev = 0.f;
  for (int c = 0; c < NCH; ++c) {
    const float4* dl = (const float4*)(Dloc + ((size_t)bh*NCH + c)*8192);
    float4* cb = (float4*)(Cbef + ((size_t)bh*NCH + c)*8192);
    float Gend = Gv[bh*NB_S + c*CL + CL - 1];
    float decay = (c == 0) ? 0.f : expf(Gprev - Gend);
    #pragma unroll
    for (int p = 0; p < 8; ++p) {
      int idx = tid + p*256;
      cb[idx] = acc[p];
      float4 d = dl[idx];
      acc[p].x = acc[p].x*decay + d.x;
      acc[p].y = acc[p].y*decay + d.y;
      acc[p].z = acc[p].z*decay + d.z;
      acc[p].w = acc[p].w*decay + d.w;
    }
    Gprev = Gend;
  }
}

// ---------------- chunked attention + state + LN + gate -> hng (bf16) ----------------
// grid 256: bh(16) x c(8) x half(2); each block computes 64 t-rows of one chunk.
__global__ __launch_bounds__(256,1) void chunk_out(
    const float* __restrict__ Pqk, const float* __restrict__ Pvx,
    const float* __restrict__ gv, const float* __restrict__ Gv,
    const float* __restrict__ Cbef,
    const float* __restrict__ lnw, const float* __restrict__ lnb,
    unsigned short* __restrict__ hng)
{
  __shared__ float attT[128][132];
  __shared__ float buf[128][132];
  __shared__ float gsh[128], Gsh[128], rsh[128];

  const int bx = blockIdx.x;
  const int half = bx & 1, c = (bx >> 1) & 7, bh = bx >> 4;
  const int b = bh >> 3, h = bh & 7;
  const int tid = threadIdx.x;
  const int tr = tid >> 4, tc = tid & 15;
  const int t0 = half*64 + tr*4;
  const size_t rowbase = (size_t)b*NB_S + (size_t)c*CL;
  const int sgbase = bh*NB_S + c*CL;

  #pragma unroll
  for (int p = 0; p < 8; ++p) {
    int qd = tid + p*256;
    int t = qd >> 4, iq = qd & 15;
    float4 q4 = *(const float4*)(Pqk + (rowbase + t)*1024 + h*NB_DQK + iq*4);
    buf[iq*4+0][t]=q4.x; buf[iq*4+1][t]=q4.y; buf[iq*4+2][t]=q4.z; buf[iq*4+3][t]=q4.w;
    float4 k4 = *(const float4*)(Pqk + (rowbase + t)*1024 + 512 + h*NB_DQK + iq*4);
    buf[64+iq*4+0][t]=k4.x; buf[64+iq*4+1][t]=k4.y; buf[64+iq*4+2][t]=k4.z; buf[64+iq*4+3][t]=k4.w;
  }
  if (tid < 128) {
    float gval = gv[sgbase + tid];
    float Gval = Gv[sgbase + tid];
    gsh[tid] = gval; Gsh[tid] = Gval;
    float Gprev = (c > 0) ? Gv[sgbase - 1] : 0.f;
    rsh[tid] = 0.125f * expf(Gprev - Gval);
  }
  __syncthreads();

  auto mm = [&](float (&accR)[4][8], float (*Am)[132], int ar0,
                float (*Bm)[132], int br0, int nq) {
    for (int iq = 0; iq < nq; ++iq) {
      float a[4][4], bq[4][8];
      #pragma unroll
      for (int w = 0; w < 4; ++w) {
        const float* ap = Am[ar0 + iq*4 + w];
        *(float4*)(&a[w][0]) = *(const float4*)(ap + t0);
        const float* bp = Bm[br0 + iq*4 + w];
        *(float4*)(&bq[w][0]) = *(const float4*)(bp + tc*4);
        *(float4*)(&bq[w][4]) = *(const float4*)(bp + tc*4 + 64);
      }
      #pragma unroll
      for (int w = 0; w < 4; ++w)
        #pragma unroll
        for (int u = 0; u < 4; ++u)
          #pragma unroll
          for (int x = 0; x < 8; ++x)
            accR[u][x] += a[w][u]*bq[w][x];
    }
  };

  { // att = Q K^T, weight, mask, store transposed (all 128 s rows written)
    float accA[4][8] = {};
    mm(accA, buf, 0, buf, 64, 16);
    float gtv[4];
    #pragma unroll
    for (int u = 0; u < 4; ++u) gtv[u] = Gsh[t0 + u];
    #pragma unroll
    for (int x = 0; x < 8; ++x) {
      int s = tc*4 + (x>>2)*64 + (x&3);
      float gs = gsh[s];
      float vv[4];
      #pragma unroll
      for (int u = 0; u < 4; ++u) {
        int t = t0 + u;
        float w = 0.125f * expf(gs - gtv[u]);
        vv[u] = (s <= t) ? accA[u][x]*w : 0.f;
      }
      float4 lo = {vv[0],vv[1],vv[2],vv[3]};
      *(float4*)(&attT[s][t0]) = lo;
    }
  }
  __syncthreads();

  { // load Cbefore into buf rows 64..127
    const float* Cbp = Cbef + ((size_t)bh*NCH + c)*(NB_DQK*NB_DH);
    #pragma unroll
    for (int p = 0; p < 8; ++p) {
      int qd = tid + p*256;
      int i = qd >> 5, jq = qd & 31;
      *(float4*)(&buf[64+i][jq*4]) = *(const float4*)(Cbp + (size_t)i*NB_DH + jq*4);
    }
  }
  __syncthreads();
  float acc2[4][8] = {};
  mm(acc2, buf, 0, buf, 64, 16);
  __syncthreads();

  { // load V into buf
    #pragma unroll
    for (int p = 0; p < 16; ++p) {
      int qd = tid + p*256;
      int sv = qd >> 5, jq = qd & 31;
      *(float4*)(&buf[sv][jq*4]) =
        *(const float4*)(Pvx + (rowbase + sv)*2048 + h*NB_DH + jq*4);
    }
  }
  __syncthreads();
  float hacc[4][8] = {};
  mm(hacc, attT, 0, buf, 0, 32);

  float lw[8], lb[8];
  {
    float4 a0 = *(const float4*)(lnw + h*NB_DH + tc*4);
    float4 a1 = *(const float4*)(lnw + h*NB_DH + tc*4 + 64);
    lw[0]=a0.x; lw[1]=a0.y; lw[2]=a0.z; lw[3]=a0.w;
    lw[4]=a1.x; lw[5]=a1.y; lw[6]=a1.z; lw[7]=a1.w;
    float4 b0 = *(const float4*)(lnb + h*NB_DH + tc*4);
    float4 b1 = *(const float4*)(lnb + h*NB_DH + tc*4 + 64);
    lb[0]=b0.x; lb[1]=b0.y; lb[2]=b0.z; lb[3]=b0.w;
    lb[4]=b1.x; lb[5]=b1.y; lb[6]=b1.z; lb[7]=b1.w;
  }
  #pragma unroll
  for (int u = 0; u < 4; ++u) {
    int t = t0 + u;
    float r = rsh[t];
    float hrow[8];
    #pragma unroll
    for (int x = 0; x < 8; ++x) hrow[x] = hacc[u][x] + r*acc2[u][x];
    float sum = 0.f, ssq = 0.f;
    #pragma unroll
    for (int x = 0; x < 8; ++x) { sum += hrow[x]; ssq += hrow[x]*hrow[x]; }
    #pragma unroll
    for (int off = 1; off < 16; off <<= 1) {
      sum += __shfl_xor(sum, off);
      ssq += __shfl_xor(ssq, off);
    }
    float mean = sum * (1.f/NB_DH);
    float var  = ssq * (1.f/NB_DH) - mean*mean;
    float rstd = rsqrtf(var + 1e-6f);
    #pragma unroll
    for (int m = 0; m < 2; ++m) {
      float4 xo = *(const float4*)(Pvx + (rowbase + t)*2048 + 1024 + h*NB_DH + tc*4 + m*64);
      float xov[4] = {xo.x, xo.y, xo.z, xo.w};
      unsigned short res[4];
      #pragma unroll
      for (int w = 0; w < 4; ++w) {
        int x = m*4 + w;
        float hn = (hrow[x] - mean)*rstd*lw[x] + lb[x];
        float tt = tanhf(xov[w]*(1.f/15.f))*15.f;
        float o = 1.f/(1.f + expf(-tt));
        res[w] = f2bf(hn*o);
      }
      ushort4v r4 = {res[0],res[1],res[2],res[3]};
      *(ushort4v*)(hng + (rowbase + t)*1024 + h*NB_DH + tc*4 + m*64) = r4;
    }
  }
}

extern "C" void kernel_launch(void* const* d_in, const int* in_sizes, int n_in,
                              void* d_out, int out_size, void* d_ws, size_t ws_size,
                              hipStream_t stream)
{
  (void)in_sizes; (void)n_in; (void)out_size; (void)ws_size;
  const float* x   = (const float*)d_in[0];
  const float* Wq  = (const float*)d_in[1];
  const float* Wk  = (const float*)d_in[2];
  const float* Wv  = (const float*)d_in[3];
  const float* Wi  = (const float*)d_in[4];
  const float* bi  = (const float*)d_in[5];
  const float* Wf  = (const float*)d_in[6];
  const float* bf  = (const float*)d_in[7];
  const float* Wog = (const float*)d_in[8];
  const float* lnw = (const float*)d_in[9];
  const float* lnb = (const float*)d_in[10];
  const float* Wout= (const float*)d_in[11];
  float* out = (float*)d_out;
  float* ws  = (float*)d_ws;

  float*          Pqk = ws + OFF_PQK;
  float*          Pvx = ws + OFF_PVX;
  unsigned short* xh  = (unsigned short*)(ws + OFF_XH);
  unsigned short* xl  = (unsigned short*)(ws + OFF_XL);
  unsigned short* Whi = (unsigned short*)(ws + OFF_WHI);
  unsigned short* Wlo = (unsigned short*)(ws + OFF_WLO);
  unsigned short* WtO = (unsigned short*)(ws + OFF_WTO);   // alias of Wlo (after proj)
  float*          iv  = ws + OFF_IV;
  float*          fv  = ws + OFF_FV;
  float*          g   = ws + OFF_G;
  float*          G   = ws + OFF_GM;
  float*          Dl  = ws + OFF_DL;                        // alias of xh
  float*          Cb  = ws + OFF_CB;                        // alias of Whi
  unsigned short* hng = (unsigned short*)(ws + OFF_HNG);    // alias of xl

  conv_split<<<1024, 256, 0, stream>>>(x, xh, xl, 2048*1024);
  transp4   <<<dim3(48,16), 256, 0, stream>>>(Wq, Wk, Wv, Wog, Whi, Wlo);

  proj_if  <<<2048, 64, 0, stream>>>(x, Wi, bi, Wf, bf, iv, fv);
  gate_scan<<<16, 64, 0, stream>>>(iv, fv, g, G);

  // balanced fused projection (in-block split-bf16 accumulation, no atomics)
  gemm_proj<<<512, 256, 0, stream>>>(xh, xl, Whi, Wlo, Pqk, Pvx);

  // Wout transpose reuses Wlo space (gemm_proj already consumed it)
  transp_hl<<<dim3(16,16), 256, 0, stream>>>(Wout, WtO, 1024);

  chunk_local  <<<128, 128, 0, stream>>>(Pqk, Pvx, g, G, Dl);
  chunk_combine<<<16, 256, 0, stream>>>(Dl, G, Cb);
  chunk_out    <<<256, 256, 0, stream>>>(Pqk, Pvx, g, G, Cb, lnw, lnb, hng);

  // out = hng[2048x1024] x Wout[1024x1024]
  gemm_out64<<<dim3(16,16), 256, 0, stream>>>(hng, WtO, out, 1024);
}

// Round 8
// 149.003 us; speedup vs baseline: 1.2161x; 1.0387x over previous
//
#include <hip/hip_runtime.h>
#include <math.h>

#define NB_B   2
#define NB_S   1024
#define NB_D   1024
#define NB_NH  8
#define NB_DQK 64
#define NB_DH  128
#define NCH    8
#define CL     128

typedef __attribute__((ext_vector_type(8))) short  short8v;   // 8 x bf16
typedef __attribute__((ext_vector_type(4))) float  f32x4;
typedef __attribute__((ext_vector_type(8))) unsigned short ushort8v;
typedef __attribute__((ext_vector_type(4))) unsigned short ushort4v;

__device__ __forceinline__ unsigned short f2bf(float f) {
  unsigned u = __float_as_uint(f);
  unsigned r = (u + 0x7FFFu + ((u >> 16) & 1u)) >> 16;
  return (unsigned short)r;
}
__device__ __forceinline__ float bf2f(unsigned short h) {
  return __uint_as_float(((unsigned)h) << 16);
}

#define GLD_LDS16(g, l) __builtin_amdgcn_global_load_lds( \
    (const __attribute__((address_space(1))) void*)(g),   \
    (__attribute__((address_space(3))) void*)(l), 16, 0, 0)

#define MFMA_BF16(a, b, c) __builtin_amdgcn_mfma_f32_16x16x32_bf16((a), (b), (c), 0, 0, 0)

// ---------------- workspace offsets (floats) ----------------
constexpr size_t OFF_PQK = 0;                            // Pqk fp32 [2048][1024] = 2,097,152
constexpr size_t OFF_PVX = OFF_PQK + 2097152;            // Pvx fp32 [2048][2048] = 4,194,304
constexpr size_t OFF_XH  = OFF_PVX + 4194304;            // xh bf16 [2048][1024] -> 1,048,576 f
constexpr size_t OFF_XL  = OFF_XH  + 1048576;            // xl bf16 [2048][1024] -> 1,048,576 f
constexpr size_t OFF_WHI = OFF_XL  + 1048576;            // Whi bf16 [3072][1024] -> 1,572,864 f
constexpr size_t OFF_WLO = OFF_WHI + 1572864;            // Wlo bf16 [1024][1024] -> 524,288 f
constexpr size_t OFF_IV  = OFF_WLO + 524288;
constexpr size_t OFF_FV  = OFF_IV  + 16384;
constexpr size_t OFF_G   = OFF_FV  + 16384;
constexpr size_t OFF_GM  = OFF_G   + 16384;
// total 10,551,296 floats = 42.2 MB (same proven footprint)
// aliases (dead after gemm_proj):
constexpr size_t OFF_DL  = OFF_XH;                       // Dloc fp32 1,048,576
constexpr size_t OFF_HNG = OFF_XL;                       // hng bf16 [2048][1024] -> 1,048,576 f
constexpr size_t OFF_CB  = OFF_WHI;                      // Cbef fp32 1,048,576 (<= Whi region)
constexpr size_t OFF_WTO = OFF_WLO;                      // WtO bf16 [1024][1024]

// ---------------- fp32 -> (hi,lo) bf16 split ----------------
__global__ __launch_bounds__(256) void conv_split(
    const float* __restrict__ src,
    unsigned short* __restrict__ hi, unsigned short* __restrict__ lo, int n)
{
  int i = (blockIdx.x * 256 + threadIdx.x) * 8;
  if (i >= n) return;
  float4 a = *(const float4*)(src + i);
  float4 b = *(const float4*)(src + i + 4);
  float v[8] = { a.x, a.y, a.z, a.w, b.x, b.y, b.z, b.w };
  ushort8v rh, rl;
  #pragma unroll
  for (int j = 0; j < 8; ++j) {
    unsigned short h = f2bf(v[j]);
    rh[j] = h;
    rl[j] = f2bf(v[j] - bf2f(h));
  }
  *(ushort8v*)(hi + i) = rh;
  *(ushort8v*)(lo + i) = rl;
}

// ---------------- transpose + convert core ----------------
__device__ __forceinline__ void transp_body(
    const float* __restrict__ src,
    unsigned short* __restrict__ hi, unsigned short* __restrict__ lo,
    int N, int nt, int kt, int tid, float (*Ls)[65])
{
  #pragma unroll
  for (int p = 0; p < 16; ++p) {
    int lin = p * 256 + tid;
    int kr = lin >> 6, nc = lin & 63;
    Ls[kr][nc] = src[(size_t)(kt*64 + kr) * N + nt*64 + nc];
  }
  __syncthreads();
  #pragma unroll
  for (int p = 0; p < 16; ++p) {
    int lin = p * 256 + tid;
    int nr = lin >> 6, kc = lin & 63;
    float v = Ls[kc][nr];
    unsigned short h = f2bf(v);
    size_t di = (size_t)(nt*64 + nr) * 1024 + kt*64 + kc;
    hi[di] = h;
    if (lo) lo[di] = f2bf(v - bf2f(h));
  }
}

// merged transpose of Wq,Wk,Wv,Wog (grid.x = 8+8+16+16 = 48)
__global__ __launch_bounds__(256) void transp4(
    const float* __restrict__ Wq, const float* __restrict__ Wk,
    const float* __restrict__ Wv, const float* __restrict__ Wog,
    unsigned short* __restrict__ Whi, unsigned short* __restrict__ Wlo)
{
  __shared__ float Ls[64][65];
  const int x = blockIdx.x, kt = blockIdx.y, tid = threadIdx.x;
  if (x < 8)       transp_body(Wq,  Whi,              Wlo,            512,  x,      kt, tid, Ls);
  else if (x < 16) transp_body(Wk,  Whi +  512*1024,  Wlo + 512*1024, 512,  x - 8,  kt, tid, Ls);
  else if (x < 32) transp_body(Wv,  Whi + 1024*1024,  nullptr,        1024, x - 16, kt, tid, Ls);
  else             transp_body(Wog, Whi + 2048*1024,  nullptr,        1024, x - 32, kt, tid, Ls);
}

// single transpose (Wout, runs after gemm_proj frees Wlo space)
__global__ __launch_bounds__(256) void transp_hl(
    const float* __restrict__ src,
    unsigned short* __restrict__ hi, int N)
{
  __shared__ float Ls[64][65];
  transp_body(src, hi, nullptr, N, blockIdx.x, blockIdx.y, threadIdx.x, Ls);
}

// ---------------- fused projection GEMM, balanced heavy/light blocks ----------------
__global__ __launch_bounds__(256) void gemm_proj(
    const unsigned short* __restrict__ xh,
    const unsigned short* __restrict__ xl,
    const unsigned short* __restrict__ Whi,
    const unsigned short* __restrict__ Wlo,
    float* __restrict__ Pqk, float* __restrict__ Pvx)
{
  __shared__ __align__(16) char smem[49152];
  const int tid  = threadIdx.x;
  const int bid  = blockIdx.x;
  const int wid  = tid >> 6, lane = tid & 63;
  const int wm   = wid >> 1, wn = wid & 1;
  const int lrow = lane & 15;
  const int lk   = (lane >> 4) * 16;
  const int srow = tid >> 3;            // 0..31
  const int scb  = (tid & 7) << 4;      // 0..112 B
  const int ldsW = wid * 1024;

  if (!(bid & 1)) {
    // HEAVY: q,k with split-bf16, M=64
    const int h  = bid >> 1;
    const int ct = h & 7, bm = h >> 3;
    char* Ah = smem;
    char* Al = smem + 8192;
    char* Bh = smem + 16384;
    char* Bl = smem + 32768;
    const char* xhB = (const char*)xh;
    const char* xlB = (const char*)xl;
    const char* whB = (const char*)(Whi + (size_t)ct*128*1024);
    const char* wlB = (const char*)(Wlo + (size_t)ct*128*1024);

    size_t gA[2], gB[4];
    #pragma unroll
    for (int i = 0; i < 2; ++i) {
      int row = i * 32 + srow;
      int cbs = scb ^ ((row & 7) << 4);
      gA[i] = (size_t)(bm*64 + row) * 2048 + cbs;
    }
    #pragma unroll
    for (int i = 0; i < 4; ++i) {
      int row = i * 32 + srow;
      int cbs = scb ^ ((row & 7) << 4);
      gB[i] = (size_t)row * 2048 + cbs;
    }

    f32x4 acc[2][4];
    const f32x4 z4 = { 0.f, 0.f, 0.f, 0.f };
    #pragma unroll
    for (int m = 0; m < 2; ++m)
      #pragma unroll
      for (int n = 0; n < 4; ++n) acc[m][n] = z4;

    for (int kt = 0; kt < 16; ++kt) {
      __syncthreads();
      #pragma unroll
      for (int i = 0; i < 2; ++i) GLD_LDS16(xhB + gA[i] + kt*128, Ah + i*4096 + ldsW);
      #pragma unroll
      for (int i = 0; i < 2; ++i) GLD_LDS16(xlB + gA[i] + kt*128, Al + i*4096 + ldsW);
      #pragma unroll
      for (int i = 0; i < 4; ++i) GLD_LDS16(whB + gB[i] + kt*128, Bh + i*4096 + ldsW);
      #pragma unroll
      for (int i = 0; i < 4; ++i) GLD_LDS16(wlB + gB[i] + kt*128, Bl + i*4096 + ldsW);
      __syncthreads();

      #pragma unroll
      for (int kk = 0; kk < 2; ++kk) {
        short8v ah[2], al[2], bh[4], bl[4];
        #pragma unroll
        for (int m = 0; m < 2; ++m) {
          int row = wm*32 + m*16 + lrow;
          int kb  = (kk*64 + lk) ^ ((row & 7) << 4);
          ah[m] = *(const short8v*)(Ah + row*128 + kb);
          al[m] = *(const short8v*)(Al + row*128 + kb);
        }
        #pragma unroll
        for (int n = 0; n < 4; ++n) {
          int row = wn*64 + n*16 + lrow;
          int kb  = (kk*64 + lk) ^ ((row & 7) << 4);
          bh[n] = *(const short8v*)(Bh + row*128 + kb);
          bl[n] = *(const short8v*)(Bl + row*128 + kb);
        }
        #pragma unroll
        for (int m = 0; m < 2; ++m)
          #pragma unroll
          for (int n = 0; n < 4; ++n) {
            acc[m][n] = MFMA_BF16(ah[m], bh[n], acc[m][n]);
            acc[m][n] = MFMA_BF16(al[m], bh[n], acc[m][n]);
            acc[m][n] = MFMA_BF16(ah[m], bl[n], acc[m][n]);
          }
      }
    }

    const int crow0 = bm*64 + wm*32 + ((lane >> 4) << 2);
    const int ccol0 = ct*128 + wn*64 + lrow;
    #pragma unroll
    for (int m = 0; m < 2; ++m)
      #pragma unroll
      for (int n = 0; n < 4; ++n)
        #pragma unroll
        for (int r = 0; r < 4; ++r)
          Pqk[(size_t)(crow0 + m*16 + r) * 1024 + ccol0 + n*16] = acc[m][n][r];
  } else {
    // LIGHT: v,xog plain bf16, M=128
    const int l  = bid >> 1;
    const int ct = l & 15, bm = l >> 4;
    char* As = smem;
    char* Bs = smem + 16384;
    const char* xhB = (const char*)xh;
    const char* wB  = (const char*)(Whi + (size_t)(8 + ct)*128*1024);

    size_t gA[4], gB[4];
    #pragma unroll
    for (int i = 0; i < 4; ++i) {
      int row = i * 32 + srow;
      int cbs = scb ^ ((row & 7) << 4);
      gA[i] = (size_t)(bm*128 + row) * 2048 + cbs;
      gB[i] = (size_t)row * 2048 + cbs;
    }

    f32x4 acc[4][4];
    const f32x4 z4 = { 0.f, 0.f, 0.f, 0.f };
    #pragma unroll
    for (int m = 0; m < 4; ++m)
      #pragma unroll
      for (int n = 0; n < 4; ++n) acc[m][n] = z4;

    for (int kt = 0; kt < 16; ++kt) {
      __syncthreads();
      #pragma unroll
      for (int i = 0; i < 4; ++i) GLD_LDS16(xhB + gA[i] + kt*128, As + i*4096 + ldsW);
      #pragma unroll
      for (int i = 0; i < 4; ++i) GLD_LDS16(wB  + gB[i] + kt*128, Bs + i*4096 + ldsW);
      __syncthreads();

      #pragma unroll
      for (int kk = 0; kk < 2; ++kk) {
        short8v a[4], b[4];
        #pragma unroll
        for (int m = 0; m < 4; ++m) {
          int row = wm*64 + m*16 + lrow;
          int kb  = (kk*64 + lk) ^ ((row & 7) << 4);
          a[m] = *(const short8v*)(As + row*128 + kb);
        }
        #pragma unroll
        for (int n = 0; n < 4; ++n) {
          int row = wn*64 + n*16 + lrow;
          int kb  = (kk*64 + lk) ^ ((row & 7) << 4);
          b[n] = *(const short8v*)(Bs + row*128 + kb);
        }
        #pragma unroll
        for (int m = 0; m < 4; ++m)
          #pragma unroll
          for (int n = 0; n < 4; ++n)
            acc[m][n] = MFMA_BF16(a[m], b[n], acc[m][n]);
      }
    }

    const int crow0 = bm*128 + wm*64 + ((lane >> 4) << 2);
    const int ccol0 = ct*128 + wn*64 + lrow;
    #pragma unroll
    for (int m = 0; m < 4; ++m)
      #pragma unroll
      for (int n = 0; n < 4; ++n)
        #pragma unroll
        for (int r = 0; r < 4; ++r)
          Pvx[(size_t)(crow0 + m*16 + r) * 2048 + ccol0 + n*16] = acc[m][n][r];
  }
}

// ---------------- output GEMM: 128x64 tiles ----------------
__global__ __launch_bounds__(256) void gemm_out64(
    const unsigned short* __restrict__ A,
    const unsigned short* __restrict__ Bt,
    float* __restrict__ C, int ldc)
{
  __shared__ __align__(16) unsigned short As[128*64];
  __shared__ __align__(16) unsigned short Bs[64*64];
  const int tid  = threadIdx.x;
  const int bm   = blockIdx.y, cn = blockIdx.x;
  const int wid  = tid >> 6, lane = tid & 63;
  const int wm   = wid >> 1, wn = wid & 1;
  const int lrow = lane & 15;
  const int lk   = (lane >> 4) * 16;

  f32x4 acc[4][2];
  const f32x4 z4 = { 0.f, 0.f, 0.f, 0.f };
  #pragma unroll
  for (int m = 0; m < 4; ++m)
    #pragma unroll
    for (int n = 0; n < 2; ++n) acc[m][n] = z4;

  const int srow = tid >> 3;
  const int scb  = (tid & 7) << 4;
  const char* Ab = (const char*)A;
  const char* Bb = (const char*)Bt;
  size_t gA[4], gB[2];
  #pragma unroll
  for (int i = 0; i < 4; ++i) {
    int row = i * 32 + srow;
    int cbs = scb ^ ((row & 7) << 4);
    gA[i] = (size_t)(bm*128 + row) * 2048 + cbs;
  }
  #pragma unroll
  for (int i = 0; i < 2; ++i) {
    int row = i * 32 + srow;
    int cbs = scb ^ ((row & 7) << 4);
    gB[i] = (size_t)(cn*64 + row) * 2048 + cbs;
  }
  const int ldsW = wid * 1024;

  for (int kt = 0; kt < 16; ++kt) {
    __syncthreads();
    #pragma unroll
    for (int i = 0; i < 4; ++i)
      GLD_LDS16(Ab + gA[i] + kt*128, (char*)As + i*4096 + ldsW);
    #pragma unroll
    for (int i = 0; i < 2; ++i)
      GLD_LDS16(Bb + gB[i] + kt*128, (char*)Bs + i*4096 + ldsW);
    __syncthreads();

    #pragma unroll
    for (int kk = 0; kk < 2; ++kk) {
      short8v a[4], b[2];
      #pragma unroll
      for (int m = 0; m < 4; ++m) {
        int row = wm*64 + m*16 + lrow;
        int kb  = (kk*64 + lk) ^ ((row & 7) << 4);
        a[m] = *(const short8v*)((const char*)As + row*128 + kb);
      }
      #pragma unroll
      for (int n = 0; n < 2; ++n) {
        int row = wn*32 + n*16 + lrow;
        int kb  = (kk*64 + lk) ^ ((row & 7) << 4);
        b[n] = *(const short8v*)((const char*)Bs + row*128 + kb);
      }
      #pragma unroll
      for (int m = 0; m < 4; ++m)
        #pragma unroll
        for (int n = 0; n < 2; ++n)
          acc[m][n] = MFMA_BF16(a[m], b[n], acc[m][n]);
    }
  }

  const int crow0 = bm*128 + wm*64 + ((lane >> 4) << 2);
  const int ccol0 = cn*64 + wn*32 + (lane & 15);
  #pragma unroll
  for (int m = 0; m < 4; ++m)
    #pragma unroll
    for (int n = 0; n < 2; ++n)
      #pragma unroll
      for (int r = 0; r < 4; ++r)
        C[(size_t)(crow0 + m*16 + r) * ldc + ccol0 + n*16] = acc[m][n][r];
}

// ---------------- i/f projections (fp32, skinny N=8, float4-vectorized) ----------------
__global__ __launch_bounds__(64) void proj_if(
    const float* __restrict__ x,
    const float* __restrict__ Wi, const float* __restrict__ bi,
    const float* __restrict__ Wf, const float* __restrict__ bf,
    float* __restrict__ iv, float* __restrict__ fv)
{
  const int row = blockIdx.x, l = threadIdx.x;
  const float4* xr4 = (const float4*)(x + (size_t)row * NB_D);
  float ai[8] = {}, af[8] = {};
  #pragma unroll
  for (int p = 0; p < 4; ++p) {
    float4 xv = xr4[l + p*64];
    int k0 = (l + p*64) * 4;
    const float* xs = (const float*)&xv;
    #pragma unroll
    for (int j = 0; j < 4; ++j) {
      float xsv = xs[j];
      const float4* wi4 = (const float4*)(Wi + (size_t)(k0 + j) * 8);
      const float4* wf4 = (const float4*)(Wf + (size_t)(k0 + j) * 8);
      float4 w0 = wi4[0], w1 = wi4[1];
      float4 v0 = wf4[0], v1 = wf4[1];
      ai[0] += xsv*w0.x; ai[1] += xsv*w0.y; ai[2] += xsv*w0.z; ai[3] += xsv*w0.w;
      ai[4] += xsv*w1.x; ai[5] += xsv*w1.y; ai[6] += xsv*w1.z; ai[7] += xsv*w1.w;
      af[0] += xsv*v0.x; af[1] += xsv*v0.y; af[2] += xsv*v0.z; af[3] += xsv*v0.w;
      af[4] += xsv*v1.x; af[5] += xsv*v1.y; af[6] += xsv*v1.z; af[7] += xsv*v1.w;
    }
  }
  #pragma unroll
  for (int off = 1; off < 64; off <<= 1) {
    #pragma unroll
    for (int cc = 0; cc < 8; ++cc) {
      ai[cc] += __shfl_xor(ai[cc], off);
      af[cc] += __shfl_xor(af[cc], off);
    }
  }
  if (l == 0) {
    int b = row >> 10, s = row & (NB_S - 1);
    #pragma unroll
    for (int cc = 0; cc < 8; ++cc) {
      iv[(size_t)(b*NB_NH + cc) * NB_S + s] = ai[cc] + bi[cc];
      fv[(size_t)(b*NB_NH + cc) * NB_S + s] = af[cc] + bf[cc];
    }
  }
}

// ---------------- gate scan ----------------
__global__ __launch_bounds__(64) void gate_scan(
    const float* __restrict__ iv, const float* __restrict__ fv,
    float* __restrict__ gv, float* __restrict__ Gv)
{
  const int bh = blockIdx.x, l = threadIdx.x;
  const int base = bh * NB_S + l * 16;
  float fl[16];
  float run = 0.f;
  #pragma unroll
  for (int u = 0; u < 16; ++u) {
    float fr = fv[base + u];
    float flog = (fr >= 0.f) ? -log1pf(expf(-fr)) : (fr - log1pf(expf(fr)));
    run += flog; fl[u] = run;
  }
  float tot = run, sc = tot;
  #pragma unroll
  for (int off = 1; off < 64; off <<= 1) {
    float t = __shfl_up(sc, off);
    if (l >= off) sc += t;
  }
  float excl = sc - tot;
  float gm[16]; float rmax = -1e30f;
  #pragma unroll
  for (int u = 0; u < 16; ++u) {
    float bt = excl + fl[u];
    float g = iv[base + u] - bt;
    gv[base + u] = g;
    rmax = fmaxf(rmax, g); gm[u] = rmax;
  }
  float mx = rmax;
  #pragma unroll
  for (int off = 1; off < 64; off <<= 1) {
    float t = __shfl_up(mx, off);
    if (l >= off) mx = fmaxf(mx, t);
  }
  float em = __shfl_up(mx, 1);
  if (l == 0) em = -1e30f;
  #pragma unroll
  for (int u = 0; u < 16; ++u)
    Gv[base + u] = fmaxf(0.f, fmaxf(em, gm[u]));
}

// ---------------- per-chunk local KV state ----------------
__global__ __launch_bounds__(128) void chunk_local(
    const float* __restrict__ Pqk, const float* __restrict__ Pvx,
    const float* __restrict__ gv, const float* __restrict__ Gv,
    float* __restrict__ Dloc)
{
  __shared__ float ks[16][68];
  __shared__ float vs[16][132];
  __shared__ float wsg[16];
  const int bx = blockIdx.x, bh = bx >> 3, c = bx & 7;
  const int b = bh >> 3, h = bh & 7;
  const int tid = threadIdx.x;
  const int rg = tid >> 3, cg = tid & 7;
  const int i0 = rg * 4;
  float acc[4][16] = {};
  const float Gend = Gv[bh*NB_S + c*CL + CL - 1];
  const float* kbp = Pqk + ((size_t)b*NB_S + c*CL) * 1024 + 512 + h*NB_DQK;
  const float* vbp = Pvx + ((size_t)b*NB_S + c*CL) * 2048 + h*NB_DH;
  const float* gbp = gv + bh*NB_S + c*CL;
  for (int sb = 0; sb < 8; ++sb) {
    __syncthreads();
    #pragma unroll
    for (int p = 0; p < 2; ++p) {
      int qd = tid + p*128; int r = qd >> 4, cq = qd & 15;
      *(float4*)(&ks[r][cq*4]) = *(const float4*)(kbp + (size_t)(sb*16 + r)*1024 + cq*4);
    }
    #pragma unroll
    for (int p = 0; p < 4; ++p) {
      int qd = tid + p*128; int r = qd >> 5, cq = qd & 31;
      *(float4*)(&vs[r][cq*4]) = *(const float4*)(vbp + (size_t)(sb*16 + r)*2048 + cq*4);
    }
    if (tid < 16) wsg[tid] = expf(gbp[sb*16 + tid] - Gend);
    __syncthreads();
    #pragma unroll
    for (int s = 0; s < 16; ++s) {
      float w = wsg[s];
      float4 kq = *(const float4*)(&ks[s][i0]);
      float wk[4] = { w*kq.x, w*kq.y, w*kq.z, w*kq.w };
      #pragma unroll
      for (int m = 0; m < 4; ++m) {
        float4 vq = *(const float4*)(&vs[s][cg*4 + m*32]);
        #pragma unroll
        for (int u = 0; u < 4; ++u) {
          acc[u][m*4+0] += wk[u]*vq.x;
          acc[u][m*4+1] += wk[u]*vq.y;
          acc[u][m*4+2] += wk[u]*vq.z;
          acc[u][m*4+3] += wk[u]*vq.w;
        }
      }
    }
  }
  float* dst = Dloc + ((size_t)bh*NCH + c) * (NB_DQK*NB_DH);
  #pragma unroll
  for (int u = 0; u < 4; ++u)
    #pragma unroll
    for (int m = 0; m < 4; ++m) {
      float4 o4 = { acc[u][m*4+0], acc[u][m*4+1], acc[u][m*4+2], acc[u][m*4+3] };
      *(float4*)(dst + (size_t)(i0+u)*NB_DH + cg*4 + m*32) = o4;
    }
}

// ---------------- sequential chunk-state combine ----------------
__global__ __launch_bounds__(256) void chunk_combine(
    const float* __restrict__ Dloc, const float* __restrict__ Gv,
    float* __restrict__ Cbef)
{
  const int bh = blockIdx.x, tid = threadIdx.x;
  float4 acc[8];
  #pragma unroll
  for (int p = 0; p < 8; ++p) acc[p] = float4{0.f,0.f,0.f,0.f};
  float Gprev = 0.f;
  for (int c = 0; c < NCH; ++c) {
    const float4* dl = (const float4*)(Dloc + ((size_t)bh*NCH + c)*8192);
    float4* cb = (float4*)(Cbef + ((size_t)bh*NCH + c)*8192);
    float Gend = Gv[bh*NB_S + c*CL + CL - 1];
    float decay = (c == 0) ? 0.f : expf(Gprev - Gend);
    #pragma unroll
    for (int p = 0; p < 8; ++p) {
      int idx = tid + p*256;
      cb[idx] = acc[p];
      float4 d = dl[idx];
      acc[p].x = acc[p].x*decay + d.x;
      acc[p].y = acc[p].y*decay + d.y;
      acc[p].z = acc[p].z*decay + d.z;
      acc[p].w = acc[p].w*decay + d.w;
    }
    Gprev = Gend;
  }
}

// ---------------- chunked attention via MFMA + LN + gate -> hng (bf16) ----------------
// grid 256: bh(16) x c(8) x half(2); each block = 64 t-rows of one chunk, 4 waves.
// S and Q*Cbef use split-bf16 (hi+lo) for sign-exact scores; PV uses bf16 att/V.
__global__ __launch_bounds__(256,1) void chunk_out(
    const float* __restrict__ Pqk, const float* __restrict__ Pvx,
    const float* __restrict__ gv, const float* __restrict__ Gv,
    const float* __restrict__ Cbef,
    const float* __restrict__ lnw, const float* __restrict__ lnb,
    unsigned short* __restrict__ hng)
{
  // LDS layout (bytes): qh 8K | ql 8K | kh 16K | kl 16K | att 16K | vt 32K | cbh 16K | cbl 16K
  __shared__ __align__(16) char smem[131072];
  __shared__ float gsh[128], Gsh[128], rsh[128];
  constexpr int QH = 0, QL = 8192, KH = 16384, KL = 32768;
  constexpr int ATT = 49152, VT = 65536, CBH = 98304, CBL = 114688;

  const int bx = blockIdx.x;
  const int half = bx & 1, c = (bx >> 1) & 7, bh = bx >> 4;
  const int b = bh >> 3, h = bh & 7;
  const int tid = threadIdx.x;
  const int wid = tid >> 6, lane = tid & 63;
  const int lrow = lane & 15;
  const int lkB  = (lane >> 4) * 16;        // byte offset of 8-elem k-subchunk
  const size_t rowbase = (size_t)b*NB_S + (size_t)c*CL;
  const int sgbase = bh*NB_S + c*CL;

  if (tid < 128) {
    float gval = gv[sgbase + tid];
    float Gval = Gv[sgbase + tid];
    gsh[tid] = gval; Gsh[tid] = Gval;
    float Gprev = (c > 0) ? Gv[sgbase - 1] : 0.f;
    rsh[tid] = 0.125f * expf(Gprev - Gval);
  }

  // ---- phase 0: convert operands into swizzled LDS ----
  // q (own half, 64x64) -> qh/ql
  #pragma unroll
  for (int p = 0; p < 4; ++p) {
    int lin = p*256 + tid;
    int row = lin >> 4, i0 = (lin & 15) * 4;
    float4 v4 = *(const float4*)(Pqk + (rowbase + half*64 + row)*1024 + h*NB_DQK + i0);
    float vv[4] = { v4.x, v4.y, v4.z, v4.w };
    ushort4v h4, l4;
    #pragma unroll
    for (int j = 0; j < 4; ++j) {
      unsigned short hh = f2bf(vv[j]); h4[j] = hh; l4[j] = f2bf(vv[j] - bf2f(hh));
    }
    int off = (row*128 + i0*2) ^ ((row & 7) << 4);
    *(ushort4v*)(smem + QH + off) = h4;
    *(ushort4v*)(smem + QL + off) = l4;
  }
  // k (full chunk, 128x64) -> kh/kl
  #pragma unroll
  for (int p = 0; p < 8; ++p) {
    int lin = p*256 + tid;
    int row = lin >> 4, i0 = (lin & 15) * 4;
    float4 v4 = *(const float4*)(Pqk + (rowbase + row)*1024 + 512 + h*NB_DQK + i0);
    float vv[4] = { v4.x, v4.y, v4.z, v4.w };
    ushort4v h4, l4;
    #pragma unroll
    for (int j = 0; j < 4; ++j) {
      unsigned short hh = f2bf(vv[j]); h4[j] = hh; l4[j] = f2bf(vv[j] - bf2f(hh));
    }
    int off = (row*128 + i0*2) ^ ((row & 7) << 4);
    *(ushort4v*)(smem + KH + off) = h4;
    *(ushort4v*)(smem + KL + off) = l4;
  }
  // V^T (128s x 128j -> vt[j][s], bf16)
  #pragma unroll
  for (int p = 0; p < 16; ++p) {
    int lin = p*256 + tid;
    int s = lin >> 5, j0 = (lin & 31) * 4;
    float4 v4 = *(const float4*)(Pvx + (rowbase + s)*2048 + h*NB_DH + j0);
    float vv[4] = { v4.x, v4.y, v4.z, v4.w };
    #pragma unroll
    for (int j = 0; j < 4; ++j) {
      int jj = j0 + j;
      int off = (jj*256 + s*2) ^ ((jj & 7) << 4);
      *(unsigned short*)(smem + VT + off) = f2bf(vv[j]);
    }
  }
  // Cb^T (Cbef [64i][128j] fp32 -> cbh/cbl [128j][64i] bf16 hi/lo)
  {
    const float* Cbp = Cbef + ((size_t)bh*NCH + c)*(NB_DQK*NB_DH);
    #pragma unroll
    for (int p = 0; p < 8; ++p) {
      int lin = p*256 + tid;
      int i = lin >> 5, j0 = (lin & 31) * 4;
      float4 v4 = *(const float4*)(Cbp + (size_t)i*NB_DH + j0);
      float vv[4] = { v4.x, v4.y, v4.z, v4.w };
      #pragma unroll
      for (int w = 0; w < 4; ++w) {
        int jj = j0 + w;
        int off = (jj*128 + i*2) ^ ((jj & 7) << 4);
        unsigned short hh = f2bf(vv[w]);
        *(unsigned short*)(smem + CBH + off) = hh;
        *(unsigned short*)(smem + CBL + off) = f2bf(vv[w] - bf2f(hh));
      }
    }
  }
  __syncthreads();

  const f32x4 z4 = { 0.f, 0.f, 0.f, 0.f };
  const int trow = wid*16 + lrow;                 // A-frag row (t in [0,64))

  // ---- phase 1a: S = q k^T (split-bf16), weight+mask -> att (bf16) ----
  f32x4 sacc[8];
  #pragma unroll
  for (int n = 0; n < 8; ++n) sacc[n] = z4;
  #pragma unroll
  for (int kk = 0; kk < 2; ++kk) {
    int qb = kk*64 + lkB;
    int ab = (trow*128 + qb) ^ ((trow & 7) << 4);
    short8v aqh = *(const short8v*)(smem + QH + ab);
    short8v aql = *(const short8v*)(smem + QL + ab);
    #pragma unroll
    for (int n = 0; n < 8; ++n) {
      int srw = n*16 + lrow;
      int bb = (srw*128 + qb) ^ ((srw & 7) << 4);
      short8v bkh = *(const short8v*)(smem + KH + bb);
      short8v bkl = *(const short8v*)(smem + KL + bb);
      sacc[n] = MFMA_BF16(aqh, bkh, sacc[n]);
      sacc[n] = MFMA_BF16(aql, bkh, sacc[n]);
      sacc[n] = MFMA_BF16(aqh, bkl, sacc[n]);
    }
  }
  {
    int td[4]; float gt[4];
    #pragma unroll
    for (int r = 0; r < 4; ++r) {
      td[r] = wid*16 + ((lane >> 4) << 2) + r;    // t in [0,64)
      gt[r] = Gsh[half*64 + td[r]];
    }
    #pragma unroll
    for (int n = 0; n < 8; ++n) {
      int s = n*16 + lrow;
      float gs = gsh[s];
      #pragma unroll
      for (int r = 0; r < 4; ++r) {
        float w = 0.125f * expf(gs - gt[r]);
        float val = (s <= half*64 + td[r]) ? sacc[n][r]*w : 0.f;
        int off = (td[r]*256 + s*2) ^ ((td[r] & 7) << 4);
        *(unsigned short*)(smem + ATT + off) = f2bf(val);
      }
    }
  }

  // ---- phase 1b: state term h2 = q * Cbef (split-bf16) ----
  f32x4 h2[8];
  #pragma unroll
  for (int n = 0; n < 8; ++n) h2[n] = z4;
  #pragma unroll
  for (int kk = 0; kk < 2; ++kk) {
    int qb = kk*64 + lkB;
    int ab = (trow*128 + qb) ^ ((trow & 7) << 4);
    short8v aqh = *(const short8v*)(smem + QH + ab);
    short8v aql = *(const short8v*)(smem + QL + ab);
    #pragma unroll
    for (int n = 0; n < 8; ++n) {
      int jrw = n*16 + lrow;
      int bb = (jrw*128 + qb) ^ ((jrw & 7) << 4);
      short8v bch = *(const short8v*)(smem + CBH + bb);
      short8v bcl = *(const short8v*)(smem + CBL + bb);
      h2[n] = MFMA_BF16(aqh, bch, h2[n]);
      h2[n] = MFMA_BF16(aql, bch, h2[n]);
      h2[n] = MFMA_BF16(aqh, bcl, h2[n]);
    }
  }
  __syncthreads();   // att fully written

  // ---- phase 2: PV: h1 = att * V ----
  f32x4 h1[8];
  #pragma unroll
  for (int n = 0; n < 8; ++n) h1[n] = z4;
  #pragma unroll
  for (int kk = 0; kk < 4; ++kk) {
    int ab = (trow*256 + kk*64 + lkB) ^ ((trow & 7) << 4);
    short8v aat = *(const short8v*)(smem + ATT + ab);
    #pragma unroll
    for (int n = 0; n < 8; ++n) {
      int jrw = n*16 + lrow;
      int bb = (jrw*256 + kk*64 + lkB) ^ ((jrw & 7) << 4);
      short8v bvt = *(const short8v*)(smem + VT + bb);
      h1[n] = MFMA_BF16(aat, bvt, h1[n]);
    }
  }
  __syncthreads();   // q/k LDS dead -> reuse as H buffer

  // ---- phase 3: combine, stage H in LDS, epilogue ----
  float* Hb = (float*)smem;           // [64][132] fp32 = 33.8 KB (aliases QH..KL)
  {
    #pragma unroll
    for (int r = 0; r < 4; ++r) {
      int tl = wid*16 + ((lane >> 4) << 2) + r;
      float rr = rsh[half*64 + tl];
      #pragma unroll
      for (int n = 0; n < 8; ++n)
        Hb[tl*132 + n*16 + lrow] = h1[n][r] + rr*h2[n][r];
    }
  }
  __syncthreads();

  const int tr = tid >> 4, tc = tid & 15;
  float lw[8], lb[8];
  {
    float4 a0 = *(const float4*)(lnw + h*NB_DH + tc*4);
    float4 a1 = *(const float4*)(lnw + h*NB_DH + tc*4 + 64);
    lw[0]=a0.x; lw[1]=a0.y; lw[2]=a0.z; lw[3]=a0.w;
    lw[4]=a1.x; lw[5]=a1.y; lw[6]=a1.z; lw[7]=a1.w;
    float4 b0 = *(const float4*)(lnb + h*NB_DH + tc*4);
    float4 b1 = *(const float4*)(lnb + h*NB_DH + tc*4 + 64);
    lb[0]=b0.x; lb[1]=b0.y; lb[2]=b0.z; lb[3]=b0.w;
    lb[4]=b1.x; lb[5]=b1.y; lb[6]=b1.z; lb[7]=b1.w;
  }
  #pragma unroll
  for (int u = 0; u < 4; ++u) {
    int tl = tr*4 + u;                 // 0..63
    int t  = half*64 + tl;             // chunk pos
    float hrow[8];
    float4 hl0 = *(const float4*)(&Hb[tl*132 + tc*4]);
    float4 hl1 = *(const float4*)(&Hb[tl*132 + tc*4 + 64]);
    hrow[0]=hl0.x; hrow[1]=hl0.y; hrow[2]=hl0.z; hrow[3]=hl0.w;
    hrow[4]=hl1.x; hrow[5]=hl1.y; hrow[6]=hl1.z; hrow[7]=hl1.w;
    float sum = 0.f, ssq = 0.f;
    #pragma unroll
    for (int x = 0; x < 8; ++x) { sum += hrow[x]; ssq += hrow[x]*hrow[x]; }
    #pragma unroll
    for (int off = 1; off < 16; off <<= 1) {
      sum += __shfl_xor(sum, off);
      ssq += __shfl_xor(ssq, off);
    }
    float mean = sum * (1.f/NB_DH);
    float var  = ssq * (1.f/NB_DH) - mean*mean;
    float rstd = rsqrtf(var + 1e-6f);
    #pragma unroll
    for (int m = 0; m < 2; ++m) {
      float4 xo = *(const float4*)(Pvx + (rowbase + t)*2048 + 1024 + h*NB_DH + tc*4 + m*64);
      float xov[4] = { xo.x, xo.y, xo.z, xo.w };
      unsigned short res[4];
      #pragma unroll
      for (int w = 0; w < 4; ++w) {
        int x = m*4 + w;
        float hn = (hrow[x] - mean)*rstd*lw[x] + lb[x];
        float tt = tanhf(xov[w]*(1.f/15.f))*15.f;
        float o = 1.f/(1.f + expf(-tt));
        res[w] = f2bf(hn*o);
      }
      ushort4v r4 = { res[0], res[1], res[2], res[3] };
      *(ushort4v*)(hng + (rowbase + t)*1024 + h*NB_DH + tc*4 + m*64) = r4;
    }
  }
}

extern "C" void kernel_launch(void* const* d_in, const int* in_sizes, int n_in,
                              void* d_out, int out_size, void* d_ws, size_t ws_size,
                              hipStream_t stream)
{
  (void)in_sizes; (void)n_in; (void)out_size; (void)ws_size;
  const float* x   = (const float*)d_in[0];
  const float* Wq  = (const float*)d_in[1];
  const float* Wk  = (const float*)d_in[2];
  const float* Wv  = (const float*)d_in[3];
  const float* Wi  = (const float*)d_in[4];
  const float* bi  = (const float*)d_in[5];
  const float* Wf  = (const float*)d_in[6];
  const float* bf  = (const float*)d_in[7];
  const float* Wog = (const float*)d_in[8];
  const float* lnw = (const float*)d_in[9];
  const float* lnb = (const float*)d_in[10];
  const float* Wout= (const float*)d_in[11];
  float* out = (float*)d_out;
  float* ws  = (float*)d_ws;

  float*          Pqk = ws + OFF_PQK;
  float*          Pvx = ws + OFF_PVX;
  unsigned short* xh  = (unsigned short*)(ws + OFF_XH);
  unsigned short* xl  = (unsigned short*)(ws + OFF_XL);
  unsigned short* Whi = (unsigned short*)(ws + OFF_WHI);
  unsigned short* Wlo = (unsigned short*)(ws + OFF_WLO);
  unsigned short* WtO = (unsigned short*)(ws + OFF_WTO);   // alias of Wlo (after proj)
  float*          iv  = ws + OFF_IV;
  float*          fv  = ws + OFF_FV;
  float*          g   = ws + OFF_G;
  float*          G   = ws + OFF_GM;
  float*          Dl  = ws + OFF_DL;                        // alias of xh
  float*          Cb  = ws + OFF_CB;                        // alias of Whi
  unsigned short* hng = (unsigned short*)(ws + OFF_HNG);    // alias of xl

  conv_split<<<1024, 256, 0, stream>>>(x, xh, xl, 2048*1024);
  transp4   <<<dim3(48,16), 256, 0, stream>>>(Wq, Wk, Wv, Wog, Whi, Wlo);

  proj_if  <<<2048, 64, 0, stream>>>(x, Wi, bi, Wf, bf, iv, fv);
  gate_scan<<<16, 64, 0, stream>>>(iv, fv, g, G);

  // balanced fused projection (in-block split-bf16 accumulation, no atomics)
  gemm_proj<<<512, 256, 0, stream>>>(xh, xl, Whi, Wlo, Pqk, Pvx);

  // Wout transpose reuses Wlo space (gemm_proj already consumed it)
  transp_hl<<<dim3(16,16), 256, 0, stream>>>(Wout, WtO, 1024);

  chunk_local  <<<128, 128, 0, stream>>>(Pqk, Pvx, g, G, Dl);
  chunk_combine<<<16, 256, 0, stream>>>(Dl, G, Cb);
  chunk_out    <<<256, 256, 0, stream>>>(Pqk, Pvx, g, G, Cb, lnw, lnb, hng);

  // out = hng[2048x1024] x Wout[1024x1024]
  gemm_out64<<<dim3(16,16), 256, 0, stream>>>(hng, WtO, out, 1024);
}

// Round 10
// 135.064 us; speedup vs baseline: 1.3416x; 1.1032x over previous
//
#include <hip/hip_runtime.h>
#include <math.h>

#define NB_B   2
#define NB_S   1024
#define NB_D   1024
#define NB_NH  8
#define NB_DQK 64
#define NB_DH  128
#define NCH    8
#define CL     128

typedef __attribute__((ext_vector_type(8))) short  short8v;   // 8 x bf16
typedef __attribute__((ext_vector_type(4))) float  f32x4;
typedef __attribute__((ext_vector_type(8))) unsigned short ushort8v;
typedef __attribute__((ext_vector_type(4))) unsigned short ushort4v;

__device__ __forceinline__ unsigned short f2bf(float f) {
  unsigned u = __float_as_uint(f);
  unsigned r = (u + 0x7FFFu + ((u >> 16) & 1u)) >> 16;
  return (unsigned short)r;
}
__device__ __forceinline__ float bf2f(unsigned short h) {
  return __uint_as_float(((unsigned)h) << 16);
}

#define GLD_LDS16(g, l) __builtin_amdgcn_global_load_lds( \
    (const __attribute__((address_space(1))) void*)(g),   \
    (__attribute__((address_space(3))) void*)(l), 16, 0, 0)

#define MFMA_BF16(a, b, c) __builtin_amdgcn_mfma_f32_16x16x32_bf16((a), (b), (c), 0, 0, 0)

// ---------------- workspace map (units: FLOAT SLOTS) ----------------
// BF(n): n bf16 elements occupy n/2 float slots. Every offset derived, never
// hand-computed (round-3/round-9 bug class: elems vs slots confusion).
constexpr size_t BF(size_t elems) { return elems / 2; }
constexpr size_t SZ_PQK = 2048ull * 1024;          // fp32 [2048][1024]
constexpr size_t SZ_PVX = BF(2048ull * 2048);      // bf16 [2048][2048] -> 2,097,152 slots
constexpr size_t SZ_XH  = BF(2048ull * 1024);
constexpr size_t SZ_XL  = BF(2048ull * 1024);
constexpr size_t SZ_WHI = BF(3072ull * 1024);
constexpr size_t SZ_WLO = BF(1024ull * 1024);
constexpr size_t SZ_WTO = BF(1024ull * 1024);
constexpr size_t SZ_GBUF= 16ull * 1024;            // fp32 [16][1024]
constexpr size_t SZ_DL  = 16ull * 8 * 8192;        // fp32
constexpr size_t SZ_CB  = 16ull * 8 * 8192;        // fp32
constexpr size_t SZ_HNG = BF(2048ull * 1024);

constexpr size_t OFF_PQK = 0;
constexpr size_t OFF_PVX = OFF_PQK + SZ_PQK;
constexpr size_t OFF_XH  = OFF_PVX + SZ_PVX;
constexpr size_t OFF_XL  = OFF_XH  + SZ_XH;
constexpr size_t OFF_WHI = OFF_XL  + SZ_XL;
constexpr size_t OFF_WLO = OFF_WHI + SZ_WHI;
constexpr size_t OFF_WTO = OFF_WLO + SZ_WLO;
constexpr size_t OFF_IV  = OFF_WTO + SZ_WTO;
constexpr size_t OFF_FV  = OFF_IV  + SZ_GBUF;
constexpr size_t OFF_G   = OFF_FV  + SZ_GBUF;
constexpr size_t OFF_GM  = OFF_G   + SZ_GBUF;
constexpr size_t OFF_DL  = OFF_GM  + SZ_GBUF;
constexpr size_t OFF_CB  = OFF_DL  + SZ_DL;
constexpr size_t OFF_HNG = OFF_CB  + SZ_CB;
constexpr size_t WS_TOTAL = OFF_HNG + SZ_HNG;      // 12,124,160 floats = 48.5 MB
static_assert(OFF_XH == OFF_PVX + 2097152, "Pvx is 2048x2048 bf16 = 2,097,152 float slots");

// ---------------- fused per-row: x->(hi,lo) bf16 + i/f projections ----------------
__global__ __launch_bounds__(64) void row_pre(
    const float* __restrict__ x,
    const float* __restrict__ Wi, const float* __restrict__ bi,
    const float* __restrict__ Wf, const float* __restrict__ bf,
    unsigned short* __restrict__ xh, unsigned short* __restrict__ xl,
    float* __restrict__ iv, float* __restrict__ fv)
{
  const int row = blockIdx.x, l = threadIdx.x;
  const float4* xr4 = (const float4*)(x + (size_t)row * NB_D);
  float ai[8] = {}, af[8] = {};
  #pragma unroll
  for (int p = 0; p < 4; ++p) {
    int q4i = l + p * 64;
    float4 xv = xr4[q4i];
    int k0 = q4i * 4;
    const float* xs = (const float*)&xv;
    ushort4v h4, l4;
    #pragma unroll
    for (int j = 0; j < 4; ++j) {
      float xsv = xs[j];
      unsigned short hh = f2bf(xsv);
      h4[j] = hh; l4[j] = f2bf(xsv - bf2f(hh));
      const float4* wi4 = (const float4*)(Wi + (size_t)(k0 + j) * 8);
      const float4* wf4 = (const float4*)(Wf + (size_t)(k0 + j) * 8);
      float4 w0 = wi4[0], w1 = wi4[1];
      float4 v0 = wf4[0], v1 = wf4[1];
      ai[0] += xsv*w0.x; ai[1] += xsv*w0.y; ai[2] += xsv*w0.z; ai[3] += xsv*w0.w;
      ai[4] += xsv*w1.x; ai[5] += xsv*w1.y; ai[6] += xsv*w1.z; ai[7] += xsv*w1.w;
      af[0] += xsv*v0.x; af[1] += xsv*v0.y; af[2] += xsv*v0.z; af[3] += xsv*v0.w;
      af[4] += xsv*v1.x; af[5] += xsv*v1.y; af[6] += xsv*v1.z; af[7] += xsv*v1.w;
    }
    *(ushort4v*)(xh + (size_t)row * NB_D + k0) = h4;
    *(ushort4v*)(xl + (size_t)row * NB_D + k0) = l4;
  }
  #pragma unroll
  for (int off = 1; off < 64; off <<= 1) {
    #pragma unroll
    for (int cc = 0; cc < 8; ++cc) {
      ai[cc] += __shfl_xor(ai[cc], off);
      af[cc] += __shfl_xor(af[cc], off);
    }
  }
  if (l == 0) {
    int b = row >> 10, s = row & (NB_S - 1);
    #pragma unroll
    for (int cc = 0; cc < 8; ++cc) {
      iv[(size_t)(b*NB_NH + cc) * NB_S + s] = ai[cc] + bi[cc];
      fv[(size_t)(b*NB_NH + cc) * NB_S + s] = af[cc] + bf[cc];
    }
  }
}

// ---------------- transpose + convert core ----------------
__device__ __forceinline__ void transp_body(
    const float* __restrict__ src,
    unsigned short* __restrict__ hi, unsigned short* __restrict__ lo,
    int N, int nt, int kt, int tid, float (*Ls)[65])
{
  #pragma unroll
  for (int p = 0; p < 16; ++p) {
    int lin = p * 256 + tid;
    int kr = lin >> 6, nc = lin & 63;
    Ls[kr][nc] = src[(size_t)(kt*64 + kr) * N + nt*64 + nc];
  }
  __syncthreads();
  #pragma unroll
  for (int p = 0; p < 16; ++p) {
    int lin = p * 256 + tid;
    int nr = lin >> 6, kc = lin & 63;
    float v = Ls[kc][nr];
    unsigned short h = f2bf(v);
    size_t di = (size_t)(nt*64 + nr) * 1024 + kt*64 + kc;
    hi[di] = h;
    if (lo) lo[di] = f2bf(v - bf2f(h));
  }
}

// merged transpose of Wq,Wk,Wv,Wog,Wout (grid.x = 8+8+16+16+16 = 64)
__global__ __launch_bounds__(256) void transp5(
    const float* __restrict__ Wq, const float* __restrict__ Wk,
    const float* __restrict__ Wv, const float* __restrict__ Wog,
    const float* __restrict__ Wout,
    unsigned short* __restrict__ Whi, unsigned short* __restrict__ Wlo,
    unsigned short* __restrict__ WtO)
{
  __shared__ float Ls[64][65];
  const int x = blockIdx.x, kt = blockIdx.y, tid = threadIdx.x;
  if (x < 8)       transp_body(Wq,   Whi,              Wlo,            512,  x,      kt, tid, Ls);
  else if (x < 16) transp_body(Wk,   Whi +  512*1024,  Wlo + 512*1024, 512,  x - 8,  kt, tid, Ls);
  else if (x < 32) transp_body(Wv,   Whi + 1024*1024,  nullptr,        1024, x - 16, kt, tid, Ls);
  else if (x < 48) transp_body(Wog,  Whi + 2048*1024,  nullptr,        1024, x - 32, kt, tid, Ls);
  else             transp_body(Wout, WtO,              nullptr,        1024, x - 48, kt, tid, Ls);
}

// ---------------- fused projection GEMM, balanced heavy/light blocks ----------------
// 512 blocks, XCD-swizzled then parity-decoded:
//  even bid -> HEAVY (q,k, split-bf16, M=64) -> Pqk fp32
//  odd  bid -> LIGHT (v,xog, plain bf16, M=128) -> Pvx bf16
__global__ __launch_bounds__(256) void gemm_proj(
    const unsigned short* __restrict__ xh,
    const unsigned short* __restrict__ xl,
    const unsigned short* __restrict__ Whi,
    const unsigned short* __restrict__ Wlo,
    float* __restrict__ Pqk, unsigned short* __restrict__ Pvx)
{
  __shared__ __align__(16) char smem[49152];
  const int tid  = threadIdx.x;
  const int bid  = ((blockIdx.x & 7) << 6) | (blockIdx.x >> 3);   // XCD swizzle (512 = 8*64)
  const int wid  = tid >> 6, lane = tid & 63;
  const int wm   = wid >> 1, wn = wid & 1;
  const int lrow = lane & 15;
  const int lk   = (lane >> 4) * 16;
  const int srow = tid >> 3;
  const int scb  = (tid & 7) << 4;
  const int ldsW = wid * 1024;

  if (!(bid & 1)) {
    // HEAVY: q,k with split-bf16, M=64
    const int h  = bid >> 1;
    const int ct = h & 7, bm = h >> 3;
    char* Ah = smem;
    char* Al = smem + 8192;
    char* Bh = smem + 16384;
    char* Bl = smem + 32768;
    const char* xhB = (const char*)xh;
    const char* xlB = (const char*)xl;
    const char* whB = (const char*)(Whi + (size_t)ct*128*1024);
    const char* wlB = (const char*)(Wlo + (size_t)ct*128*1024);

    size_t gA[2], gB[4];
    #pragma unroll
    for (int i = 0; i < 2; ++i) {
      int row = i * 32 + srow;
      int cbs = scb ^ ((row & 7) << 4);
      gA[i] = (size_t)(bm*64 + row) * 2048 + cbs;
    }
    #pragma unroll
    for (int i = 0; i < 4; ++i) {
      int row = i * 32 + srow;
      int cbs = scb ^ ((row & 7) << 4);
      gB[i] = (size_t)row * 2048 + cbs;
    }

    f32x4 acc[2][4];
    const f32x4 z4 = { 0.f, 0.f, 0.f, 0.f };
    #pragma unroll
    for (int m = 0; m < 2; ++m)
      #pragma unroll
      for (int n = 0; n < 4; ++n) acc[m][n] = z4;

    for (int kt = 0; kt < 16; ++kt) {
      __syncthreads();
      #pragma unroll
      for (int i = 0; i < 2; ++i) GLD_LDS16(xhB + gA[i] + kt*128, Ah + i*4096 + ldsW);
      #pragma unroll
      for (int i = 0; i < 2; ++i) GLD_LDS16(xlB + gA[i] + kt*128, Al + i*4096 + ldsW);
      #pragma unroll
      for (int i = 0; i < 4; ++i) GLD_LDS16(whB + gB[i] + kt*128, Bh + i*4096 + ldsW);
      #pragma unroll
      for (int i = 0; i < 4; ++i) GLD_LDS16(wlB + gB[i] + kt*128, Bl + i*4096 + ldsW);
      __syncthreads();

      #pragma unroll
      for (int kk = 0; kk < 2; ++kk) {
        short8v ah[2], al[2], bh[4], bl[4];
        #pragma unroll
        for (int m = 0; m < 2; ++m) {
          int row = wm*32 + m*16 + lrow;
          int kb  = (kk*64 + lk) ^ ((row & 7) << 4);
          ah[m] = *(const short8v*)(Ah + row*128 + kb);
          al[m] = *(const short8v*)(Al + row*128 + kb);
        }
        #pragma unroll
        for (int n = 0; n < 4; ++n) {
          int row = wn*64 + n*16 + lrow;
          int kb  = (kk*64 + lk) ^ ((row & 7) << 4);
          bh[n] = *(const short8v*)(Bh + row*128 + kb);
          bl[n] = *(const short8v*)(Bl + row*128 + kb);
        }
        #pragma unroll
        for (int m = 0; m < 2; ++m)
          #pragma unroll
          for (int n = 0; n < 4; ++n) {
            acc[m][n] = MFMA_BF16(ah[m], bh[n], acc[m][n]);
            acc[m][n] = MFMA_BF16(al[m], bh[n], acc[m][n]);
            acc[m][n] = MFMA_BF16(ah[m], bl[n], acc[m][n]);
          }
      }
    }

    const int crow0 = bm*64 + wm*32 + ((lane >> 4) << 2);
    const int ccol0 = ct*128 + wn*64 + lrow;
    #pragma unroll
    for (int m = 0; m < 2; ++m)
      #pragma unroll
      for (int n = 0; n < 4; ++n)
        #pragma unroll
        for (int r = 0; r < 4; ++r)
          Pqk[(size_t)(crow0 + m*16 + r) * 1024 + ccol0 + n*16] = acc[m][n][r];
  } else {
    // LIGHT: v,xog plain bf16, M=128 -> Pvx bf16
    const int l  = bid >> 1;
    const int ct = l & 15, bm = l >> 4;
    char* As = smem;
    char* Bs = smem + 16384;
    const char* xhB = (const char*)xh;
    const char* wB  = (const char*)(Whi + (size_t)(8 + ct)*128*1024);

    size_t gA[4], gB[4];
    #pragma unroll
    for (int i = 0; i < 4; ++i) {
      int row = i * 32 + srow;
      int cbs = scb ^ ((row & 7) << 4);
      gA[i] = (size_t)(bm*128 + row) * 2048 + cbs;
      gB[i] = (size_t)row * 2048 + cbs;
    }

    f32x4 acc[4][4];
    const f32x4 z4 = { 0.f, 0.f, 0.f, 0.f };
    #pragma unroll
    for (int m = 0; m < 4; ++m)
      #pragma unroll
      for (int n = 0; n < 4; ++n) acc[m][n] = z4;

    for (int kt = 0; kt < 16; ++kt) {
      __syncthreads();
      #pragma unroll
      for (int i = 0; i < 4; ++i) GLD_LDS16(xhB + gA[i] + kt*128, As + i*4096 + ldsW);
      #pragma unroll
      for (int i = 0; i < 4; ++i) GLD_LDS16(wB  + gB[i] + kt*128, Bs + i*4096 + ldsW);
      __syncthreads();

      #pragma unroll
      for (int kk = 0; kk < 2; ++kk) {
        short8v a[4], b[4];
        #pragma unroll
        for (int m = 0; m < 4; ++m) {
          int row = wm*64 + m*16 + lrow;
          int kb  = (kk*64 + lk) ^ ((row & 7) << 4);
          a[m] = *(const short8v*)(As + row*128 + kb);
        }
        #pragma unroll
        for (int n = 0; n < 4; ++n) {
          int row = wn*64 + n*16 + lrow;
          int kb  = (kk*64 + lk) ^ ((row & 7) << 4);
          b[n] = *(const short8v*)(Bs + row*128 + kb);
        }
        #pragma unroll
        for (int m = 0; m < 4; ++m)
          #pragma unroll
          for (int n = 0; n < 4; ++n)
            acc[m][n] = MFMA_BF16(a[m], b[n], acc[m][n]);
      }
    }

    const int crow0 = bm*128 + wm*64 + ((lane >> 4) << 2);
    const int ccol0 = ct*128 + wn*64 + lrow;
    #pragma unroll
    for (int m = 0; m < 4; ++m)
      #pragma unroll
      for (int n = 0; n < 4; ++n)
        #pragma unroll
        for (int r = 0; r < 4; ++r)
          Pvx[(size_t)(crow0 + m*16 + r) * 2048 + ccol0 + n*16] = f2bf(acc[m][n][r]);
  }
}

// ---------------- output GEMM: 128x64 tiles, XCD-swizzled 1-D grid (256) ----------------
__global__ __launch_bounds__(256) void gemm_out64(
    const unsigned short* __restrict__ A,
    const unsigned short* __restrict__ Bt,
    float* __restrict__ C, int ldc)
{
  __shared__ __align__(16) unsigned short As[128*64];
  __shared__ __align__(16) unsigned short Bs[64*64];
  const int tid  = threadIdx.x;
  const int bid  = ((blockIdx.x & 7) << 5) | (blockIdx.x >> 3);   // 256 = 8*32
  const int cn   = bid & 15, bm = bid >> 4;
  const int wid  = tid >> 6, lane = tid & 63;
  const int wm   = wid >> 1, wn = wid & 1;
  const int lrow = lane & 15;
  const int lk   = (lane >> 4) * 16;

  f32x4 acc[4][2];
  const f32x4 z4 = { 0.f, 0.f, 0.f, 0.f };
  #pragma unroll
  for (int m = 0; m < 4; ++m)
    #pragma unroll
    for (int n = 0; n < 2; ++n) acc[m][n] = z4;

  const int srow = tid >> 3;
  const int scb  = (tid & 7) << 4;
  const char* Ab = (const char*)A;
  const char* Bb = (const char*)Bt;
  size_t gA[4], gB[2];
  #pragma unroll
  for (int i = 0; i < 4; ++i) {
    int row = i * 32 + srow;
    int cbs = scb ^ ((row & 7) << 4);
    gA[i] = (size_t)(bm*128 + row) * 2048 + cbs;
  }
  #pragma unroll
  for (int i = 0; i < 2; ++i) {
    int row = i * 32 + srow;
    int cbs = scb ^ ((row & 7) << 4);
    gB[i] = (size_t)(cn*64 + row) * 2048 + cbs;
  }
  const int ldsW = wid * 1024;

  for (int kt = 0; kt < 16; ++kt) {
    __syncthreads();
    #pragma unroll
    for (int i = 0; i < 4; ++i)
      GLD_LDS16(Ab + gA[i] + kt*128, (char*)As + i*4096 + ldsW);
    #pragma unroll
    for (int i = 0; i < 2; ++i)
      GLD_LDS16(Bb + gB[i] + kt*128, (char*)Bs + i*4096 + ldsW);
    __syncthreads();

    #pragma unroll
    for (int kk = 0; kk < 2; ++kk) {
      short8v a[4], b[2];
      #pragma unroll
      for (int m = 0; m < 4; ++m) {
        int row = wm*64 + m*16 + lrow;
        int kb  = (kk*64 + lk) ^ ((row & 7) << 4);
        a[m] = *(const short8v*)((const char*)As + row*128 + kb);
      }
      #pragma unroll
      for (int n = 0; n < 2; ++n) {
        int row = wn*32 + n*16 + lrow;
        int kb  = (kk*64 + lk) ^ ((row & 7) << 4);
        b[n] = *(const short8v*)((const char*)Bs + row*128 + kb);
      }
      #pragma unroll
      for (int m = 0; m < 4; ++m)
        #pragma unroll
        for (int n = 0; n < 2; ++n)
          acc[m][n] = MFMA_BF16(a[m], b[n], acc[m][n]);
    }
  }

  const int crow0 = bm*128 + wm*64 + ((lane >> 4) << 2);
  const int ccol0 = cn*64 + wn*32 + (lane & 15);
  #pragma unroll
  for (int m = 0; m < 4; ++m)
    #pragma unroll
    for (int n = 0; n < 2; ++n)
      #pragma unroll
      for (int r = 0; r < 4; ++r)
        C[(size_t)(crow0 + m*16 + r) * ldc + ccol0 + n*16] = acc[m][n][r];
}

// ---------------- gate scan ----------------
__global__ __launch_bounds__(64) void gate_scan(
    const float* __restrict__ iv, const float* __restrict__ fv,
    float* __restrict__ gv, float* __restrict__ Gv)
{
  const int bh = blockIdx.x, l = threadIdx.x;
  const int base = bh * NB_S + l * 16;
  float fl[16];
  float run = 0.f;
  #pragma unroll
  for (int u = 0; u < 16; ++u) {
    float fr = fv[base + u];
    float flog = (fr >= 0.f) ? -log1pf(expf(-fr)) : (fr - log1pf(expf(fr)));
    run += flog; fl[u] = run;
  }
  float tot = run, sc = tot;
  #pragma unroll
  for (int off = 1; off < 64; off <<= 1) {
    float t = __shfl_up(sc, off);
    if (l >= off) sc += t;
  }
  float excl = sc - tot;
  float gm[16]; float rmax = -1e30f;
  #pragma unroll
  for (int u = 0; u < 16; ++u) {
    float bt = excl + fl[u];
    float g = iv[base + u] - bt;
    gv[base + u] = g;
    rmax = fmaxf(rmax, g); gm[u] = rmax;
  }
  float mx = rmax;
  #pragma unroll
  for (int off = 1; off < 64; off <<= 1) {
    float t = __shfl_up(mx, off);
    if (l >= off) mx = fmaxf(mx, t);
  }
  float em = __shfl_up(mx, 1);
  if (l == 0) em = -1e30f;
  #pragma unroll
  for (int u = 0; u < 16; ++u)
    Gv[base + u] = fmaxf(0.f, fmaxf(em, gm[u]));
}

// ---------------- per-chunk local KV state (v bf16) ----------------
__global__ __launch_bounds__(128) void chunk_local(
    const float* __restrict__ Pqk, const unsigned short* __restrict__ Pvx,
    const float* __restrict__ gv, const float* __restrict__ Gv,
    float* __restrict__ Dloc)
{
  __shared__ float ks[16][68];
  __shared__ float vs[16][132];
  __shared__ float wsg[16];
  const int bx = blockIdx.x, bh = bx >> 3, c = bx & 7;
  const int b = bh >> 3, h = bh & 7;
  const int tid = threadIdx.x;
  const int rg = tid >> 3, cg = tid & 7;
  const int i0 = rg * 4;
  float acc[4][16] = {};
  const float Gend = Gv[bh*NB_S + c*CL + CL - 1];
  const float* kbp = Pqk + ((size_t)b*NB_S + c*CL) * 1024 + 512 + h*NB_DQK;
  const unsigned short* vbp = Pvx + ((size_t)b*NB_S + c*CL) * 2048 + h*NB_DH;
  const float* gbp = gv + bh*NB_S + c*CL;
  for (int sb = 0; sb < 8; ++sb) {
    __syncthreads();
    #pragma unroll
    for (int p = 0; p < 2; ++p) {
      int qd = tid + p*128; int r = qd >> 4, cq = qd & 15;
      *(float4*)(&ks[r][cq*4]) = *(const float4*)(kbp + (size_t)(sb*16 + r)*1024 + cq*4);
    }
    #pragma unroll
    for (int p = 0; p < 4; ++p) {
      int qd = tid + p*128; int r = qd >> 5, cq = qd & 31;
      ushort4v v4 = *(const ushort4v*)(vbp + (size_t)(sb*16 + r)*2048 + cq*4);
      vs[r][cq*4+0] = bf2f(v4[0]); vs[r][cq*4+1] = bf2f(v4[1]);
      vs[r][cq*4+2] = bf2f(v4[2]); vs[r][cq*4+3] = bf2f(v4[3]);
    }
    if (tid < 16) wsg[tid] = expf(gbp[sb*16 + tid] - Gend);
    __syncthreads();
    #pragma unroll
    for (int s = 0; s < 16; ++s) {
      float w = wsg[s];
      float4 kq = *(const float4*)(&ks[s][i0]);
      float wk[4] = { w*kq.x, w*kq.y, w*kq.z, w*kq.w };
      #pragma unroll
      for (int m = 0; m < 4; ++m) {
        float4 vq = *(const float4*)(&vs[s][cg*4 + m*32]);
        #pragma unroll
        for (int u = 0; u < 4; ++u) {
          acc[u][m*4+0] += wk[u]*vq.x;
          acc[u][m*4+1] += wk[u]*vq.y;
          acc[u][m*4+2] += wk[u]*vq.z;
          acc[u][m*4+3] += wk[u]*vq.w;
        }
      }
    }
  }
  float* dst = Dloc + ((size_t)bh*NCH + c) * (NB_DQK*NB_DH);
  #pragma unroll
  for (int u = 0; u < 4; ++u)
    #pragma unroll
    for (int m = 0; m < 4; ++m) {
      float4 o4 = { acc[u][m*4+0], acc[u][m*4+1], acc[u][m*4+2], acc[u][m*4+3] };
      *(float4*)(dst + (size_t)(i0+u)*NB_DH + cg*4 + m*32) = o4;
    }
}

// ---------------- chunk-state combine: 128 blocks (bh x 8 slices) ----------------
__global__ __launch_bounds__(256) void chunk_combine(
    const float* __restrict__ Dloc, const float* __restrict__ Gv,
    float* __restrict__ Cbef)
{
  const int bh = blockIdx.x >> 3, sl = blockIdx.x & 7;
  const int fo = sl*1024 + threadIdx.x*4;
  float4 acc = { 0.f, 0.f, 0.f, 0.f };
  float Gprev = 0.f;
  for (int c = 0; c < NCH; ++c) {
    const float* dl = Dloc + ((size_t)bh*NCH + c)*8192 + fo;
    float* cb = Cbef + ((size_t)bh*NCH + c)*8192 + fo;
    float Gend = Gv[bh*NB_S + c*CL + CL - 1];
    float decay = (c == 0) ? 0.f : expf(Gprev - Gend);
    *(float4*)cb = acc;
    float4 d = *(const float4*)dl;
    acc.x = acc.x*decay + d.x;
    acc.y = acc.y*decay + d.y;
    acc.z = acc.z*decay + d.z;
    acc.w = acc.w*decay + d.w;
    Gprev = Gend;
  }
}

// ---------------- chunked attention via MFMA + LN + gate -> hng (bf16) ----------------
// grid 256 (XCD-swizzled): bh(16) x c(8) x half(2); block = 64 t-rows, 4 waves.
__global__ __launch_bounds__(256,1) void chunk_out(
    const float* __restrict__ Pqk, const unsigned short* __restrict__ Pvx,
    const float* __restrict__ gv, const float* __restrict__ Gv,
    const float* __restrict__ Cbef,
    const float* __restrict__ lnw, const float* __restrict__ lnb,
    unsigned short* __restrict__ hng)
{
  __shared__ __align__(16) char smem[131072];
  __shared__ float gsh[128], Gsh[128], rsh[128];
  constexpr int QH = 0, QL = 8192, KH = 16384, KL = 32768;
  constexpr int ATT = 49152, VT = 65536, CBH = 98304, CBL = 114688;

  const int bx = ((blockIdx.x & 7) << 5) | (blockIdx.x >> 3);   // 256 = 8*32
  const int half = bx & 1, c = (bx >> 1) & 7, bh = bx >> 4;
  const int b = bh >> 3, h = bh & 7;
  const int tid = threadIdx.x;
  const int wid = tid >> 6, lane = tid & 63;
  const int lrow = lane & 15;
  const int lkB  = (lane >> 4) * 16;
  const size_t rowbase = (size_t)b*NB_S + (size_t)c*CL;
  const int sgbase = bh*NB_S + c*CL;

  if (tid < 128) {
    float gval = gv[sgbase + tid];
    float Gval = Gv[sgbase + tid];
    gsh[tid] = gval; Gsh[tid] = Gval;
    float Gprev = (c > 0) ? Gv[sgbase - 1] : 0.f;
    rsh[tid] = 0.125f * expf(Gprev - Gval);
  }

  // ---- phase 0: convert operands into swizzled LDS ----
  #pragma unroll
  for (int p = 0; p < 4; ++p) {
    int lin = p*256 + tid;
    int row = lin >> 4, i0 = (lin & 15) * 4;
    float4 v4 = *(const float4*)(Pqk + (rowbase + half*64 + row)*1024 + h*NB_DQK + i0);
    float vv[4] = { v4.x, v4.y, v4.z, v4.w };
    ushort4v h4, l4;
    #pragma unroll
    for (int j = 0; j < 4; ++j) {
      unsigned short hh = f2bf(vv[j]); h4[j] = hh; l4[j] = f2bf(vv[j] - bf2f(hh));
    }
    int off = (row*128 + i0*2) ^ ((row & 7) << 4);
    *(ushort4v*)(smem + QH + off) = h4;
    *(ushort4v*)(smem + QL + off) = l4;
  }
  #pragma unroll
  for (int p = 0; p < 8; ++p) {
    int lin = p*256 + tid;
    int row = lin >> 4, i0 = (lin & 15) * 4;
    float4 v4 = *(const float4*)(Pqk + (rowbase + row)*1024 + 512 + h*NB_DQK + i0);
    float vv[4] = { v4.x, v4.y, v4.z, v4.w };
    ushort4v h4, l4;
    #pragma unroll
    for (int j = 0; j < 4; ++j) {
      unsigned short hh = f2bf(vv[j]); h4[j] = hh; l4[j] = f2bf(vv[j] - bf2f(hh));
    }
    int off = (row*128 + i0*2) ^ ((row & 7) << 4);
    *(ushort4v*)(smem + KH + off) = h4;
    *(ushort4v*)(smem + KL + off) = l4;
  }
  // V^T (bf16 source -> re-layout only)
  #pragma unroll
  for (int p = 0; p < 8; ++p) {
    int lin = p*256 + tid;
    int s = lin >> 4, j0 = (lin & 15) * 8;
    ushort8v v8 = *(const ushort8v*)(Pvx + (rowbase + s)*2048 + h*NB_DH + j0);
    #pragma unroll
    for (int j = 0; j < 8; ++j) {
      int jj = j0 + j;
      int off = (jj*256 + s*2) ^ ((jj & 7) << 4);
      *(unsigned short*)(smem + VT + off) = v8[j];
    }
  }
  // Cb^T hi/lo
  {
    const float* Cbp = Cbef + ((size_t)bh*NCH + c)*(NB_DQK*NB_DH);
    #pragma unroll
    for (int p = 0; p < 8; ++p) {
      int lin = p*256 + tid;
      int i = lin >> 5, j0 = (lin & 31) * 4;
      float4 v4 = *(const float4*)(Cbp + (size_t)i*NB_DH + j0);
      float vv[4] = { v4.x, v4.y, v4.z, v4.w };
      #pragma unroll
      for (int w = 0; w < 4; ++w) {
        int jj = j0 + w;
        int off = (jj*128 + i*2) ^ ((jj & 7) << 4);
        unsigned short hh = f2bf(vv[w]);
        *(unsigned short*)(smem + CBH + off) = hh;
        *(unsigned short*)(smem + CBL + off) = f2bf(vv[w] - bf2f(hh));
      }
    }
  }
  __syncthreads();

  const f32x4 z4 = { 0.f, 0.f, 0.f, 0.f };
  const int trow = wid*16 + lrow;

  // ---- phase 1a: S = q k^T (split-bf16), weight+mask -> att (bf16) ----
  f32x4 sacc[8];
  #pragma unroll
  for (int n = 0; n < 8; ++n) sacc[n] = z4;
  #pragma unroll
  for (int kk = 0; kk < 2; ++kk) {
    int qb = kk*64 + lkB;
    int ab = (trow*128 + qb) ^ ((trow & 7) << 4);
    short8v aqh = *(const short8v*)(smem + QH + ab);
    short8v aql = *(const short8v*)(smem + QL + ab);
    #pragma unroll
    for (int n = 0; n < 8; ++n) {
      int srw = n*16 + lrow;
      int bb = (srw*128 + qb) ^ ((srw & 7) << 4);
      short8v bkh = *(const short8v*)(smem + KH + bb);
      short8v bkl = *(const short8v*)(smem + KL + bb);
      sacc[n] = MFMA_BF16(aqh, bkh, sacc[n]);
      sacc[n] = MFMA_BF16(aql, bkh, sacc[n]);
      sacc[n] = MFMA_BF16(aqh, bkl, sacc[n]);
    }
  }
  {
    int td[4]; float gt[4];
    #pragma unroll
    for (int r = 0; r < 4; ++r) {
      td[r] = wid*16 + ((lane >> 4) << 2) + r;
      gt[r] = Gsh[half*64 + td[r]];
    }
    #pragma unroll
    for (int n = 0; n < 8; ++n) {
      int s = n*16 + lrow;
      float gs = gsh[s];
      #pragma unroll
      for (int r = 0; r < 4; ++r) {
        float w = 0.125f * expf(gs - gt[r]);
        float val = (s <= half*64 + td[r]) ? sacc[n][r]*w : 0.f;
        int off = (td[r]*256 + s*2) ^ ((td[r] & 7) << 4);
        *(unsigned short*)(smem + ATT + off) = f2bf(val);
      }
    }
  }

  // ---- phase 1b: state term h2 = q * Cbef (split-bf16) ----
  f32x4 h2[8];
  #pragma unroll
  for (int n = 0; n < 8; ++n) h2[n] = z4;
  #pragma unroll
  for (int kk = 0; kk < 2; ++kk) {
    int qb = kk*64 + lkB;
    int ab = (trow*128 + qb) ^ ((trow & 7) << 4);
    short8v aqh = *(const short8v*)(smem + QH + ab);
    short8v aql = *(const short8v*)(smem + QL + ab);
    #pragma unroll
    for (int n = 0; n < 8; ++n) {
      int jrw = n*16 + lrow;
      int bb = (jrw*128 + qb) ^ ((jrw & 7) << 4);
      short8v bch = *(const short8v*)(smem + CBH + bb);
      short8v bcl = *(const short8v*)(smem + CBL + bb);
      h2[n] = MFMA_BF16(aqh, bch, h2[n]);
      h2[n] = MFMA_BF16(aql, bch, h2[n]);
      h2[n] = MFMA_BF16(aqh, bcl, h2[n]);
    }
  }
  __syncthreads();

  // ---- phase 2: PV: h1 = att * V ----
  f32x4 h1[8];
  #pragma unroll
  for (int n = 0; n < 8; ++n) h1[n] = z4;
  #pragma unroll
  for (int kk = 0; kk < 4; ++kk) {
    int ab = (trow*256 + kk*64 + lkB) ^ ((trow & 7) << 4);
    short8v aat = *(const short8v*)(smem + ATT + ab);
    #pragma unroll
    for (int n = 0; n < 8; ++n) {
      int jrw = n*16 + lrow;
      int bb = (jrw*256 + kk*64 + lkB) ^ ((jrw & 7) << 4);
      short8v bvt = *(const short8v*)(smem + VT + bb);
      h1[n] = MFMA_BF16(aat, bvt, h1[n]);
    }
  }
  __syncthreads();

  // ---- phase 3: combine, stage H in LDS, epilogue ----
  float* Hb = (float*)smem;
  {
    #pragma unroll
    for (int r = 0; r < 4; ++r) {
      int tl = wid*16 + ((lane >> 4) << 2) + r;
      float rr = rsh[half*64 + tl];
      #pragma unroll
      for (int n = 0; n < 8; ++n)
        Hb[tl*132 + n*16 + lrow] = h1[n][r] + rr*h2[n][r];
    }
  }
  __syncthreads();

  const int tr = tid >> 4, tc = tid & 15;
  float lw[8], lb[8];
  {
    float4 a0 = *(const float4*)(lnw + h*NB_DH + tc*4);
    float4 a1 = *(const float4*)(lnw + h*NB_DH + tc*4 + 64);
    lw[0]=a0.x; lw[1]=a0.y; lw[2]=a0.z; lw[3]=a0.w;
    lw[4]=a1.x; lw[5]=a1.y; lw[6]=a1.z; lw[7]=a1.w;
    float4 b0 = *(const float4*)(lnb + h*NB_DH + tc*4);
    float4 b1 = *(const float4*)(lnb + h*NB_DH + tc*4 + 64);
    lb[0]=b0.x; lb[1]=b0.y; lb[2]=b0.z; lb[3]=b0.w;
    lb[4]=b1.x; lb[5]=b1.y; lb[6]=b1.z; lb[7]=b1.w;
  }
  #pragma unroll
  for (int u = 0; u < 4; ++u) {
    int tl = tr*4 + u;
    int t  = half*64 + tl;
    float hrow[8];
    float4 hl0 = *(const float4*)(&Hb[tl*132 + tc*4]);
    float4 hl1 = *(const float4*)(&Hb[tl*132 + tc*4 + 64]);
    hrow[0]=hl0.x; hrow[1]=hl0.y; hrow[2]=hl0.z; hrow[3]=hl0.w;
    hrow[4]=hl1.x; hrow[5]=hl1.y; hrow[6]=hl1.z; hrow[7]=hl1.w;
    float sum = 0.f, ssq = 0.f;
    #pragma unroll
    for (int x = 0; x < 8; ++x) { sum += hrow[x]; ssq += hrow[x]*hrow[x]; }
    #pragma unroll
    for (int off = 1; off < 16; off <<= 1) {
      sum += __shfl_xor(sum, off);
      ssq += __shfl_xor(ssq, off);
    }
    float mean = sum * (1.f/NB_DH);
    float var  = ssq * (1.f/NB_DH) - mean*mean;
    float rstd = rsqrtf(var + 1e-6f);
    #pragma unroll
    for (int m = 0; m < 2; ++m) {
      ushort4v xo4 = *(const ushort4v*)(Pvx + (rowbase + t)*2048 + 1024 + h*NB_DH + tc*4 + m*64);
      float xov[4] = { bf2f(xo4[0]), bf2f(xo4[1]), bf2f(xo4[2]), bf2f(xo4[3]) };
      unsigned short res[4];
      #pragma unroll
      for (int w = 0; w < 4; ++w) {
        int x = m*4 + w;
        float hn = (hrow[x] - mean)*rstd*lw[x] + lb[x];
        float tt = tanhf(xov[w]*(1.f/15.f))*15.f;
        float o = 1.f/(1.f + expf(-tt));
        res[w] = f2bf(hn*o);
      }
      ushort4v r4 = { res[0], res[1], res[2], res[3] };
      *(ushort4v*)(hng + (rowbase + t)*1024 + h*NB_DH + tc*4 + m*64) = r4;
    }
  }
}

extern "C" void kernel_launch(void* const* d_in, const int* in_sizes, int n_in,
                              void* d_out, int out_size, void* d_ws, size_t ws_size,
                              hipStream_t stream)
{
  (void)in_sizes; (void)n_in; (void)out_size; (void)ws_size;
  const float* x   = (const float*)d_in[0];
  const float* Wq  = (const float*)d_in[1];
  const float* Wk  = (const float*)d_in[2];
  const float* Wv  = (const float*)d_in[3];
  const float* Wi  = (const float*)d_in[4];
  const float* bi  = (const float*)d_in[5];
  const float* Wf  = (const float*)d_in[6];
  const float* bf  = (const float*)d_in[7];
  const float* Wog = (const float*)d_in[8];
  const float* lnw = (const float*)d_in[9];
  const float* lnb = (const float*)d_in[10];
  const float* Wout= (const float*)d_in[11];
  float* out = (float*)d_out;
  float* ws  = (float*)d_ws;

  float*          Pqk = ws + OFF_PQK;
  unsigned short* Pvx = (unsigned short*)(ws + OFF_PVX);
  unsigned short* xh  = (unsigned short*)(ws + OFF_XH);
  unsigned short* xl  = (unsigned short*)(ws + OFF_XL);
  unsigned short* Whi = (unsigned short*)(ws + OFF_WHI);
  unsigned short* Wlo = (unsigned short*)(ws + OFF_WLO);
  unsigned short* WtO = (unsigned short*)(ws + OFF_WTO);
  float*          iv  = ws + OFF_IV;
  float*          fv  = ws + OFF_FV;
  float*          g   = ws + OFF_G;
  float*          G   = ws + OFF_GM;
  float*          Dl  = ws + OFF_DL;
  float*          Cb  = ws + OFF_CB;
  unsigned short* hng = (unsigned short*)(ws + OFF_HNG);

  row_pre <<<2048, 64, 0, stream>>>(x, Wi, bi, Wf, bf, xh, xl, iv, fv);
  transp5 <<<dim3(64,16), 256, 0, stream>>>(Wq, Wk, Wv, Wog, Wout, Whi, Wlo, WtO);
  gate_scan<<<16, 64, 0, stream>>>(iv, fv, g, G);

  gemm_proj<<<512, 256, 0, stream>>>(xh, xl, Whi, Wlo, Pqk, Pvx);

  chunk_local  <<<128, 128, 0, stream>>>(Pqk, Pvx, g, G, Dl);
  chunk_combine<<<128, 256, 0, stream>>>(Dl, G, Cb);
  chunk_out    <<<256, 256, 0, stream>>>(Pqk, Pvx, g, G, Cb, lnw, lnb, hng);

  gemm_out64<<<256, 256, 0, stream>>>(hng, WtO, out, 1024);
}

// Round 11
// 129.640 us; speedup vs baseline: 1.3977x; 1.0418x over previous
//
#include <hip/hip_runtime.h>
#include <math.h>

#define NB_B   2
#define NB_S   1024
#define NB_D   1024
#define NB_NH  8
#define NB_DQK 64
#define NB_DH  128
#define NCH    8
#define CL     128

typedef __attribute__((ext_vector_type(8))) short  short8v;   // 8 x bf16
typedef __attribute__((ext_vector_type(4))) float  f32x4;
typedef __attribute__((ext_vector_type(8))) unsigned short ushort8v;
typedef __attribute__((ext_vector_type(4))) unsigned short ushort4v;

__device__ __forceinline__ unsigned short f2bf(float f) {
  unsigned u = __float_as_uint(f);
  unsigned r = (u + 0x7FFFu + ((u >> 16) & 1u)) >> 16;
  return (unsigned short)r;
}
__device__ __forceinline__ float bf2f(unsigned short h) {
  return __uint_as_float(((unsigned)h) << 16);
}

#define GLD_LDS16(g, l) __builtin_amdgcn_global_load_lds( \
    (const __attribute__((address_space(1))) void*)(g),   \
    (__attribute__((address_space(3))) void*)(l), 16, 0, 0)

#define MFMA_BF16(a, b, c) __builtin_amdgcn_mfma_f32_16x16x32_bf16((a), (b), (c), 0, 0, 0)

// ---------------- workspace map (units: FLOAT SLOTS) ----------------
// BF(n): n bf16 elements occupy n/2 float slots. Every offset derived.
constexpr size_t BF(size_t elems) { return elems / 2; }
constexpr size_t SZ_PQK = 2048ull * 1024;          // fp32 [2048][1024]
constexpr size_t SZ_PVX = BF(2048ull * 2048);      // bf16 [2048][2048]
constexpr size_t SZ_XH  = BF(2048ull * 1024);
constexpr size_t SZ_XL  = BF(2048ull * 1024);
constexpr size_t SZ_WHI = BF(3072ull * 1024);
constexpr size_t SZ_WLO = BF(1024ull * 1024);
constexpr size_t SZ_WTO = BF(1024ull * 1024);
constexpr size_t SZ_GBUF= 16ull * 1024;            // fp32 [16][1024]
constexpr size_t SZ_DL  = 16ull * 8 * 8192;        // fp32
constexpr size_t SZ_HNG = BF(2048ull * 1024);

constexpr size_t OFF_PQK = 0;
constexpr size_t OFF_PVX = OFF_PQK + SZ_PQK;
constexpr size_t OFF_XH  = OFF_PVX + SZ_PVX;
constexpr size_t OFF_XL  = OFF_XH  + SZ_XH;
constexpr size_t OFF_WHI = OFF_XL  + SZ_XL;
constexpr size_t OFF_WLO = OFF_WHI + SZ_WHI;
constexpr size_t OFF_WTO = OFF_WLO + SZ_WLO;
constexpr size_t OFF_IV  = OFF_WTO + SZ_WTO;
constexpr size_t OFF_FV  = OFF_IV  + SZ_GBUF;
constexpr size_t OFF_G   = OFF_FV  + SZ_GBUF;
constexpr size_t OFF_GM  = OFF_G   + SZ_GBUF;
constexpr size_t OFF_DL  = OFF_GM  + SZ_GBUF;
constexpr size_t OFF_HNG = OFF_DL  + SZ_DL;
constexpr size_t WS_TOTAL = OFF_HNG + SZ_HNG;      // ~11.1M floats = 44.3 MB
static_assert(OFF_XH == OFF_PVX + 2097152, "Pvx is 2048x2048 bf16 = 2,097,152 float slots");

// ---------------- transpose + convert core ----------------
__device__ __forceinline__ void transp_body(
    const float* __restrict__ src,
    unsigned short* __restrict__ hi, unsigned short* __restrict__ lo,
    int N, int nt, int kt, int tid, float (*Ls)[65])
{
  #pragma unroll
  for (int p = 0; p < 16; ++p) {
    int lin = p * 256 + tid;
    int kr = lin >> 6, nc = lin & 63;
    Ls[kr][nc] = src[(size_t)(kt*64 + kr) * N + nt*64 + nc];
  }
  __syncthreads();
  #pragma unroll
  for (int p = 0; p < 16; ++p) {
    int lin = p * 256 + tid;
    int nr = lin >> 6, kc = lin & 63;
    float v = Ls[kc][nr];
    unsigned short h = f2bf(v);
    size_t di = (size_t)(nt*64 + nr) * 1024 + kt*64 + kc;
    hi[di] = h;
    if (lo) lo[di] = f2bf(v - bf2f(h));
  }
}

// ---------------- fused prep: row path (x split + i/f proj) + weight transposes ----------------
// grid 1536 x 256 threads:
//   bx <  512 : 4 rows each (wave-per-row): x->(xh,xl), i/f projections
//   bx >= 512 : transpose blocks, idx = bx-512 -> (x = idx&63, kt = idx>>6)
__global__ __launch_bounds__(256) void prep(
    const float* __restrict__ x,
    const float* __restrict__ Wi, const float* __restrict__ bi,
    const float* __restrict__ Wf, const float* __restrict__ bf,
    const float* __restrict__ Wq, const float* __restrict__ Wk,
    const float* __restrict__ Wv, const float* __restrict__ Wog,
    const float* __restrict__ Wout,
    unsigned short* __restrict__ xh, unsigned short* __restrict__ xl,
    float* __restrict__ iv, float* __restrict__ fv,
    unsigned short* __restrict__ Whi, unsigned short* __restrict__ Wlo,
    unsigned short* __restrict__ WtO)
{
  __shared__ float Ls[64][65];
  const int bx = blockIdx.x, tid = threadIdx.x;
  if (bx < 512) {
    const int row = bx * 4 + (tid >> 6);
    const int l = tid & 63;
    const float4* xr4 = (const float4*)(x + (size_t)row * NB_D);
    float ai[8] = {}, af[8] = {};
    #pragma unroll
    for (int p = 0; p < 4; ++p) {
      int q4i = l + p * 64;
      float4 xv = xr4[q4i];
      int k0 = q4i * 4;
      const float* xs = (const float*)&xv;
      ushort4v h4, l4;
      #pragma unroll
      for (int j = 0; j < 4; ++j) {
        float xsv = xs[j];
        unsigned short hh = f2bf(xsv);
        h4[j] = hh; l4[j] = f2bf(xsv - bf2f(hh));
        const float4* wi4 = (const float4*)(Wi + (size_t)(k0 + j) * 8);
        const float4* wf4 = (const float4*)(Wf + (size_t)(k0 + j) * 8);
        float4 w0 = wi4[0], w1 = wi4[1];
        float4 v0 = wf4[0], v1 = wf4[1];
        ai[0] += xsv*w0.x; ai[1] += xsv*w0.y; ai[2] += xsv*w0.z; ai[3] += xsv*w0.w;
        ai[4] += xsv*w1.x; ai[5] += xsv*w1.y; ai[6] += xsv*w1.z; ai[7] += xsv*w1.w;
        af[0] += xsv*v0.x; af[1] += xsv*v0.y; af[2] += xsv*v0.z; af[3] += xsv*v0.w;
        af[4] += xsv*v1.x; af[5] += xsv*v1.y; af[6] += xsv*v1.z; af[7] += xsv*v1.w;
      }
      *(ushort4v*)(xh + (size_t)row * NB_D + k0) = h4;
      *(ushort4v*)(xl + (size_t)row * NB_D + k0) = l4;
    }
    #pragma unroll
    for (int off = 1; off < 64; off <<= 1) {
      #pragma unroll
      for (int cc = 0; cc < 8; ++cc) {
        ai[cc] += __shfl_xor(ai[cc], off);
        af[cc] += __shfl_xor(af[cc], off);
      }
    }
    if (l == 0) {
      int b = row >> 10, s = row & (NB_S - 1);
      #pragma unroll
      for (int cc = 0; cc < 8; ++cc) {
        iv[(size_t)(b*NB_NH + cc) * NB_S + s] = ai[cc] + bi[cc];
        fv[(size_t)(b*NB_NH + cc) * NB_S + s] = af[cc] + bf[cc];
      }
    }
  } else {
    const int idx = bx - 512;
    const int xq = idx & 63, kt = idx >> 6;
    if (xq < 8)       transp_body(Wq,   Whi,              Wlo,            512,  xq,      kt, tid, Ls);
    else if (xq < 16) transp_body(Wk,   Whi +  512*1024,  Wlo + 512*1024, 512,  xq - 8,  kt, tid, Ls);
    else if (xq < 32) transp_body(Wv,   Whi + 1024*1024,  nullptr,        1024, xq - 16, kt, tid, Ls);
    else if (xq < 48) transp_body(Wog,  Whi + 2048*1024,  nullptr,        1024, xq - 32, kt, tid, Ls);
    else              transp_body(Wout, WtO,              nullptr,        1024, xq - 48, kt, tid, Ls);
  }
}

// ---------------- fused projection GEMM, balanced heavy/light blocks ----------------
__global__ __launch_bounds__(256) void gemm_proj(
    const unsigned short* __restrict__ xh,
    const unsigned short* __restrict__ xl,
    const unsigned short* __restrict__ Whi,
    const unsigned short* __restrict__ Wlo,
    float* __restrict__ Pqk, unsigned short* __restrict__ Pvx)
{
  __shared__ __align__(16) char smem[49152];
  const int tid  = threadIdx.x;
  const int bid  = ((blockIdx.x & 7) << 6) | (blockIdx.x >> 3);   // XCD swizzle (512 = 8*64)
  const int wid  = tid >> 6, lane = tid & 63;
  const int wm   = wid >> 1, wn = wid & 1;
  const int lrow = lane & 15;
  const int lk   = (lane >> 4) * 16;
  const int srow = tid >> 3;
  const int scb  = (tid & 7) << 4;
  const int ldsW = wid * 1024;

  if (!(bid & 1)) {
    // HEAVY: q,k with split-bf16, M=64
    const int h  = bid >> 1;
    const int ct = h & 7, bm = h >> 3;
    char* Ah = smem;
    char* Al = smem + 8192;
    char* Bh = smem + 16384;
    char* Bl = smem + 32768;
    const char* xhB = (const char*)xh;
    const char* xlB = (const char*)xl;
    const char* whB = (const char*)(Whi + (size_t)ct*128*1024);
    const char* wlB = (const char*)(Wlo + (size_t)ct*128*1024);

    size_t gA[2], gB[4];
    #pragma unroll
    for (int i = 0; i < 2; ++i) {
      int row = i * 32 + srow;
      int cbs = scb ^ ((row & 7) << 4);
      gA[i] = (size_t)(bm*64 + row) * 2048 + cbs;
    }
    #pragma unroll
    for (int i = 0; i < 4; ++i) {
      int row = i * 32 + srow;
      int cbs = scb ^ ((row & 7) << 4);
      gB[i] = (size_t)row * 2048 + cbs;
    }

    f32x4 acc[2][4];
    const f32x4 z4 = { 0.f, 0.f, 0.f, 0.f };
    #pragma unroll
    for (int m = 0; m < 2; ++m)
      #pragma unroll
      for (int n = 0; n < 4; ++n) acc[m][n] = z4;

    for (int kt = 0; kt < 16; ++kt) {
      __syncthreads();
      #pragma unroll
      for (int i = 0; i < 2; ++i) GLD_LDS16(xhB + gA[i] + kt*128, Ah + i*4096 + ldsW);
      #pragma unroll
      for (int i = 0; i < 2; ++i) GLD_LDS16(xlB + gA[i] + kt*128, Al + i*4096 + ldsW);
      #pragma unroll
      for (int i = 0; i < 4; ++i) GLD_LDS16(whB + gB[i] + kt*128, Bh + i*4096 + ldsW);
      #pragma unroll
      for (int i = 0; i < 4; ++i) GLD_LDS16(wlB + gB[i] + kt*128, Bl + i*4096 + ldsW);
      __syncthreads();

      #pragma unroll
      for (int kk = 0; kk < 2; ++kk) {
        short8v ah[2], al[2], bh[4], bl[4];
        #pragma unroll
        for (int m = 0; m < 2; ++m) {
          int row = wm*32 + m*16 + lrow;
          int kb  = (kk*64 + lk) ^ ((row & 7) << 4);
          ah[m] = *(const short8v*)(Ah + row*128 + kb);
          al[m] = *(const short8v*)(Al + row*128 + kb);
        }
        #pragma unroll
        for (int n = 0; n < 4; ++n) {
          int row = wn*64 + n*16 + lrow;
          int kb  = (kk*64 + lk) ^ ((row & 7) << 4);
          bh[n] = *(const short8v*)(Bh + row*128 + kb);
          bl[n] = *(const short8v*)(Bl + row*128 + kb);
        }
        #pragma unroll
        for (int m = 0; m < 2; ++m)
          #pragma unroll
          for (int n = 0; n < 4; ++n) {
            acc[m][n] = MFMA_BF16(ah[m], bh[n], acc[m][n]);
            acc[m][n] = MFMA_BF16(al[m], bh[n], acc[m][n]);
            acc[m][n] = MFMA_BF16(ah[m], bl[n], acc[m][n]);
          }
      }
    }

    const int crow0 = bm*64 + wm*32 + ((lane >> 4) << 2);
    const int ccol0 = ct*128 + wn*64 + lrow;
    #pragma unroll
    for (int m = 0; m < 2; ++m)
      #pragma unroll
      for (int n = 0; n < 4; ++n)
        #pragma unroll
        for (int r = 0; r < 4; ++r)
          Pqk[(size_t)(crow0 + m*16 + r) * 1024 + ccol0 + n*16] = acc[m][n][r];
  } else {
    // LIGHT: v,xog plain bf16, M=128 -> Pvx bf16
    const int l  = bid >> 1;
    const int ct = l & 15, bm = l >> 4;
    char* As = smem;
    char* Bs = smem + 16384;
    const char* xhB = (const char*)xh;
    const char* wB  = (const char*)(Whi + (size_t)(8 + ct)*128*1024);

    size_t gA[4], gB[4];
    #pragma unroll
    for (int i = 0; i < 4; ++i) {
      int row = i * 32 + srow;
      int cbs = scb ^ ((row & 7) << 4);
      gA[i] = (size_t)(bm*128 + row) * 2048 + cbs;
      gB[i] = (size_t)row * 2048 + cbs;
    }

    f32x4 acc[4][4];
    const f32x4 z4 = { 0.f, 0.f, 0.f, 0.f };
    #pragma unroll
    for (int m = 0; m < 4; ++m)
      #pragma unroll
      for (int n = 0; n < 4; ++n) acc[m][n] = z4;

    for (int kt = 0; kt < 16; ++kt) {
      __syncthreads();
      #pragma unroll
      for (int i = 0; i < 4; ++i) GLD_LDS16(xhB + gA[i] + kt*128, As + i*4096 + ldsW);
      #pragma unroll
      for (int i = 0; i < 4; ++i) GLD_LDS16(wB  + gB[i] + kt*128, Bs + i*4096 + ldsW);
      __syncthreads();

      #pragma unroll
      for (int kk = 0; kk < 2; ++kk) {
        short8v a[4], b[4];
        #pragma unroll
        for (int m = 0; m < 4; ++m) {
          int row = wm*64 + m*16 + lrow;
          int kb  = (kk*64 + lk) ^ ((row & 7) << 4);
          a[m] = *(const short8v*)(As + row*128 + kb);
        }
        #pragma unroll
        for (int n = 0; n < 4; ++n) {
          int row = wn*64 + n*16 + lrow;
          int kb  = (kk*64 + lk) ^ ((row & 7) << 4);
          b[n] = *(const short8v*)(Bs + row*128 + kb);
        }
        #pragma unroll
        for (int m = 0; m < 4; ++m)
          #pragma unroll
          for (int n = 0; n < 4; ++n)
            acc[m][n] = MFMA_BF16(a[m], b[n], acc[m][n]);
      }
    }

    const int crow0 = bm*128 + wm*64 + ((lane >> 4) << 2);
    const int ccol0 = ct*128 + wn*64 + lrow;
    #pragma unroll
    for (int m = 0; m < 4; ++m)
      #pragma unroll
      for (int n = 0; n < 4; ++n)
        #pragma unroll
        for (int r = 0; r < 4; ++r)
          Pvx[(size_t)(crow0 + m*16 + r) * 2048 + ccol0 + n*16] = f2bf(acc[m][n][r]);
  }
}

// ---------------- output GEMM: 128x64 tiles, XCD-swizzled 1-D grid (256) ----------------
__global__ __launch_bounds__(256) void gemm_out64(
    const unsigned short* __restrict__ A,
    const unsigned short* __restrict__ Bt,
    float* __restrict__ C, int ldc)
{
  __shared__ __align__(16) unsigned short As[128*64];
  __shared__ __align__(16) unsigned short Bs[64*64];
  const int tid  = threadIdx.x;
  const int bid  = ((blockIdx.x & 7) << 5) | (blockIdx.x >> 3);   // 256 = 8*32
  const int cn   = bid & 15, bm = bid >> 4;
  const int wid  = tid >> 6, lane = tid & 63;
  const int wm   = wid >> 1, wn = wid & 1;
  const int lrow = lane & 15;
  const int lk   = (lane >> 4) * 16;

  f32x4 acc[4][2];
  const f32x4 z4 = { 0.f, 0.f, 0.f, 0.f };
  #pragma unroll
  for (int m = 0; m < 4; ++m)
    #pragma unroll
    for (int n = 0; n < 2; ++n) acc[m][n] = z4;

  const int srow = tid >> 3;
  const int scb  = (tid & 7) << 4;
  const char* Ab = (const char*)A;
  const char* Bb = (const char*)Bt;
  size_t gA[4], gB[2];
  #pragma unroll
  for (int i = 0; i < 4; ++i) {
    int row = i * 32 + srow;
    int cbs = scb ^ ((row & 7) << 4);
    gA[i] = (size_t)(bm*128 + row) * 2048 + cbs;
  }
  #pragma unroll
  for (int i = 0; i < 2; ++i) {
    int row = i * 32 + srow;
    int cbs = scb ^ ((row & 7) << 4);
    gB[i] = (size_t)(cn*64 + row) * 2048 + cbs;
  }
  const int ldsW = wid * 1024;

  for (int kt = 0; kt < 16; ++kt) {
    __syncthreads();
    #pragma unroll
    for (int i = 0; i < 4; ++i)
      GLD_LDS16(Ab + gA[i] + kt*128, (char*)As + i*4096 + ldsW);
    #pragma unroll
    for (int i = 0; i < 2; ++i)
      GLD_LDS16(Bb + gB[i] + kt*128, (char*)Bs + i*4096 + ldsW);
    __syncthreads();

    #pragma unroll
    for (int kk = 0; kk < 2; ++kk) {
      short8v a[4], b[2];
      #pragma unroll
      for (int m = 0; m < 4; ++m) {
        int row = wm*64 + m*16 + lrow;
        int kb  = (kk*64 + lk) ^ ((row & 7) << 4);
        a[m] = *(const short8v*)((const char*)As + row*128 + kb);
      }
      #pragma unroll
      for (int n = 0; n < 2; ++n) {
        int row = wn*32 + n*16 + lrow;
        int kb  = (kk*64 + lk) ^ ((row & 7) << 4);
        b[n] = *(const short8v*)((const char*)Bs + row*128 + kb);
      }
      #pragma unroll
      for (int m = 0; m < 4; ++m)
        #pragma unroll
        for (int n = 0; n < 2; ++n)
          acc[m][n] = MFMA_BF16(a[m], b[n], acc[m][n]);
    }
  }

  const int crow0 = bm*128 + wm*64 + ((lane >> 4) << 2);
  const int ccol0 = cn*64 + wn*32 + (lane & 15);
  #pragma unroll
  for (int m = 0; m < 4; ++m)
    #pragma unroll
    for (int n = 0; n < 2; ++n)
      #pragma unroll
      for (int r = 0; r < 4; ++r)
        C[(size_t)(crow0 + m*16 + r) * ldc + ccol0 + n*16] = acc[m][n][r];
}

// ---------------- gate scan ----------------
__global__ __launch_bounds__(64) void gate_scan(
    const float* __restrict__ iv, const float* __restrict__ fv,
    float* __restrict__ gv, float* __restrict__ Gv)
{
  const int bh = blockIdx.x, l = threadIdx.x;
  const int base = bh * NB_S + l * 16;
  float fl[16];
  float run = 0.f;
  #pragma unroll
  for (int u = 0; u < 16; ++u) {
    float fr = fv[base + u];
    float flog = (fr >= 0.f) ? -log1pf(expf(-fr)) : (fr - log1pf(expf(fr)));
    run += flog; fl[u] = run;
  }
  float tot = run, sc = tot;
  #pragma unroll
  for (int off = 1; off < 64; off <<= 1) {
    float t = __shfl_up(sc, off);
    if (l >= off) sc += t;
  }
  float excl = sc - tot;
  float gm[16]; float rmax = -1e30f;
  #pragma unroll
  for (int u = 0; u < 16; ++u) {
    float bt = excl + fl[u];
    float g = iv[base + u] - bt;
    gv[base + u] = g;
    rmax = fmaxf(rmax, g); gm[u] = rmax;
  }
  float mx = rmax;
  #pragma unroll
  for (int off = 1; off < 64; off <<= 1) {
    float t = __shfl_up(mx, off);
    if (l >= off) mx = fmaxf(mx, t);
  }
  float em = __shfl_up(mx, 1);
  if (l == 0) em = -1e30f;
  #pragma unroll
  for (int u = 0; u < 16; ++u)
    Gv[base + u] = fmaxf(0.f, fmaxf(em, gm[u]));
}

// ---------------- per-chunk local KV state (v bf16) ----------------
__global__ __launch_bounds__(128) void chunk_local(
    const float* __restrict__ Pqk, const unsigned short* __restrict__ Pvx,
    const float* __restrict__ gv, const float* __restrict__ Gv,
    float* __restrict__ Dloc)
{
  __shared__ float ks[16][68];
  __shared__ float vs[16][132];
  __shared__ float wsg[16];
  const int bx = blockIdx.x, bh = bx >> 3, c = bx & 7;
  const int b = bh >> 3, h = bh & 7;
  const int tid = threadIdx.x;
  const int rg = tid >> 3, cg = tid & 7;
  const int i0 = rg * 4;
  float acc[4][16] = {};
  const float Gend = Gv[bh*NB_S + c*CL + CL - 1];
  const float* kbp = Pqk + ((size_t)b*NB_S + c*CL) * 1024 + 512 + h*NB_DQK;
  const unsigned short* vbp = Pvx + ((size_t)b*NB_S + c*CL) * 2048 + h*NB_DH;
  const float* gbp = gv + bh*NB_S + c*CL;
  for (int sb = 0; sb < 8; ++sb) {
    __syncthreads();
    #pragma unroll
    for (int p = 0; p < 2; ++p) {
      int qd = tid + p*128; int r = qd >> 4, cq = qd & 15;
      *(float4*)(&ks[r][cq*4]) = *(const float4*)(kbp + (size_t)(sb*16 + r)*1024 + cq*4);
    }
    #pragma unroll
    for (int p = 0; p < 4; ++p) {
      int qd = tid + p*128; int r = qd >> 5, cq = qd & 31;
      ushort4v v4 = *(const ushort4v*)(vbp + (size_t)(sb*16 + r)*2048 + cq*4);
      vs[r][cq*4+0] = bf2f(v4[0]); vs[r][cq*4+1] = bf2f(v4[1]);
      vs[r][cq*4+2] = bf2f(v4[2]); vs[r][cq*4+3] = bf2f(v4[3]);
    }
    if (tid < 16) wsg[tid] = expf(gbp[sb*16 + tid] - Gend);
    __syncthreads();
    #pragma unroll
    for (int s = 0; s < 16; ++s) {
      float w = wsg[s];
      float4 kq = *(const float4*)(&ks[s][i0]);
      float wk[4] = { w*kq.x, w*kq.y, w*kq.z, w*kq.w };
      #pragma unroll
      for (int m = 0; m < 4; ++m) {
        float4 vq = *(const float4*)(&vs[s][cg*4 + m*32]);
        #pragma unroll
        for (int u = 0; u < 4; ++u) {
          acc[u][m*4+0] += wk[u]*vq.x;
          acc[u][m*4+1] += wk[u]*vq.y;
          acc[u][m*4+2] += wk[u]*vq.z;
          acc[u][m*4+3] += wk[u]*vq.w;
        }
      }
    }
  }
  float* dst = Dloc + ((size_t)bh*NCH + c) * (NB_DQK*NB_DH);
  #pragma unroll
  for (int u = 0; u < 4; ++u)
    #pragma unroll
    for (int m = 0; m < 4; ++m) {
      float4 o4 = { acc[u][m*4+0], acc[u][m*4+1], acc[u][m*4+2], acc[u][m*4+3] };
      *(float4*)(dst + (size_t)(i0+u)*NB_DH + cg*4 + m*32) = o4;
    }
}

// ---------------- chunked attention via MFMA + inline state combine + LN + gate ----------------
// grid 256 (XCD-swizzled): bh(16) x c(8) x half(2); block = 64 t-rows, 4 waves.
// Cbef computed inline: Cbef[c] = sum_{c'<c} exp(Gend_{c'} - Gend_{c-1}) * Dloc[c'].
__global__ __launch_bounds__(256,1) void chunk_out(
    const float* __restrict__ Pqk, const unsigned short* __restrict__ Pvx,
    const float* __restrict__ gv, const float* __restrict__ Gv,
    const float* __restrict__ Dloc,
    const float* __restrict__ lnw, const float* __restrict__ lnb,
    unsigned short* __restrict__ hng)
{
  __shared__ __align__(16) char smem[131072];
  __shared__ float gsh[128], Gsh[128], rsh[128];
  constexpr int QH = 0, QL = 8192, KH = 16384, KL = 32768;
  constexpr int ATT = 49152, VT = 65536, CBH = 98304, CBL = 114688;

  const int bx = ((blockIdx.x & 7) << 5) | (blockIdx.x >> 3);   // 256 = 8*32
  const int half = bx & 1, c = (bx >> 1) & 7, bh = bx >> 4;
  const int b = bh >> 3, h = bh & 7;
  const int tid = threadIdx.x;
  const int wid = tid >> 6, lane = tid & 63;
  const int lrow = lane & 15;
  const int lkB  = (lane >> 4) * 16;
  const size_t rowbase = (size_t)b*NB_S + (size_t)c*CL;
  const int sgbase = bh*NB_S + c*CL;

  if (tid < 128) {
    float gval = gv[sgbase + tid];
    float Gval = Gv[sgbase + tid];
    gsh[tid] = gval; Gsh[tid] = Gval;
    float Gprev = (c > 0) ? Gv[sgbase - 1] : 0.f;
    rsh[tid] = 0.125f * expf(Gprev - Gval);
  }

  // ---- phase 0: convert operands into swizzled LDS ----
  #pragma unroll
  for (int p = 0; p < 4; ++p) {
    int lin = p*256 + tid;
    int row = lin >> 4, i0 = (lin & 15) * 4;
    float4 v4 = *(const float4*)(Pqk + (rowbase + half*64 + row)*1024 + h*NB_DQK + i0);
    float vv[4] = { v4.x, v4.y, v4.z, v4.w };
    ushort4v h4, l4;
    #pragma unroll
    for (int j = 0; j < 4; ++j) {
      unsigned short hh = f2bf(vv[j]); h4[j] = hh; l4[j] = f2bf(vv[j] - bf2f(hh));
    }
    int off = (row*128 + i0*2) ^ ((row & 7) << 4);
    *(ushort4v*)(smem + QH + off) = h4;
    *(ushort4v*)(smem + QL + off) = l4;
  }
  #pragma unroll
  for (int p = 0; p < 8; ++p) {
    int lin = p*256 + tid;
    int row = lin >> 4, i0 = (lin & 15) * 4;
    float4 v4 = *(const float4*)(Pqk + (rowbase + row)*1024 + 512 + h*NB_DQK + i0);
    float vv[4] = { v4.x, v4.y, v4.z, v4.w };
    ushort4v h4, l4;
    #pragma unroll
    for (int j = 0; j < 4; ++j) {
      unsigned short hh = f2bf(vv[j]); h4[j] = hh; l4[j] = f2bf(vv[j] - bf2f(hh));
    }
    int off = (row*128 + i0*2) ^ ((row & 7) << 4);
    *(ushort4v*)(smem + KH + off) = h4;
    *(ushort4v*)(smem + KL + off) = l4;
  }
  // V^T (bf16 source -> re-layout only)
  #pragma unroll
  for (int p = 0; p < 8; ++p) {
    int lin = p*256 + tid;
    int s = lin >> 4, j0 = (lin & 15) * 8;
    ushort8v v8 = *(const ushort8v*)(Pvx + (rowbase + s)*2048 + h*NB_DH + j0);
    #pragma unroll
    for (int j = 0; j < 8; ++j) {
      int jj = j0 + j;
      int off = (jj*256 + s*2) ^ ((jj & 7) << 4);
      *(unsigned short*)(smem + VT + off) = v8[j];
    }
  }
  // Cb^T hi/lo via closed-form weighted sum of Dloc over previous chunks
  {
    float4 cbacc[8];
    #pragma unroll
    for (int p = 0; p < 8; ++p) cbacc[p] = float4{0.f,0.f,0.f,0.f};
    const float Gcm1 = (c > 0) ? Gv[sgbase - 1] : 0.f;
    for (int cp = 0; cp < c; ++cp) {
      float wgt = expf(Gv[bh*NB_S + cp*CL + CL - 1] - Gcm1);
      const float4* dl4 = (const float4*)(Dloc + ((size_t)bh*NCH + cp)*8192);
      #pragma unroll
      for (int p = 0; p < 8; ++p) {
        float4 d = dl4[p*256 + tid];
        cbacc[p].x += wgt*d.x; cbacc[p].y += wgt*d.y;
        cbacc[p].z += wgt*d.z; cbacc[p].w += wgt*d.w;
      }
    }
    #pragma unroll
    for (int p = 0; p < 8; ++p) {
      int lin = p*256 + tid;
      int i = lin >> 5, j0 = (lin & 31) * 4;
      float vv[4] = { cbacc[p].x, cbacc[p].y, cbacc[p].z, cbacc[p].w };
      #pragma unroll
      for (int w = 0; w < 4; ++w) {
        int jj = j0 + w;
        int off = (jj*128 + i*2) ^ ((jj & 7) << 4);
        unsigned short hh = f2bf(vv[w]);
        *(unsigned short*)(smem + CBH + off) = hh;
        *(unsigned short*)(smem + CBL + off) = f2bf(vv[w] - bf2f(hh));
      }
    }
  }
  __syncthreads();

  const f32x4 z4 = { 0.f, 0.f, 0.f, 0.f };
  const int trow = wid*16 + lrow;

  // ---- phase 1a: S = q k^T (split-bf16), weight+mask -> att (bf16) ----
  f32x4 sacc[8];
  #pragma unroll
  for (int n = 0; n < 8; ++n) sacc[n] = z4;
  #pragma unroll
  for (int kk = 0; kk < 2; ++kk) {
    int qb = kk*64 + lkB;
    int ab = (trow*128 + qb) ^ ((trow & 7) << 4);
    short8v aqh = *(const short8v*)(smem + QH + ab);
    short8v aql = *(const short8v*)(smem + QL + ab);
    #pragma unroll
    for (int n = 0; n < 8; ++n) {
      int srw = n*16 + lrow;
      int bb = (srw*128 + qb) ^ ((srw & 7) << 4);
      short8v bkh = *(const short8v*)(smem + KH + bb);
      short8v bkl = *(const short8v*)(smem + KL + bb);
      sacc[n] = MFMA_BF16(aqh, bkh, sacc[n]);
      sacc[n] = MFMA_BF16(aql, bkh, sacc[n]);
      sacc[n] = MFMA_BF16(aqh, bkl, sacc[n]);
    }
  }
  {
    int td[4]; float gt[4];
    #pragma unroll
    for (int r = 0; r < 4; ++r) {
      td[r] = wid*16 + ((lane >> 4) << 2) + r;
      gt[r] = Gsh[half*64 + td[r]];
    }
    #pragma unroll
    for (int n = 0; n < 8; ++n) {
      int s = n*16 + lrow;
      float gs = gsh[s];
      #pragma unroll
      for (int r = 0; r < 4; ++r) {
        float w = 0.125f * expf(gs - gt[r]);
        float val = (s <= half*64 + td[r]) ? sacc[n][r]*w : 0.f;
        int off = (td[r]*256 + s*2) ^ ((td[r] & 7) << 4);
        *(unsigned short*)(smem + ATT + off) = f2bf(val);
      }
    }
  }

  // ---- phase 1b: state term h2 = q * Cbef (split-bf16) ----
  f32x4 h2[8];
  #pragma unroll
  for (int n = 0; n < 8; ++n) h2[n] = z4;
  #pragma unroll
  for (int kk = 0; kk < 2; ++kk) {
    int qb = kk*64 + lkB;
    int ab = (trow*128 + qb) ^ ((trow & 7) << 4);
    short8v aqh = *(const short8v*)(smem + QH + ab);
    short8v aql = *(const short8v*)(smem + QL + ab);
    #pragma unroll
    for (int n = 0; n < 8; ++n) {
      int jrw = n*16 + lrow;
      int bb = (jrw*128 + qb) ^ ((jrw & 7) << 4);
      short8v bch = *(const short8v*)(smem + CBH + bb);
      short8v bcl = *(const short8v*)(smem + CBL + bb);
      h2[n] = MFMA_BF16(aqh, bch, h2[n]);
      h2[n] = MFMA_BF16(aql, bch, h2[n]);
      h2[n] = MFMA_BF16(aqh, bcl, h2[n]);
    }
  }
  __syncthreads();

  // ---- phase 2: PV: h1 = att * V ----
  f32x4 h1[8];
  #pragma unroll
  for (int n = 0; n < 8; ++n) h1[n] = z4;
  #pragma unroll
  for (int kk = 0; kk < 4; ++kk) {
    int ab = (trow*256 + kk*64 + lkB) ^ ((trow & 7) << 4);
    short8v aat = *(const short8v*)(smem + ATT + ab);
    #pragma unroll
    for (int n = 0; n < 8; ++n) {
      int jrw = n*16 + lrow;
      int bb = (jrw*256 + kk*64 + lkB) ^ ((jrw & 7) << 4);
      short8v bvt = *(const short8v*)(smem + VT + bb);
      h1[n] = MFMA_BF16(aat, bvt, h1[n]);
    }
  }
  __syncthreads();

  // ---- phase 3: combine, stage H in LDS, epilogue ----
  float* Hb = (float*)smem;
  {
    #pragma unroll
    for (int r = 0; r < 4; ++r) {
      int tl = wid*16 + ((lane >> 4) << 2) + r;
      float rr = rsh[half*64 + tl];
      #pragma unroll
      for (int n = 0; n < 8; ++n)
        Hb[tl*132 + n*16 + lrow] = h1[n][r] + rr*h2[n][r];
    }
  }
  __syncthreads();

  const int tr = tid >> 4, tc = tid & 15;
  float lw[8], lb[8];
  {
    float4 a0 = *(const float4*)(lnw + h*NB_DH + tc*4);
    float4 a1 = *(const float4*)(lnw + h*NB_DH + tc*4 + 64);
    lw[0]=a0.x; lw[1]=a0.y; lw[2]=a0.z; lw[3]=a0.w;
    lw[4]=a1.x; lw[5]=a1.y; lw[6]=a1.z; lw[7]=a1.w;
    float4 b0 = *(const float4*)(lnb + h*NB_DH + tc*4);
    float4 b1 = *(const float4*)(lnb + h*NB_DH + tc*4 + 64);
    lb[0]=b0.x; lb[1]=b0.y; lb[2]=b0.z; lb[3]=b0.w;
    lb[4]=b1.x; lb[5]=b1.y; lb[6]=b1.z; lb[7]=b1.w;
  }
  #pragma unroll
  for (int u = 0; u < 4; ++u) {
    int tl = tr*4 + u;
    int t  = half*64 + tl;
    float hrow[8];
    float4 hl0 = *(const float4*)(&Hb[tl*132 + tc*4]);
    float4 hl1 = *(const float4*)(&Hb[tl*132 + tc*4 + 64]);
    hrow[0]=hl0.x; hrow[1]=hl0.y; hrow[2]=hl0.z; hrow[3]=hl0.w;
    hrow[4]=hl1.x; hrow[5]=hl1.y; hrow[6]=hl1.z; hrow[7]=hl1.w;
    float sum = 0.f, ssq = 0.f;
    #pragma unroll
    for (int x = 0; x < 8; ++x) { sum += hrow[x]; ssq += hrow[x]*hrow[x]; }
    #pragma unroll
    for (int off = 1; off < 16; off <<= 1) {
      sum += __shfl_xor(sum, off);
      ssq += __shfl_xor(ssq, off);
    }
    float mean = sum * (1.f/NB_DH);
    float var  = ssq * (1.f/NB_DH) - mean*mean;
    float rstd = rsqrtf(var + 1e-6f);
    #pragma unroll
    for (int m = 0; m < 2; ++m) {
      ushort4v xo4 = *(const ushort4v*)(Pvx + (rowbase + t)*2048 + 1024 + h*NB_DH + tc*4 + m*64);
      float xov[4] = { bf2f(xo4[0]), bf2f(xo4[1]), bf2f(xo4[2]), bf2f(xo4[3]) };
      unsigned short res[4];
      #pragma unroll
      for (int w = 0; w < 4; ++w) {
        int x = m*4 + w;
        float hn = (hrow[x] - mean)*rstd*lw[x] + lb[x];
        float tt = tanhf(xov[w]*(1.f/15.f))*15.f;
        float o = 1.f/(1.f + expf(-tt));
        res[w] = f2bf(hn*o);
      }
      ushort4v r4 = { res[0], res[1], res[2], res[3] };
      *(ushort4v*)(hng + (rowbase + t)*1024 + h*NB_DH + tc*4 + m*64) = r4;
    }
  }
}

extern "C" void kernel_launch(void* const* d_in, const int* in_sizes, int n_in,
                              void* d_out, int out_size, void* d_ws, size_t ws_size,
                              hipStream_t stream)
{
  (void)in_sizes; (void)n_in; (void)out_size; (void)ws_size;
  const float* x   = (const float*)d_in[0];
  const float* Wq  = (const float*)d_in[1];
  const float* Wk  = (const float*)d_in[2];
  const float* Wv  = (const float*)d_in[3];
  const float* Wi  = (const float*)d_in[4];
  const float* bi  = (const float*)d_in[5];
  const float* Wf  = (const float*)d_in[6];
  const float* bf  = (const float*)d_in[7];
  const float* Wog = (const float*)d_in[8];
  const float* lnw = (const float*)d_in[9];
  const float* lnb = (const float*)d_in[10];
  const float* Wout= (const float*)d_in[11];
  float* out = (float*)d_out;
  float* ws  = (float*)d_ws;

  float*          Pqk = ws + OFF_PQK;
  unsigned short* Pvx = (unsigned short*)(ws + OFF_PVX);
  unsigned short* xh  = (unsigned short*)(ws + OFF_XH);
  unsigned short* xl  = (unsigned short*)(ws + OFF_XL);
  unsigned short* Whi = (unsigned short*)(ws + OFF_WHI);
  unsigned short* Wlo = (unsigned short*)(ws + OFF_WLO);
  unsigned short* WtO = (unsigned short*)(ws + OFF_WTO);
  float*          iv  = ws + OFF_IV;
  float*          fv  = ws + OFF_FV;
  float*          g   = ws + OFF_G;
  float*          G   = ws + OFF_GM;
  float*          Dl  = ws + OFF_DL;
  unsigned short* hng = (unsigned short*)(ws + OFF_HNG);

  prep     <<<1536, 256, 0, stream>>>(x, Wi, bi, Wf, bf, Wq, Wk, Wv, Wog, Wout,
                                      xh, xl, iv, fv, Whi, Wlo, WtO);
  gate_scan<<<16, 64, 0, stream>>>(iv, fv, g, G);

  gemm_proj<<<512, 256, 0, stream>>>(xh, xl, Whi, Wlo, Pqk, Pvx);

  chunk_local<<<128, 128, 0, stream>>>(Pqk, Pvx, g, G, Dl);
  chunk_out  <<<256, 256, 0, stream>>>(Pqk, Pvx, g, G, Dl, lnw, lnb, hng);

  gemm_out64 <<<256, 256, 0, stream>>>(hng, WtO, out, 1024);
}

// Round 12
// 109.913 us; speedup vs baseline: 1.6486x; 1.1795x over previous
//
#include <hip/hip_runtime.h>
#include <math.h>

#define NB_B   2
#define NB_S   1024
#define NB_D   1024
#define NB_NH  8
#define NB_DQK 64
#define NB_DH  128
#define NCH    8
#define CL     128

typedef __attribute__((ext_vector_type(8))) short  short8v;   // 8 x bf16
typedef __attribute__((ext_vector_type(4))) float  f32x4;
typedef __attribute__((ext_vector_type(8))) unsigned short ushort8v;
typedef __attribute__((ext_vector_type(4))) unsigned short ushort4v;

__device__ __forceinline__ unsigned short f2bf(float f) {
  unsigned u = __float_as_uint(f);
  unsigned r = (u + 0x7FFFu + ((u >> 16) & 1u)) >> 16;
  return (unsigned short)r;
}
__device__ __forceinline__ float bf2f(unsigned short h) {
  return __uint_as_float(((unsigned)h) << 16);
}

#define GLD_LDS16(g, l) __builtin_amdgcn_global_load_lds( \
    (const __attribute__((address_space(1))) void*)(g),   \
    (__attribute__((address_space(3))) void*)(l), 16, 0, 0)

#define MFMA_BF16(a, b, c) __builtin_amdgcn_mfma_f32_16x16x32_bf16((a), (b), (c), 0, 0, 0)

// ---------------- workspace map (units: FLOAT SLOTS) ----------------
// BF(n): n bf16 elements occupy n/2 float slots. Every offset derived.
constexpr size_t BF(size_t elems) { return elems / 2; }
constexpr size_t SZ_PQK = 2048ull * 1024;          // fp32 [2048][1024]
constexpr size_t SZ_PVX = BF(2048ull * 2048);      // bf16 [2048][2048]
constexpr size_t SZ_XH  = BF(2048ull * 1024);
constexpr size_t SZ_XL  = BF(2048ull * 1024);
constexpr size_t SZ_WHI = BF(3072ull * 1024);
constexpr size_t SZ_WLO = BF(1024ull * 1024);
constexpr size_t SZ_WTO = BF(1024ull * 1024);
constexpr size_t SZ_GBUF= 16ull * 1024;            // fp32 [16][1024]
constexpr size_t SZ_DL  = 16ull * 8 * 8192;        // fp32
constexpr size_t SZ_HNG = BF(2048ull * 1024);

constexpr size_t OFF_PQK = 0;
constexpr size_t OFF_PVX = OFF_PQK + SZ_PQK;
constexpr size_t OFF_XH  = OFF_PVX + SZ_PVX;
constexpr size_t OFF_XL  = OFF_XH  + SZ_XH;
constexpr size_t OFF_WHI = OFF_XL  + SZ_XL;
constexpr size_t OFF_WLO = OFF_WHI + SZ_WHI;
constexpr size_t OFF_WTO = OFF_WLO + SZ_WLO;
constexpr size_t OFF_IV  = OFF_WTO + SZ_WTO;
constexpr size_t OFF_FV  = OFF_IV  + SZ_GBUF;
constexpr size_t OFF_G   = OFF_FV  + SZ_GBUF;
constexpr size_t OFF_GM  = OFF_G   + SZ_GBUF;
constexpr size_t OFF_DL  = OFF_GM  + SZ_GBUF;
constexpr size_t OFF_HNG = OFF_DL  + SZ_DL;
constexpr size_t WS_TOTAL = OFF_HNG + SZ_HNG;      // ~11.1M floats = 44.3 MB
static_assert(OFF_XH == OFF_PVX + 2097152, "Pvx is 2048x2048 bf16 = 2,097,152 float slots");

// ---------------- transpose + convert core ----------------
__device__ __forceinline__ void transp_body(
    const float* __restrict__ src,
    unsigned short* __restrict__ hi, unsigned short* __restrict__ lo,
    int N, int nt, int kt, int tid, float (*Ls)[65])
{
  #pragma unroll
  for (int p = 0; p < 16; ++p) {
    int lin = p * 256 + tid;
    int kr = lin >> 6, nc = lin & 63;
    Ls[kr][nc] = src[(size_t)(kt*64 + kr) * N + nt*64 + nc];
  }
  __syncthreads();
  #pragma unroll
  for (int p = 0; p < 16; ++p) {
    int lin = p * 256 + tid;
    int nr = lin >> 6, kc = lin & 63;
    float v = Ls[kc][nr];
    unsigned short h = f2bf(v);
    size_t di = (size_t)(nt*64 + nr) * 1024 + kt*64 + kc;
    hi[di] = h;
    if (lo) lo[di] = f2bf(v - bf2f(h));
  }
}

// ---------------- fused prep: row path (x split + i/f proj) + weight transposes ----------------
__global__ __launch_bounds__(256) void prep(
    const float* __restrict__ x,
    const float* __restrict__ Wi, const float* __restrict__ bi,
    const float* __restrict__ Wf, const float* __restrict__ bf,
    const float* __restrict__ Wq, const float* __restrict__ Wk,
    const float* __restrict__ Wv, const float* __restrict__ Wog,
    const float* __restrict__ Wout,
    unsigned short* __restrict__ xh, unsigned short* __restrict__ xl,
    float* __restrict__ iv, float* __restrict__ fv,
    unsigned short* __restrict__ Whi, unsigned short* __restrict__ Wlo,
    unsigned short* __restrict__ WtO)
{
  __shared__ float Ls[64][65];
  const int bx = blockIdx.x, tid = threadIdx.x;
  if (bx < 512) {
    const int row = bx * 4 + (tid >> 6);
    const int l = tid & 63;
    const float4* xr4 = (const float4*)(x + (size_t)row * NB_D);
    float ai[8] = {}, af[8] = {};
    #pragma unroll
    for (int p = 0; p < 4; ++p) {
      int q4i = l + p * 64;
      float4 xv = xr4[q4i];
      int k0 = q4i * 4;
      const float* xs = (const float*)&xv;
      ushort4v h4, l4;
      #pragma unroll
      for (int j = 0; j < 4; ++j) {
        float xsv = xs[j];
        unsigned short hh = f2bf(xsv);
        h4[j] = hh; l4[j] = f2bf(xsv - bf2f(hh));
        const float4* wi4 = (const float4*)(Wi + (size_t)(k0 + j) * 8);
        const float4* wf4 = (const float4*)(Wf + (size_t)(k0 + j) * 8);
        float4 w0 = wi4[0], w1 = wi4[1];
        float4 v0 = wf4[0], v1 = wf4[1];
        ai[0] += xsv*w0.x; ai[1] += xsv*w0.y; ai[2] += xsv*w0.z; ai[3] += xsv*w0.w;
        ai[4] += xsv*w1.x; ai[5] += xsv*w1.y; ai[6] += xsv*w1.z; ai[7] += xsv*w1.w;
        af[0] += xsv*v0.x; af[1] += xsv*v0.y; af[2] += xsv*v0.z; af[3] += xsv*v0.w;
        af[4] += xsv*v1.x; af[5] += xsv*v1.y; af[6] += xsv*v1.z; af[7] += xsv*v1.w;
      }
      *(ushort4v*)(xh + (size_t)row * NB_D + k0) = h4;
      *(ushort4v*)(xl + (size_t)row * NB_D + k0) = l4;
    }
    #pragma unroll
    for (int off = 1; off < 64; off <<= 1) {
      #pragma unroll
      for (int cc = 0; cc < 8; ++cc) {
        ai[cc] += __shfl_xor(ai[cc], off);
        af[cc] += __shfl_xor(af[cc], off);
      }
    }
    if (l == 0) {
      int b = row >> 10, s = row & (NB_S - 1);
      #pragma unroll
      for (int cc = 0; cc < 8; ++cc) {
        iv[(size_t)(b*NB_NH + cc) * NB_S + s] = ai[cc] + bi[cc];
        fv[(size_t)(b*NB_NH + cc) * NB_S + s] = af[cc] + bf[cc];
      }
    }
  } else {
    const int idx = bx - 512;
    const int xq = idx & 63, kt = idx >> 6;
    if (xq < 8)       transp_body(Wq,   Whi,              Wlo,            512,  xq,      kt, tid, Ls);
    else if (xq < 16) transp_body(Wk,   Whi +  512*1024,  Wlo + 512*1024, 512,  xq - 8,  kt, tid, Ls);
    else if (xq < 32) transp_body(Wv,   Whi + 1024*1024,  nullptr,        1024, xq - 16, kt, tid, Ls);
    else if (xq < 48) transp_body(Wog,  Whi + 2048*1024,  nullptr,        1024, xq - 32, kt, tid, Ls);
    else              transp_body(Wout, WtO,              nullptr,        1024, xq - 48, kt, tid, Ls);
  }
}

// ---------------- fused projection GEMM + gate_scan tail blocks ----------------
// grid 528: blocks [0,512) = GEMM (XCD-swizzled, parity heavy/light);
//           blocks [512,528) = gate scan for bh = bx-512 (wave 0 only).
__global__ __launch_bounds__(256) void gemm_proj(
    const unsigned short* __restrict__ xh,
    const unsigned short* __restrict__ xl,
    const unsigned short* __restrict__ Whi,
    const unsigned short* __restrict__ Wlo,
    float* __restrict__ Pqk, unsigned short* __restrict__ Pvx,
    const float* __restrict__ iv, const float* __restrict__ fv,
    float* __restrict__ gv, float* __restrict__ Gv)
{
  __shared__ __align__(16) char smem[49152];
  const int tid  = threadIdx.x;

  if (blockIdx.x >= 512) {
    // ---- gate scan (one wave per (b,h)) ----
    if (tid >= 64) return;
    const int bh = blockIdx.x - 512, l = tid;
    const int base = bh * NB_S + l * 16;
    float fl[16];
    float run = 0.f;
    #pragma unroll
    for (int u = 0; u < 16; ++u) {
      float fr = fv[base + u];
      float flog = (fr >= 0.f) ? -log1pf(expf(-fr)) : (fr - log1pf(expf(fr)));
      run += flog; fl[u] = run;
    }
    float tot = run, sc = tot;
    #pragma unroll
    for (int off = 1; off < 64; off <<= 1) {
      float t = __shfl_up(sc, off);
      if (l >= off) sc += t;
    }
    float excl = sc - tot;
    float gm[16]; float rmax = -1e30f;
    #pragma unroll
    for (int u = 0; u < 16; ++u) {
      float bt = excl + fl[u];
      float g = iv[base + u] - bt;
      gv[base + u] = g;
      rmax = fmaxf(rmax, g); gm[u] = rmax;
    }
    float mx = rmax;
    #pragma unroll
    for (int off = 1; off < 64; off <<= 1) {
      float t = __shfl_up(mx, off);
      if (l >= off) mx = fmaxf(mx, t);
    }
    float em = __shfl_up(mx, 1);
    if (l == 0) em = -1e30f;
    #pragma unroll
    for (int u = 0; u < 16; ++u)
      Gv[base + u] = fmaxf(0.f, fmaxf(em, gm[u]));
    return;
  }

  const int bid  = ((blockIdx.x & 7) << 6) | (blockIdx.x >> 3);   // XCD swizzle (512 = 8*64)
  const int wid  = tid >> 6, lane = tid & 63;
  const int wm   = wid >> 1, wn = wid & 1;
  const int lrow = lane & 15;
  const int lk   = (lane >> 4) * 16;
  const int srow = tid >> 3;
  const int scb  = (tid & 7) << 4;
  const int ldsW = wid * 1024;

  if (!(bid & 1)) {
    // HEAVY: q,k with split-bf16, M=64
    const int h  = bid >> 1;
    const int ct = h & 7, bm = h >> 3;
    char* Ah = smem;
    char* Al = smem + 8192;
    char* Bh = smem + 16384;
    char* Bl = smem + 32768;
    const char* xhB = (const char*)xh;
    const char* xlB = (const char*)xl;
    const char* whB = (const char*)(Whi + (size_t)ct*128*1024);
    const char* wlB = (const char*)(Wlo + (size_t)ct*128*1024);

    size_t gA[2], gB[4];
    #pragma unroll
    for (int i = 0; i < 2; ++i) {
      int row = i * 32 + srow;
      int cbs = scb ^ ((row & 7) << 4);
      gA[i] = (size_t)(bm*64 + row) * 2048 + cbs;
    }
    #pragma unroll
    for (int i = 0; i < 4; ++i) {
      int row = i * 32 + srow;
      int cbs = scb ^ ((row & 7) << 4);
      gB[i] = (size_t)row * 2048 + cbs;
    }

    f32x4 acc[2][4];
    const f32x4 z4 = { 0.f, 0.f, 0.f, 0.f };
    #pragma unroll
    for (int m = 0; m < 2; ++m)
      #pragma unroll
      for (int n = 0; n < 4; ++n) acc[m][n] = z4;

    for (int kt = 0; kt < 16; ++kt) {
      __syncthreads();
      #pragma unroll
      for (int i = 0; i < 2; ++i) GLD_LDS16(xhB + gA[i] + kt*128, Ah + i*4096 + ldsW);
      #pragma unroll
      for (int i = 0; i < 2; ++i) GLD_LDS16(xlB + gA[i] + kt*128, Al + i*4096 + ldsW);
      #pragma unroll
      for (int i = 0; i < 4; ++i) GLD_LDS16(whB + gB[i] + kt*128, Bh + i*4096 + ldsW);
      #pragma unroll
      for (int i = 0; i < 4; ++i) GLD_LDS16(wlB + gB[i] + kt*128, Bl + i*4096 + ldsW);
      __syncthreads();

      #pragma unroll
      for (int kk = 0; kk < 2; ++kk) {
        short8v ah[2], al[2], bh[4], bl[4];
        #pragma unroll
        for (int m = 0; m < 2; ++m) {
          int row = wm*32 + m*16 + lrow;
          int kb  = (kk*64 + lk) ^ ((row & 7) << 4);
          ah[m] = *(const short8v*)(Ah + row*128 + kb);
          al[m] = *(const short8v*)(Al + row*128 + kb);
        }
        #pragma unroll
        for (int n = 0; n < 4; ++n) {
          int row = wn*64 + n*16 + lrow;
          int kb  = (kk*64 + lk) ^ ((row & 7) << 4);
          bh[n] = *(const short8v*)(Bh + row*128 + kb);
          bl[n] = *(const short8v*)(Bl + row*128 + kb);
        }
        #pragma unroll
        for (int m = 0; m < 2; ++m)
          #pragma unroll
          for (int n = 0; n < 4; ++n) {
            acc[m][n] = MFMA_BF16(ah[m], bh[n], acc[m][n]);
            acc[m][n] = MFMA_BF16(al[m], bh[n], acc[m][n]);
            acc[m][n] = MFMA_BF16(ah[m], bl[n], acc[m][n]);
          }
      }
    }

    const int crow0 = bm*64 + wm*32 + ((lane >> 4) << 2);
    const int ccol0 = ct*128 + wn*64 + lrow;
    #pragma unroll
    for (int m = 0; m < 2; ++m)
      #pragma unroll
      for (int n = 0; n < 4; ++n)
        #pragma unroll
        for (int r = 0; r < 4; ++r)
          Pqk[(size_t)(crow0 + m*16 + r) * 1024 + ccol0 + n*16] = acc[m][n][r];
  } else {
    // LIGHT: v,xog plain bf16, M=128 -> Pvx bf16
    const int l  = bid >> 1;
    const int ct = l & 15, bm = l >> 4;
    char* As = smem;
    char* Bs = smem + 16384;
    const char* xhB = (const char*)xh;
    const char* wB  = (const char*)(Whi + (size_t)(8 + ct)*128*1024);

    size_t gA[4], gB[4];
    #pragma unroll
    for (int i = 0; i < 4; ++i) {
      int row = i * 32 + srow;
      int cbs = scb ^ ((row & 7) << 4);
      gA[i] = (size_t)(bm*128 + row) * 2048 + cbs;
      gB[i] = (size_t)row * 2048 + cbs;
    }

    f32x4 acc[4][4];
    const f32x4 z4 = { 0.f, 0.f, 0.f, 0.f };
    #pragma unroll
    for (int m = 0; m < 4; ++m)
      #pragma unroll
      for (int n = 0; n < 4; ++n) acc[m][n] = z4;

    for (int kt = 0; kt < 16; ++kt) {
      __syncthreads();
      #pragma unroll
      for (int i = 0; i < 4; ++i) GLD_LDS16(xhB + gA[i] + kt*128, As + i*4096 + ldsW);
      #pragma unroll
      for (int i = 0; i < 4; ++i) GLD_LDS16(wB  + gB[i] + kt*128, Bs + i*4096 + ldsW);
      __syncthreads();

      #pragma unroll
      for (int kk = 0; kk < 2; ++kk) {
        short8v a[4], b[4];
        #pragma unroll
        for (int m = 0; m < 4; ++m) {
          int row = wm*64 + m*16 + lrow;
          int kb  = (kk*64 + lk) ^ ((row & 7) << 4);
          a[m] = *(const short8v*)(As + row*128 + kb);
        }
        #pragma unroll
        for (int n = 0; n < 4; ++n) {
          int row = wn*64 + n*16 + lrow;
          int kb  = (kk*64 + lk) ^ ((row & 7) << 4);
          b[n] = *(const short8v*)(Bs + row*128 + kb);
        }
        #pragma unroll
        for (int m = 0; m < 4; ++m)
          #pragma unroll
          for (int n = 0; n < 4; ++n)
            acc[m][n] = MFMA_BF16(a[m], b[n], acc[m][n]);
      }
    }

    const int crow0 = bm*128 + wm*64 + ((lane >> 4) << 2);
    const int ccol0 = ct*128 + wn*64 + lrow;
    #pragma unroll
    for (int m = 0; m < 4; ++m)
      #pragma unroll
      for (int n = 0; n < 4; ++n)
        #pragma unroll
        for (int r = 0; r < 4; ++r)
          Pvx[(size_t)(crow0 + m*16 + r) * 2048 + ccol0 + n*16] = f2bf(acc[m][n][r]);
  }
}

// ---------------- output GEMM: 128x64 tiles, XCD-swizzled 1-D grid (256) ----------------
__global__ __launch_bounds__(256) void gemm_out64(
    const unsigned short* __restrict__ A,
    const unsigned short* __restrict__ Bt,
    float* __restrict__ C, int ldc)
{
  __shared__ __align__(16) unsigned short As[128*64];
  __shared__ __align__(16) unsigned short Bs[64*64];
  const int tid  = threadIdx.x;
  const int bid  = ((blockIdx.x & 7) << 5) | (blockIdx.x >> 3);   // 256 = 8*32
  const int cn   = bid & 15, bm = bid >> 4;
  const int wid  = tid >> 6, lane = tid & 63;
  const int wm   = wid >> 1, wn = wid & 1;
  const int lrow = lane & 15;
  const int lk   = (lane >> 4) * 16;

  f32x4 acc[4][2];
  const f32x4 z4 = { 0.f, 0.f, 0.f, 0.f };
  #pragma unroll
  for (int m = 0; m < 4; ++m)
    #pragma unroll
    for (int n = 0; n < 2; ++n) acc[m][n] = z4;

  const int srow = tid >> 3;
  const int scb  = (tid & 7) << 4;
  const char* Ab = (const char*)A;
  const char* Bb = (const char*)Bt;
  size_t gA[4], gB[2];
  #pragma unroll
  for (int i = 0; i < 4; ++i) {
    int row = i * 32 + srow;
    int cbs = scb ^ ((row & 7) << 4);
    gA[i] = (size_t)(bm*128 + row) * 2048 + cbs;
  }
  #pragma unroll
  for (int i = 0; i < 2; ++i) {
    int row = i * 32 + srow;
    int cbs = scb ^ ((row & 7) << 4);
    gB[i] = (size_t)(cn*64 + row) * 2048 + cbs;
  }
  const int ldsW = wid * 1024;

  for (int kt = 0; kt < 16; ++kt) {
    __syncthreads();
    #pragma unroll
    for (int i = 0; i < 4; ++i)
      GLD_LDS16(Ab + gA[i] + kt*128, (char*)As + i*4096 + ldsW);
    #pragma unroll
    for (int i = 0; i < 2; ++i)
      GLD_LDS16(Bb + gB[i] + kt*128, (char*)Bs + i*4096 + ldsW);
    __syncthreads();

    #pragma unroll
    for (int kk = 0; kk < 2; ++kk) {
      short8v a[4], b[2];
      #pragma unroll
      for (int m = 0; m < 4; ++m) {
        int row = wm*64 + m*16 + lrow;
        int kb  = (kk*64 + lk) ^ ((row & 7) << 4);
        a[m] = *(const short8v*)((const char*)As + row*128 + kb);
      }
      #pragma unroll
      for (int n = 0; n < 2; ++n) {
        int row = wn*32 + n*16 + lrow;
        int kb  = (kk*64 + lk) ^ ((row & 7) << 4);
        b[n] = *(const short8v*)((const char*)Bs + row*128 + kb);
      }
      #pragma unroll
      for (int m = 0; m < 4; ++m)
        #pragma unroll
        for (int n = 0; n < 2; ++n)
          acc[m][n] = MFMA_BF16(a[m], b[n], acc[m][n]);
    }
  }

  const int crow0 = bm*128 + wm*64 + ((lane >> 4) << 2);
  const int ccol0 = cn*64 + wn*32 + (lane & 15);
  #pragma unroll
  for (int m = 0; m < 4; ++m)
    #pragma unroll
    for (int n = 0; n < 2; ++n)
      #pragma unroll
      for (int r = 0; r < 4; ++r)
        C[(size_t)(crow0 + m*16 + r) * ldc + ccol0 + n*16] = acc[m][n][r];
}

// ---------------- per-chunk local KV state (v bf16), j-split: 256 blocks ----------------
// bx (XCD-swizzled): bh = bx>>4, c = (bx>>1)&7, jh = bx&1; block computes Dloc[:, jh*64..+64).
__global__ __launch_bounds__(128) void chunk_local(
    const float* __restrict__ Pqk, const unsigned short* __restrict__ Pvx,
    const float* __restrict__ gv, const float* __restrict__ Gv,
    float* __restrict__ Dloc)
{
  __shared__ float ks[16][68];
  __shared__ float vs[16][68];
  __shared__ float wsg[16];
  const int bx = ((blockIdx.x & 7) << 5) | (blockIdx.x >> 3);   // 256 = 8*32
  const int bh = bx >> 4, c = (bx >> 1) & 7, jh = bx & 1;
  const int b = bh >> 3, h = bh & 7;
  const int tid = threadIdx.x;
  const int rg = tid >> 3, cg = tid & 7;
  const int i0 = rg * 4;
  float acc[4][8] = {};
  const float Gend = Gv[bh*NB_S + c*CL + CL - 1];
  const float* kbp = Pqk + ((size_t)b*NB_S + c*CL) * 1024 + 512 + h*NB_DQK;
  const unsigned short* vbp = Pvx + ((size_t)b*NB_S + c*CL) * 2048 + h*NB_DH + jh*64;
  const float* gbp = gv + bh*NB_S + c*CL;
  for (int sb = 0; sb < 8; ++sb) {
    __syncthreads();
    #pragma unroll
    for (int p = 0; p < 2; ++p) {
      int qd = tid + p*128; int r = qd >> 4, cq = qd & 15;
      *(float4*)(&ks[r][cq*4]) = *(const float4*)(kbp + (size_t)(sb*16 + r)*1024 + cq*4);
    }
    #pragma unroll
    for (int p = 0; p < 2; ++p) {
      int qd = tid + p*128; int r = qd >> 4, cq = qd & 15;
      ushort4v v4 = *(const ushort4v*)(vbp + (size_t)(sb*16 + r)*2048 + cq*4);
      vs[r][cq*4+0] = bf2f(v4[0]); vs[r][cq*4+1] = bf2f(v4[1]);
      vs[r][cq*4+2] = bf2f(v4[2]); vs[r][cq*4+3] = bf2f(v4[3]);
    }
    if (tid < 16) wsg[tid] = expf(gbp[sb*16 + tid] - Gend);
    __syncthreads();
    #pragma unroll
    for (int s = 0; s < 16; ++s) {
      float w = wsg[s];
      float4 kq = *(const float4*)(&ks[s][i0]);
      float wk[4] = { w*kq.x, w*kq.y, w*kq.z, w*kq.w };
      #pragma unroll
      for (int m = 0; m < 2; ++m) {
        float4 vq = *(const float4*)(&vs[s][cg*4 + m*32]);
        #pragma unroll
        for (int u = 0; u < 4; ++u) {
          acc[u][m*4+0] += wk[u]*vq.x;
          acc[u][m*4+1] += wk[u]*vq.y;
          acc[u][m*4+2] += wk[u]*vq.z;
          acc[u][m*4+3] += wk[u]*vq.w;
        }
      }
    }
  }
  float* dst = Dloc + ((size_t)bh*NCH + c) * (NB_DQK*NB_DH) + jh*64;
  #pragma unroll
  for (int u = 0; u < 4; ++u)
    #pragma unroll
    for (int m = 0; m < 2; ++m) {
      float4 o4 = { acc[u][m*4+0], acc[u][m*4+1], acc[u][m*4+2], acc[u][m*4+3] };
      *(float4*)(dst + (size_t)(i0+u)*NB_DH + cg*4 + m*32) = o4;
    }
}

// ---------------- chunked attention via MFMA + inline state combine + LN + gate ----------------
// grid 256 (XCD-swizzled): bh(16) x c(8) x half(2); block = 64 t-rows, 4 waves.
// Cbef computed inline: Cbef[c] = sum_{c'<c} exp(Gend_{c'} - Gend_{c-1}) * Dloc[c'].
__global__ __launch_bounds__(256,1) void chunk_out(
    const float* __restrict__ Pqk, const unsigned short* __restrict__ Pvx,
    const float* __restrict__ gv, const float* __restrict__ Gv,
    const float* __restrict__ Dloc,
    const float* __restrict__ lnw, const float* __restrict__ lnb,
    unsigned short* __restrict__ hng)
{
  __shared__ __align__(16) char smem[131072];
  __shared__ float gsh[128], Gsh[128], rsh[128];
  constexpr int QH = 0, QL = 8192, KH = 16384, KL = 32768;
  constexpr int ATT = 49152, VT = 65536, CBH = 98304, CBL = 114688;

  const int bx = ((blockIdx.x & 7) << 5) | (blockIdx.x >> 3);   // 256 = 8*32
  const int half = bx & 1, c = (bx >> 1) & 7, bh = bx >> 4;
  const int b = bh >> 3, h = bh & 7;
  const int tid = threadIdx.x;
  const int wid = tid >> 6, lane = tid & 63;
  const int lrow = lane & 15;
  const int lkB  = (lane >> 4) * 16;
  const size_t rowbase = (size_t)b*NB_S + (size_t)c*CL;
  const int sgbase = bh*NB_S + c*CL;

  if (tid < 128) {
    float gval = gv[sgbase + tid];
    float Gval = Gv[sgbase + tid];
    gsh[tid] = gval; Gsh[tid] = Gval;
    float Gprev = (c > 0) ? Gv[sgbase - 1] : 0.f;
    rsh[tid] = 0.125f * expf(Gprev - Gval);
  }

  // ---- phase 0: convert operands into swizzled LDS ----
  #pragma unroll
  for (int p = 0; p < 4; ++p) {
    int lin = p*256 + tid;
    int row = lin >> 4, i0 = (lin & 15) * 4;
    float4 v4 = *(const float4*)(Pqk + (rowbase + half*64 + row)*1024 + h*NB_DQK + i0);
    float vv[4] = { v4.x, v4.y, v4.z, v4.w };
    ushort4v h4, l4;
    #pragma unroll
    for (int j = 0; j < 4; ++j) {
      unsigned short hh = f2bf(vv[j]); h4[j] = hh; l4[j] = f2bf(vv[j] - bf2f(hh));
    }
    int off = (row*128 + i0*2) ^ ((row & 7) << 4);
    *(ushort4v*)(smem + QH + off) = h4;
    *(ushort4v*)(smem + QL + off) = l4;
  }
  #pragma unroll
  for (int p = 0; p < 8; ++p) {
    int lin = p*256 + tid;
    int row = lin >> 4, i0 = (lin & 15) * 4;
    float4 v4 = *(const float4*)(Pqk + (rowbase + row)*1024 + 512 + h*NB_DQK + i0);
    float vv[4] = { v4.x, v4.y, v4.z, v4.w };
    ushort4v h4, l4;
    #pragma unroll
    for (int j = 0; j < 4; ++j) {
      unsigned short hh = f2bf(vv[j]); h4[j] = hh; l4[j] = f2bf(vv[j] - bf2f(hh));
    }
    int off = (row*128 + i0*2) ^ ((row & 7) << 4);
    *(ushort4v*)(smem + KH + off) = h4;
    *(ushort4v*)(smem + KL + off) = l4;
  }
  // V^T (bf16 source -> re-layout only)
  #pragma unroll
  for (int p = 0; p < 8; ++p) {
    int lin = p*256 + tid;
    int s = lin >> 4, j0 = (lin & 15) * 8;
    ushort8v v8 = *(const ushort8v*)(Pvx + (rowbase + s)*2048 + h*NB_DH + j0);
    #pragma unroll
    for (int j = 0; j < 8; ++j) {
      int jj = j0 + j;
      int off = (jj*256 + s*2) ^ ((jj & 7) << 4);
      *(unsigned short*)(smem + VT + off) = v8[j];
    }
  }
  // Cb^T hi/lo via closed-form weighted sum of Dloc over previous chunks
  {
    float4 cbacc[8];
    #pragma unroll
    for (int p = 0; p < 8; ++p) cbacc[p] = float4{0.f,0.f,0.f,0.f};
    const float Gcm1 = (c > 0) ? Gv[sgbase - 1] : 0.f;
    for (int cp = 0; cp < c; ++cp) {
      float wgt = expf(Gv[bh*NB_S + cp*CL + CL - 1] - Gcm1);
      const float4* dl4 = (const float4*)(Dloc + ((size_t)bh*NCH + cp)*8192);
      #pragma unroll
      for (int p = 0; p < 8; ++p) {
        float4 d = dl4[p*256 + tid];
        cbacc[p].x += wgt*d.x; cbacc[p].y += wgt*d.y;
        cbacc[p].z += wgt*d.z; cbacc[p].w += wgt*d.w;
      }
    }
    #pragma unroll
    for (int p = 0; p < 8; ++p) {
      int lin = p*256 + tid;
      int i = lin >> 5, j0 = (lin & 31) * 4;
      float vv[4] = { cbacc[p].x, cbacc[p].y, cbacc[p].z, cbacc[p].w };
      #pragma unroll
      for (int w = 0; w < 4; ++w) {
        int jj = j0 + w;
        int off = (jj*128 + i*2) ^ ((jj & 7) << 4);
        unsigned short hh = f2bf(vv[w]);
        *(unsigned short*)(smem + CBH + off) = hh;
        *(unsigned short*)(smem + CBL + off) = f2bf(vv[w] - bf2f(hh));
      }
    }
  }
  __syncthreads();

  const f32x4 z4 = { 0.f, 0.f, 0.f, 0.f };
  const int trow = wid*16 + lrow;

  // ---- phase 1a: S = q k^T (split-bf16), weight+mask -> att (bf16) ----
  f32x4 sacc[8];
  #pragma unroll
  for (int n = 0; n < 8; ++n) sacc[n] = z4;
  #pragma unroll
  for (int kk = 0; kk < 2; ++kk) {
    int qb = kk*64 + lkB;
    int ab = (trow*128 + qb) ^ ((trow & 7) << 4);
    short8v aqh = *(const short8v*)(smem + QH + ab);
    short8v aql = *(const short8v*)(smem + QL + ab);
    #pragma unroll
    for (int n = 0; n < 8; ++n) {
      int srw = n*16 + lrow;
      int bb = (srw*128 + qb) ^ ((srw & 7) << 4);
      short8v bkh = *(const short8v*)(smem + KH + bb);
      short8v bkl = *(const short8v*)(smem + KL + bb);
      sacc[n] = MFMA_BF16(aqh, bkh, sacc[n]);
      sacc[n] = MFMA_BF16(aql, bkh, sacc[n]);
      sacc[n] = MFMA_BF16(aqh, bkl, sacc[n]);
    }
  }
  {
    int td[4]; float gt[4];
    #pragma unroll
    for (int r = 0; r < 4; ++r) {
      td[r] = wid*16 + ((lane >> 4) << 2) + r;
      gt[r] = Gsh[half*64 + td[r]];
    }
    #pragma unroll
    for (int n = 0; n < 8; ++n) {
      int s = n*16 + lrow;
      float gs = gsh[s];
      #pragma unroll
      for (int r = 0; r < 4; ++r) {
        float w = 0.125f * expf(gs - gt[r]);
        float val = (s <= half*64 + td[r]) ? sacc[n][r]*w : 0.f;
        int off = (td[r]*256 + s*2) ^ ((td[r] & 7) << 4);
        *(unsigned short*)(smem + ATT + off) = f2bf(val);
      }
    }
  }

  // ---- phase 1b: state term h2 = q * Cbef (split-bf16) ----
  f32x4 h2[8];
  #pragma unroll
  for (int n = 0; n < 8; ++n) h2[n] = z4;
  #pragma unroll
  for (int kk = 0; kk < 2; ++kk) {
    int qb = kk*64 + lkB;
    int ab = (trow*128 + qb) ^ ((trow & 7) << 4);
    short8v aqh = *(const short8v*)(smem + QH + ab);
    short8v aql = *(const short8v*)(smem + QL + ab);
    #pragma unroll
    for (int n = 0; n < 8; ++n) {
      int jrw = n*16 + lrow;
      int bb = (jrw*128 + qb) ^ ((jrw & 7) << 4);
      short8v bch = *(const short8v*)(smem + CBH + bb);
      short8v bcl = *(const short8v*)(smem + CBL + bb);
      h2[n] = MFMA_BF16(aqh, bch, h2[n]);
      h2[n] = MFMA_BF16(aql, bch, h2[n]);
      h2[n] = MFMA_BF16(aqh, bcl, h2[n]);
    }
  }
  __syncthreads();

  // ---- phase 2: PV: h1 = att * V ----
  f32x4 h1[8];
  #pragma unroll
  for (int n = 0; n < 8; ++n) h1[n] = z4;
  #pragma unroll
  for (int kk = 0; kk < 4; ++kk) {
    int ab = (trow*256 + kk*64 + lkB) ^ ((trow & 7) << 4);
    short8v aat = *(const short8v*)(smem + ATT + ab);
    #pragma unroll
    for (int n = 0; n < 8; ++n) {
      int jrw = n*16 + lrow;
      int bb = (jrw*256 + kk*64 + lkB) ^ ((jrw & 7) << 4);
      short8v bvt = *(const short8v*)(smem + VT + bb);
      h1[n] = MFMA_BF16(aat, bvt, h1[n]);
    }
  }
  __syncthreads();

  // ---- phase 3: combine, stage H in LDS, epilogue ----
  float* Hb = (float*)smem;
  {
    #pragma unroll
    for (int r = 0; r < 4; ++r) {
      int tl = wid*16 + ((lane >> 4) << 2) + r;
      float rr = rsh[half*64 + tl];
      #pragma unroll
      for (int n = 0; n < 8; ++n)
        Hb[tl*132 + n*16 + lrow] = h1[n][r] + rr*h2[n][r];
    }
  }
  __syncthreads();

  const int tr = tid >> 4, tc = tid & 15;
  float lw[8], lb[8];
  {
    float4 a0 = *(const float4*)(lnw + h*NB_DH + tc*4);
    float4 a1 = *(const float4*)(lnw + h*NB_DH + tc*4 + 64);
    lw[0]=a0.x; lw[1]=a0.y; lw[2]=a0.z; lw[3]=a0.w;
    lw[4]=a1.x; lw[5]=a1.y; lw[6]=a1.z; lw[7]=a1.w;
    float4 b0 = *(const float4*)(lnb + h*NB_DH + tc*4);
    float4 b1 = *(const float4*)(lnb + h*NB_DH + tc*4 + 64);
    lb[0]=b0.x; lb[1]=b0.y; lb[2]=b0.z; lb[3]=b0.w;
    lb[4]=b1.x; lb[5]=b1.y; lb[6]=b1.z; lb[7]=b1.w;
  }
  #pragma unroll
  for (int u = 0; u < 4; ++u) {
    int tl = tr*4 + u;
    int t  = half*64 + tl;
    float hrow[8];
    float4 hl0 = *(const float4*)(&Hb[tl*132 + tc*4]);
    float4 hl1 = *(const float4*)(&Hb[tl*132 + tc*4 + 64]);
    hrow[0]=hl0.x; hrow[1]=hl0.y; hrow[2]=hl0.z; hrow[3]=hl0.w;
    hrow[4]=hl1.x; hrow[5]=hl1.y; hrow[6]=hl1.z; hrow[7]=hl1.w;
    float sum = 0.f, ssq = 0.f;
    #pragma unroll
    for (int x = 0; x < 8; ++x) { sum += hrow[x]; ssq += hrow[x]*hrow[x]; }
    #pragma unroll
    for (int off = 1; off < 16; off <<= 1) {
      sum += __shfl_xor(sum, off);
      ssq += __shfl_xor(ssq, off);
    }
    float mean = sum * (1.f/NB_DH);
    float var  = ssq * (1.f/NB_DH) - mean*mean;
    float rstd = rsqrtf(var + 1e-6f);
    #pragma unroll
    for (int m = 0; m < 2; ++m) {
      ushort4v xo4 = *(const ushort4v*)(Pvx + (rowbase + t)*2048 + 1024 + h*NB_DH + tc*4 + m*64);
      float xov[4] = { bf2f(xo4[0]), bf2f(xo4[1]), bf2f(xo4[2]), bf2f(xo4[3]) };
      unsigned short res[4];
      #pragma unroll
      for (int w = 0; w < 4; ++w) {
        int x = m*4 + w;
        float hn = (hrow[x] - mean)*rstd*lw[x] + lb[x];
        float tt = tanhf(xov[w]*(1.f/15.f))*15.f;
        float o = 1.f/(1.f + expf(-tt));
        res[w] = f2bf(hn*o);
      }
      ushort4v r4 = { res[0], res[1], res[2], res[3] };
      *(ushort4v*)(hng + (rowbase + t)*1024 + h*NB_DH + tc*4 + m*64) = r4;
    }
  }
}

extern "C" void kernel_launch(void* const* d_in, const int* in_sizes, int n_in,
                              void* d_out, int out_size, void* d_ws, size_t ws_size,
                              hipStream_t stream)
{
  (void)in_sizes; (void)n_in; (void)out_size; (void)ws_size;
  const float* x   = (const float*)d_in[0];
  const float* Wq  = (const float*)d_in[1];
  const float* Wk  = (const float*)d_in[2];
  const float* Wv  = (const float*)d_in[3];
  const float* Wi  = (const float*)d_in[4];
  const float* bi  = (const float*)d_in[5];
  const float* Wf  = (const float*)d_in[6];
  const float* bf  = (const float*)d_in[7];
  const float* Wog = (const float*)d_in[8];
  const float* lnw = (const float*)d_in[9];
  const float* lnb = (const float*)d_in[10];
  const float* Wout= (const float*)d_in[11];
  float* out = (float*)d_out;
  float* ws  = (float*)d_ws;

  float*          Pqk = ws + OFF_PQK;
  unsigned short* Pvx = (unsigned short*)(ws + OFF_PVX);
  unsigned short* xh  = (unsigned short*)(ws + OFF_XH);
  unsigned short* xl  = (unsigned short*)(ws + OFF_XL);
  unsigned short* Whi = (unsigned short*)(ws + OFF_WHI);
  unsigned short* Wlo = (unsigned short*)(ws + OFF_WLO);
  unsigned short* WtO = (unsigned short*)(ws + OFF_WTO);
  float*          iv  = ws + OFF_IV;
  float*          fv  = ws + OFF_FV;
  float*          g   = ws + OFF_G;
  float*          G   = ws + OFF_GM;
  float*          Dl  = ws + OFF_DL;
  unsigned short* hng = (unsigned short*)(ws + OFF_HNG);

  prep     <<<1536, 256, 0, stream>>>(x, Wi, bi, Wf, bf, Wq, Wk, Wv, Wog, Wout,
                                      xh, xl, iv, fv, Whi, Wlo, WtO);

  // GEMM (blocks 0..511) + gate_scan (blocks 512..527) in one dispatch
  gemm_proj<<<528, 256, 0, stream>>>(xh, xl, Whi, Wlo, Pqk, Pvx, iv, fv, g, G);

  chunk_local<<<256, 128, 0, stream>>>(Pqk, Pvx, g, G, Dl);
  chunk_out  <<<256, 256, 0, stream>>>(Pqk, Pvx, g, G, Dl, lnw, lnb, hng);

  gemm_out64 <<<256, 256, 0, stream>>>(hng, WtO, out, 1024);
}

// Round 13
// 108.973 us; speedup vs baseline: 1.6628x; 1.0086x over previous
//
#include <hip/hip_runtime.h>
#include <math.h>

#define NB_B   2
#define NB_S   1024
#define NB_D   1024
#define NB_NH  8
#define NB_DQK 64
#define NB_DH  128
#define NCH    8
#define CL     128

typedef __attribute__((ext_vector_type(8))) short  short8v;   // 8 x bf16
typedef __attribute__((ext_vector_type(4))) float  f32x4;
typedef __attribute__((ext_vector_type(8))) unsigned short ushort8v;
typedef __attribute__((ext_vector_type(4))) unsigned short ushort4v;

__device__ __forceinline__ unsigned short f2bf(float f) {
  unsigned u = __float_as_uint(f);
  unsigned r = (u + 0x7FFFu + ((u >> 16) & 1u)) >> 16;
  return (unsigned short)r;
}
__device__ __forceinline__ float bf2f(unsigned short h) {
  return __uint_as_float(((unsigned)h) << 16);
}

#define GLD_LDS16(g, l) __builtin_amdgcn_global_load_lds( \
    (const __attribute__((address_space(1))) void*)(g),   \
    (__attribute__((address_space(3))) void*)(l), 16, 0, 0)

#define MFMA_BF16(a, b, c) __builtin_amdgcn_mfma_f32_16x16x32_bf16((a), (b), (c), 0, 0, 0)

// ---------------- workspace map (units: FLOAT SLOTS) ----------------
// BF(n): n bf16 elements occupy n/2 float slots. Every offset derived.
constexpr size_t BF(size_t elems) { return elems / 2; }
constexpr size_t SZ_QK1 = BF(2048ull * 512);       // one of Qh/Ql/Kh/Kl
constexpr size_t SZ_PVX = BF(2048ull * 2048);      // bf16 [2048][2048]
constexpr size_t SZ_XH  = BF(2048ull * 1024);
constexpr size_t SZ_XL  = BF(2048ull * 1024);
constexpr size_t SZ_WHI = BF(3072ull * 1024);
constexpr size_t SZ_WLO = BF(1024ull * 1024);
constexpr size_t SZ_WTO = BF(1024ull * 1024);
constexpr size_t SZ_GBUF= 16ull * 1024;            // fp32 [16][1024]
constexpr size_t SZ_DL  = 16ull * 8 * 8192;        // fp32
constexpr size_t SZ_HNG = BF(2048ull * 1024);

constexpr size_t OFF_QH  = 0;
constexpr size_t OFF_QL  = OFF_QH  + SZ_QK1;
constexpr size_t OFF_KH  = OFF_QL  + SZ_QK1;
constexpr size_t OFF_KL  = OFF_KH  + SZ_QK1;
constexpr size_t OFF_PVX = OFF_KL  + SZ_QK1;
constexpr size_t OFF_XH  = OFF_PVX + SZ_PVX;
constexpr size_t OFF_XL  = OFF_XH  + SZ_XH;
constexpr size_t OFF_WHI = OFF_XL  + SZ_XL;
constexpr size_t OFF_WLO = OFF_WHI + SZ_WHI;
constexpr size_t OFF_WTO = OFF_WLO + SZ_WLO;
constexpr size_t OFF_IV  = OFF_WTO + SZ_WTO;
constexpr size_t OFF_FV  = OFF_IV  + SZ_GBUF;
constexpr size_t OFF_G   = OFF_FV  + SZ_GBUF;
constexpr size_t OFF_GM  = OFF_G   + SZ_GBUF;
constexpr size_t OFF_DL  = OFF_GM  + SZ_GBUF;
constexpr size_t OFF_HNG = OFF_DL  + SZ_DL;
constexpr size_t WS_TOTAL = OFF_HNG + SZ_HNG;      // ~11.1M floats = 44.3 MB
static_assert(OFF_PVX == 2097152, "Qh+Ql+Kh+Kl must equal old Pqk footprint");
static_assert(SZ_QK1 == 524288, "each qk plane is 2048x512 bf16 = 524,288 float slots");

// ---------------- transpose + convert core ----------------
__device__ __forceinline__ void transp_body(
    const float* __restrict__ src,
    unsigned short* __restrict__ hi, unsigned short* __restrict__ lo,
    int N, int nt, int kt, int tid, float (*Ls)[65])
{
  #pragma unroll
  for (int p = 0; p < 16; ++p) {
    int lin = p * 256 + tid;
    int kr = lin >> 6, nc = lin & 63;
    Ls[kr][nc] = src[(size_t)(kt*64 + kr) * N + nt*64 + nc];
  }
  __syncthreads();
  #pragma unroll
  for (int p = 0; p < 16; ++p) {
    int lin = p * 256 + tid;
    int nr = lin >> 6, kc = lin & 63;
    float v = Ls[kc][nr];
    unsigned short h = f2bf(v);
    size_t di = (size_t)(nt*64 + nr) * 1024 + kt*64 + kc;
    hi[di] = h;
    if (lo) lo[di] = f2bf(v - bf2f(h));
  }
}

// ---------------- fused prep: row path (x split + i/f proj) + weight transposes ----------------
__global__ __launch_bounds__(256) void prep(
    const float* __restrict__ x,
    const float* __restrict__ Wi, const float* __restrict__ bi,
    const float* __restrict__ Wf, const float* __restrict__ bf,
    const float* __restrict__ Wq, const float* __restrict__ Wk,
    const float* __restrict__ Wv, const float* __restrict__ Wog,
    const float* __restrict__ Wout,
    unsigned short* __restrict__ xh, unsigned short* __restrict__ xl,
    float* __restrict__ iv, float* __restrict__ fv,
    unsigned short* __restrict__ Whi, unsigned short* __restrict__ Wlo,
    unsigned short* __restrict__ WtO)
{
  __shared__ float Ls[64][65];
  const int bx = blockIdx.x, tid = threadIdx.x;
  if (bx < 512) {
    const int row = bx * 4 + (tid >> 6);
    const int l = tid & 63;
    const float4* xr4 = (const float4*)(x + (size_t)row * NB_D);
    float ai[8] = {}, af[8] = {};
    #pragma unroll
    for (int p = 0; p < 4; ++p) {
      int q4i = l + p * 64;
      float4 xv = xr4[q4i];
      int k0 = q4i * 4;
      const float* xs = (const float*)&xv;
      ushort4v h4, l4;
      #pragma unroll
      for (int j = 0; j < 4; ++j) {
        float xsv = xs[j];
        unsigned short hh = f2bf(xsv);
        h4[j] = hh; l4[j] = f2bf(xsv - bf2f(hh));
        const float4* wi4 = (const float4*)(Wi + (size_t)(k0 + j) * 8);
        const float4* wf4 = (const float4*)(Wf + (size_t)(k0 + j) * 8);
        float4 w0 = wi4[0], w1 = wi4[1];
        float4 v0 = wf4[0], v1 = wf4[1];
        ai[0] += xsv*w0.x; ai[1] += xsv*w0.y; ai[2] += xsv*w0.z; ai[3] += xsv*w0.w;
        ai[4] += xsv*w1.x; ai[5] += xsv*w1.y; ai[6] += xsv*w1.z; ai[7] += xsv*w1.w;
        af[0] += xsv*v0.x; af[1] += xsv*v0.y; af[2] += xsv*v0.z; af[3] += xsv*v0.w;
        af[4] += xsv*v1.x; af[5] += xsv*v1.y; af[6] += xsv*v1.z; af[7] += xsv*v1.w;
      }
      *(ushort4v*)(xh + (size_t)row * NB_D + k0) = h4;
      *(ushort4v*)(xl + (size_t)row * NB_D + k0) = l4;
    }
    #pragma unroll
    for (int off = 1; off < 64; off <<= 1) {
      #pragma unroll
      for (int cc = 0; cc < 8; ++cc) {
        ai[cc] += __shfl_xor(ai[cc], off);
        af[cc] += __shfl_xor(af[cc], off);
      }
    }
    if (l == 0) {
      int b = row >> 10, s = row & (NB_S - 1);
      #pragma unroll
      for (int cc = 0; cc < 8; ++cc) {
        iv[(size_t)(b*NB_NH + cc) * NB_S + s] = ai[cc] + bi[cc];
        fv[(size_t)(b*NB_NH + cc) * NB_S + s] = af[cc] + bf[cc];
      }
    }
  } else {
    const int idx = bx - 512;
    const int xq = idx & 63, kt = idx >> 6;
    if (xq < 8)       transp_body(Wq,   Whi,              Wlo,            512,  xq,      kt, tid, Ls);
    else if (xq < 16) transp_body(Wk,   Whi +  512*1024,  Wlo + 512*1024, 512,  xq - 8,  kt, tid, Ls);
    else if (xq < 32) transp_body(Wv,   Whi + 1024*1024,  nullptr,        1024, xq - 16, kt, tid, Ls);
    else if (xq < 48) transp_body(Wog,  Whi + 2048*1024,  nullptr,        1024, xq - 32, kt, tid, Ls);
    else              transp_body(Wout, WtO,              nullptr,        1024, xq - 48, kt, tid, Ls);
  }
}

// ---------------- fused projection GEMM + gate_scan head blocks ----------------
// grid 528: blocks [0,16) = gate scan (runs first, retires in GEMM's shadow);
//           blocks [16,528) = GEMM (XCD-swizzled, parity heavy/light).
// Heavy epilogue writes q,k pre-split to Qh/Ql/Kh/Kl bf16 [2048][512].
__global__ __launch_bounds__(256) void gemm_proj(
    const unsigned short* __restrict__ xh,
    const unsigned short* __restrict__ xl,
    const unsigned short* __restrict__ Whi,
    const unsigned short* __restrict__ Wlo,
    unsigned short* __restrict__ Qh, unsigned short* __restrict__ Ql,
    unsigned short* __restrict__ Kh, unsigned short* __restrict__ Kl,
    unsigned short* __restrict__ Pvx,
    const float* __restrict__ iv, const float* __restrict__ fv,
    float* __restrict__ gv, float* __restrict__ Gv)
{
  __shared__ __align__(16) char smem[49152];
  const int tid  = threadIdx.x;

  if (blockIdx.x < 16) {
    // ---- gate scan (one wave per (b,h)) ----
    if (tid >= 64) return;
    const int bh = blockIdx.x, l = tid;
    const int base = bh * NB_S + l * 16;
    float fl[16];
    float run = 0.f;
    #pragma unroll
    for (int u = 0; u < 16; ++u) {
      float fr = fv[base + u];
      float flog = (fr >= 0.f) ? -log1pf(expf(-fr)) : (fr - log1pf(expf(fr)));
      run += flog; fl[u] = run;
    }
    float tot = run, sc = tot;
    #pragma unroll
    for (int off = 1; off < 64; off <<= 1) {
      float t = __shfl_up(sc, off);
      if (l >= off) sc += t;
    }
    float excl = sc - tot;
    float gm[16]; float rmax = -1e30f;
    #pragma unroll
    for (int u = 0; u < 16; ++u) {
      float bt = excl + fl[u];
      float g = iv[base + u] - bt;
      gv[base + u] = g;
      rmax = fmaxf(rmax, g); gm[u] = rmax;
    }
    float mx = rmax;
    #pragma unroll
    for (int off = 1; off < 64; off <<= 1) {
      float t = __shfl_up(mx, off);
      if (l >= off) mx = fmaxf(mx, t);
    }
    float em = __shfl_up(mx, 1);
    if (l == 0) em = -1e30f;
    #pragma unroll
    for (int u = 0; u < 16; ++u)
      Gv[base + u] = fmaxf(0.f, fmaxf(em, gm[u]));
    return;
  }

  const int gx   = blockIdx.x - 16;                      // 0..511
  const int bid  = ((gx & 7) << 6) | (gx >> 3);          // XCD swizzle (512 = 8*64)
  const int wid  = tid >> 6, lane = tid & 63;
  const int wm   = wid >> 1, wn = wid & 1;
  const int lrow = lane & 15;
  const int lk   = (lane >> 4) * 16;
  const int srow = tid >> 3;
  const int scb  = (tid & 7) << 4;
  const int ldsW = wid * 1024;

  if (!(bid & 1)) {
    // HEAVY: q,k with split-bf16, M=64
    const int h  = bid >> 1;
    const int ct = h & 7, bm = h >> 3;
    char* Ah = smem;
    char* Al = smem + 8192;
    char* Bh = smem + 16384;
    char* Bl = smem + 32768;
    const char* xhB = (const char*)xh;
    const char* xlB = (const char*)xl;
    const char* whB = (const char*)(Whi + (size_t)ct*128*1024);
    const char* wlB = (const char*)(Wlo + (size_t)ct*128*1024);

    size_t gA[2], gB[4];
    #pragma unroll
    for (int i = 0; i < 2; ++i) {
      int row = i * 32 + srow;
      int cbs = scb ^ ((row & 7) << 4);
      gA[i] = (size_t)(bm*64 + row) * 2048 + cbs;
    }
    #pragma unroll
    for (int i = 0; i < 4; ++i) {
      int row = i * 32 + srow;
      int cbs = scb ^ ((row & 7) << 4);
      gB[i] = (size_t)row * 2048 + cbs;
    }

    f32x4 acc[2][4];
    const f32x4 z4 = { 0.f, 0.f, 0.f, 0.f };
    #pragma unroll
    for (int m = 0; m < 2; ++m)
      #pragma unroll
      for (int n = 0; n < 4; ++n) acc[m][n] = z4;

    for (int kt = 0; kt < 16; ++kt) {
      __syncthreads();
      #pragma unroll
      for (int i = 0; i < 2; ++i) GLD_LDS16(xhB + gA[i] + kt*128, Ah + i*4096 + ldsW);
      #pragma unroll
      for (int i = 0; i < 2; ++i) GLD_LDS16(xlB + gA[i] + kt*128, Al + i*4096 + ldsW);
      #pragma unroll
      for (int i = 0; i < 4; ++i) GLD_LDS16(whB + gB[i] + kt*128, Bh + i*4096 + ldsW);
      #pragma unroll
      for (int i = 0; i < 4; ++i) GLD_LDS16(wlB + gB[i] + kt*128, Bl + i*4096 + ldsW);
      __syncthreads();

      #pragma unroll
      for (int kk = 0; kk < 2; ++kk) {
        short8v ah[2], al[2], bh[4], bl[4];
        #pragma unroll
        for (int m = 0; m < 2; ++m) {
          int row = wm*32 + m*16 + lrow;
          int kb  = (kk*64 + lk) ^ ((row & 7) << 4);
          ah[m] = *(const short8v*)(Ah + row*128 + kb);
          al[m] = *(const short8v*)(Al + row*128 + kb);
        }
        #pragma unroll
        for (int n = 0; n < 4; ++n) {
          int row = wn*64 + n*16 + lrow;
          int kb  = (kk*64 + lk) ^ ((row & 7) << 4);
          bh[n] = *(const short8v*)(Bh + row*128 + kb);
          bl[n] = *(const short8v*)(Bl + row*128 + kb);
        }
        #pragma unroll
        for (int m = 0; m < 2; ++m)
          #pragma unroll
          for (int n = 0; n < 4; ++n) {
            acc[m][n] = MFMA_BF16(ah[m], bh[n], acc[m][n]);
            acc[m][n] = MFMA_BF16(al[m], bh[n], acc[m][n]);
            acc[m][n] = MFMA_BF16(ah[m], bl[n], acc[m][n]);
          }
      }
    }

    const int crow0 = bm*64 + wm*32 + ((lane >> 4) << 2);
    const int ccol0 = (ct & 3)*128 + wn*64 + lrow;        // col within 512
    unsigned short* Hd = (ct < 4) ? Qh : Kh;
    unsigned short* Ld = (ct < 4) ? Ql : Kl;
    #pragma unroll
    for (int m = 0; m < 2; ++m)
      #pragma unroll
      for (int n = 0; n < 4; ++n)
        #pragma unroll
        for (int r = 0; r < 4; ++r) {
          float v = acc[m][n][r];
          unsigned short hh = f2bf(v);
          size_t idx = (size_t)(crow0 + m*16 + r) * 512 + ccol0 + n*16;
          Hd[idx] = hh;
          Ld[idx] = f2bf(v - bf2f(hh));
        }
  } else {
    // LIGHT: v,xog plain bf16, M=128 -> Pvx bf16
    const int l  = bid >> 1;
    const int ct = l & 15, bm = l >> 4;
    char* As = smem;
    char* Bs = smem + 16384;
    const char* xhB = (const char*)xh;
    const char* wB  = (const char*)(Whi + (size_t)(8 + ct)*128*1024);

    size_t gA[4], gB[4];
    #pragma unroll
    for (int i = 0; i < 4; ++i) {
      int row = i * 32 + srow;
      int cbs = scb ^ ((row & 7) << 4);
      gA[i] = (size_t)(bm*128 + row) * 2048 + cbs;
      gB[i] = (size_t)row * 2048 + cbs;
    }

    f32x4 acc[4][4];
    const f32x4 z4 = { 0.f, 0.f, 0.f, 0.f };
    #pragma unroll
    for (int m = 0; m < 4; ++m)
      #pragma unroll
      for (int n = 0; n < 4; ++n) acc[m][n] = z4;

    for (int kt = 0; kt < 16; ++kt) {
      __syncthreads();
      #pragma unroll
      for (int i = 0; i < 4; ++i) GLD_LDS16(xhB + gA[i] + kt*128, As + i*4096 + ldsW);
      #pragma unroll
      for (int i = 0; i < 4; ++i) GLD_LDS16(wB  + gB[i] + kt*128, Bs + i*4096 + ldsW);
      __syncthreads();

      #pragma unroll
      for (int kk = 0; kk < 2; ++kk) {
        short8v a[4], b[4];
        #pragma unroll
        for (int m = 0; m < 4; ++m) {
          int row = wm*64 + m*16 + lrow;
          int kb  = (kk*64 + lk) ^ ((row & 7) << 4);
          a[m] = *(const short8v*)(As + row*128 + kb);
        }
        #pragma unroll
        for (int n = 0; n < 4; ++n) {
          int row = wn*64 + n*16 + lrow;
          int kb  = (kk*64 + lk) ^ ((row & 7) << 4);
          b[n] = *(const short8v*)(Bs + row*128 + kb);
        }
        #pragma unroll
        for (int m = 0; m < 4; ++m)
          #pragma unroll
          for (int n = 0; n < 4; ++n)
            acc[m][n] = MFMA_BF16(a[m], b[n], acc[m][n]);
      }
    }

    const int crow0 = bm*128 + wm*64 + ((lane >> 4) << 2);
    const int ccol0 = ct*128 + wn*64 + lrow;
    #pragma unroll
    for (int m = 0; m < 4; ++m)
      #pragma unroll
      for (int n = 0; n < 4; ++n)
        #pragma unroll
        for (int r = 0; r < 4; ++r)
          Pvx[(size_t)(crow0 + m*16 + r) * 2048 + ccol0 + n*16] = f2bf(acc[m][n][r]);
  }
}

// ---------------- output GEMM: 128x64 tiles, XCD-swizzled 1-D grid (256) ----------------
__global__ __launch_bounds__(256) void gemm_out64(
    const unsigned short* __restrict__ A,
    const unsigned short* __restrict__ Bt,
    float* __restrict__ C, int ldc)
{
  __shared__ __align__(16) unsigned short As[128*64];
  __shared__ __align__(16) unsigned short Bs[64*64];
  const int tid  = threadIdx.x;
  const int bid  = ((blockIdx.x & 7) << 5) | (blockIdx.x >> 3);   // 256 = 8*32
  const int cn   = bid & 15, bm = bid >> 4;
  const int wid  = tid >> 6, lane = tid & 63;
  const int wm   = wid >> 1, wn = wid & 1;
  const int lrow = lane & 15;
  const int lk   = (lane >> 4) * 16;

  f32x4 acc[4][2];
  const f32x4 z4 = { 0.f, 0.f, 0.f, 0.f };
  #pragma unroll
  for (int m = 0; m < 4; ++m)
    #pragma unroll
    for (int n = 0; n < 2; ++n) acc[m][n] = z4;

  const int srow = tid >> 3;
  const int scb  = (tid & 7) << 4;
  const char* Ab = (const char*)A;
  const char* Bb = (const char*)Bt;
  size_t gA[4], gB[2];
  #pragma unroll
  for (int i = 0; i < 4; ++i) {
    int row = i * 32 + srow;
    int cbs = scb ^ ((row & 7) << 4);
    gA[i] = (size_t)(bm*128 + row) * 2048 + cbs;
  }
  #pragma unroll
  for (int i = 0; i < 2; ++i) {
    int row = i * 32 + srow;
    int cbs = scb ^ ((row & 7) << 4);
    gB[i] = (size_t)(cn*64 + row) * 2048 + cbs;
  }
  const int ldsW = wid * 1024;

  for (int kt = 0; kt < 16; ++kt) {
    __syncthreads();
    #pragma unroll
    for (int i = 0; i < 4; ++i)
      GLD_LDS16(Ab + gA[i] + kt*128, (char*)As + i*4096 + ldsW);
    #pragma unroll
    for (int i = 0; i < 2; ++i)
      GLD_LDS16(Bb + gB[i] + kt*128, (char*)Bs + i*4096 + ldsW);
    __syncthreads();

    #pragma unroll
    for (int kk = 0; kk < 2; ++kk) {
      short8v a[4], b[2];
      #pragma unroll
      for (int m = 0; m < 4; ++m) {
        int row = wm*64 + m*16 + lrow;
        int kb  = (kk*64 + lk) ^ ((row & 7) << 4);
        a[m] = *(const short8v*)((const char*)As + row*128 + kb);
      }
      #pragma unroll
      for (int n = 0; n < 2; ++n) {
        int row = wn*32 + n*16 + lrow;
        int kb  = (kk*64 + lk) ^ ((row & 7) << 4);
        b[n] = *(const short8v*)((const char*)Bs + row*128 + kb);
      }
      #pragma unroll
      for (int m = 0; m < 4; ++m)
        #pragma unroll
        for (int n = 0; n < 2; ++n)
          acc[m][n] = MFMA_BF16(a[m], b[n], acc[m][n]);
    }
  }

  const int crow0 = bm*128 + wm*64 + ((lane >> 4) << 2);
  const int ccol0 = cn*64 + wn*32 + (lane & 15);
  #pragma unroll
  for (int m = 0; m < 4; ++m)
    #pragma unroll
    for (int n = 0; n < 2; ++n)
      #pragma unroll
      for (int r = 0; r < 4; ++r)
        C[(size_t)(crow0 + m*16 + r) * ldc + ccol0 + n*16] = acc[m][n][r];
}

// ---------------- per-chunk local KV state (k,v bf16), j-split: 256 blocks ----------------
__global__ __launch_bounds__(128) void chunk_local(
    const unsigned short* __restrict__ Kh, const unsigned short* __restrict__ Pvx,
    const float* __restrict__ gv, const float* __restrict__ Gv,
    float* __restrict__ Dloc)
{
  __shared__ float ks[16][68];
  __shared__ float vs[16][68];
  __shared__ float wsg[16];
  const int bx = ((blockIdx.x & 7) << 5) | (blockIdx.x >> 3);   // 256 = 8*32
  const int bh = bx >> 4, c = (bx >> 1) & 7, jh = bx & 1;
  const int b = bh >> 3, h = bh & 7;
  const int tid = threadIdx.x;
  const int rg = tid >> 3, cg = tid & 7;
  const int i0 = rg * 4;
  float acc[4][8] = {};
  const float Gend = Gv[bh*NB_S + c*CL + CL - 1];
  const unsigned short* kbp = Kh + ((size_t)b*NB_S + c*CL) * 512 + h*NB_DQK;
  const unsigned short* vbp = Pvx + ((size_t)b*NB_S + c*CL) * 2048 + h*NB_DH + jh*64;
  const float* gbp = gv + bh*NB_S + c*CL;
  for (int sb = 0; sb < 8; ++sb) {
    __syncthreads();
    #pragma unroll
    for (int p = 0; p < 2; ++p) {
      int qd = tid + p*128; int r = qd >> 4, cq = qd & 15;
      ushort4v k4 = *(const ushort4v*)(kbp + (size_t)(sb*16 + r)*512 + cq*4);
      ks[r][cq*4+0] = bf2f(k4[0]); ks[r][cq*4+1] = bf2f(k4[1]);
      ks[r][cq*4+2] = bf2f(k4[2]); ks[r][cq*4+3] = bf2f(k4[3]);
    }
    #pragma unroll
    for (int p = 0; p < 2; ++p) {
      int qd = tid + p*128; int r = qd >> 4, cq = qd & 15;
      ushort4v v4 = *(const ushort4v*)(vbp + (size_t)(sb*16 + r)*2048 + cq*4);
      vs[r][cq*4+0] = bf2f(v4[0]); vs[r][cq*4+1] = bf2f(v4[1]);
      vs[r][cq*4+2] = bf2f(v4[2]); vs[r][cq*4+3] = bf2f(v4[3]);
    }
    if (tid < 16) wsg[tid] = expf(gbp[sb*16 + tid] - Gend);
    __syncthreads();
    #pragma unroll
    for (int s = 0; s < 16; ++s) {
      float w = wsg[s];
      float4 kq = *(const float4*)(&ks[s][i0]);
      float wk[4] = { w*kq.x, w*kq.y, w*kq.z, w*kq.w };
      #pragma unroll
      for (int m = 0; m < 2; ++m) {
        float4 vq = *(const float4*)(&vs[s][cg*4 + m*32]);
        #pragma unroll
        for (int u = 0; u < 4; ++u) {
          acc[u][m*4+0] += wk[u]*vq.x;
          acc[u][m*4+1] += wk[u]*vq.y;
          acc[u][m*4+2] += wk[u]*vq.z;
          acc[u][m*4+3] += wk[u]*vq.w;
        }
      }
    }
  }
  float* dst = Dloc + ((size_t)bh*NCH + c) * (NB_DQK*NB_DH) + jh*64;
  #pragma unroll
  for (int u = 0; u < 4; ++u)
    #pragma unroll
    for (int m = 0; m < 2; ++m) {
      float4 o4 = { acc[u][m*4+0], acc[u][m*4+1], acc[u][m*4+2], acc[u][m*4+3] };
      *(float4*)(dst + (size_t)(i0+u)*NB_DH + cg*4 + m*32) = o4;
    }
}

// ---------------- chunked attention via MFMA + inline state combine + LN + gate ----------------
// grid 256 (XCD-swizzled): bh(16) x c(8) x half(2); block = 64 t-rows, 4 waves.
// q/k staged via global_load_lds from pre-split Qh/Ql/Kh/Kl (pre-swizzled source).
__global__ __launch_bounds__(256,1) void chunk_out(
    const unsigned short* __restrict__ Qh, const unsigned short* __restrict__ Ql,
    const unsigned short* __restrict__ Kh, const unsigned short* __restrict__ Kl,
    const unsigned short* __restrict__ Pvx,
    const float* __restrict__ gv, const float* __restrict__ Gv,
    const float* __restrict__ Dloc,
    const float* __restrict__ lnw, const float* __restrict__ lnb,
    unsigned short* __restrict__ hng)
{
  __shared__ __align__(16) char smem[131072];
  __shared__ float gsh[128], Gsh[128], rsh[128];
  constexpr int QHo = 0, QLo = 8192, KHo = 16384, KLo = 32768;
  constexpr int ATT = 49152, VT = 65536, CBH = 98304, CBL = 114688;

  const int bx = ((blockIdx.x & 7) << 5) | (blockIdx.x >> 3);   // 256 = 8*32
  const int half = bx & 1, c = (bx >> 1) & 7, bh = bx >> 4;
  const int b = bh >> 3, h = bh & 7;
  const int tid = threadIdx.x;
  const int wid = tid >> 6, lane = tid & 63;
  const int lrow = lane & 15;
  const int lkB  = (lane >> 4) * 16;
  const size_t rowbase = (size_t)b*NB_S + (size_t)c*CL;
  const int sgbase = bh*NB_S + c*CL;
  const int ldsW = wid * 1024;

  // ---- phase 0a: async q/k staging via global_load_lds (pre-swizzled source) ----
  {
    const int srow8 = tid >> 3;          // 0..31
    const int scb8  = (tid & 7) << 4;    // 0..112 bytes
    const char* QhB = (const char*)Qh;
    const char* QlB = (const char*)Ql;
    const char* KhB = (const char*)Kh;
    const char* KlB = (const char*)Kl;
    #pragma unroll
    for (int i = 0; i < 2; ++i) {
      int r = i*32 + srow8;              // 0..63
      size_t off = (size_t)(rowbase + half*64 + r)*1024 + h*128 + (scb8 ^ ((r & 7) << 4));
      GLD_LDS16(QhB + off, smem + QHo + i*4096 + ldsW);
      GLD_LDS16(QlB + off, smem + QLo + i*4096 + ldsW);
    }
    #pragma unroll
    for (int i = 0; i < 4; ++i) {
      int r = i*32 + srow8;              // 0..127
      size_t off = (size_t)(rowbase + r)*1024 + h*128 + (scb8 ^ ((r & 7) << 4));
      GLD_LDS16(KhB + off, smem + KHo + i*4096 + ldsW);
      GLD_LDS16(KlB + off, smem + KLo + i*4096 + ldsW);
    }
  }

  if (tid < 128) {
    float gval = gv[sgbase + tid];
    float Gval = Gv[sgbase + tid];
    gsh[tid] = gval; Gsh[tid] = Gval;
    float Gprev = (c > 0) ? Gv[sgbase - 1] : 0.f;
    rsh[tid] = 0.125f * expf(Gprev - Gval);
  }

  // ---- phase 0b: V^T re-layout (bf16) ----
  #pragma unroll
  for (int p = 0; p < 8; ++p) {
    int lin = p*256 + tid;
    int s = lin >> 4, j0 = (lin & 15) * 8;
    ushort8v v8 = *(const ushort8v*)(Pvx + (rowbase + s)*2048 + h*NB_DH + j0);
    #pragma unroll
    for (int j = 0; j < 8; ++j) {
      int jj = j0 + j;
      int off = (jj*256 + s*2) ^ ((jj & 7) << 4);
      *(unsigned short*)(smem + VT + off) = v8[j];
    }
  }
  // ---- phase 0c: Cb^T hi/lo via closed-form weighted sum of Dloc ----
  {
    float4 cbacc[8];
    #pragma unroll
    for (int p = 0; p < 8; ++p) cbacc[p] = float4{0.f,0.f,0.f,0.f};
    const float Gcm1 = (c > 0) ? Gv[sgbase - 1] : 0.f;
    for (int cp = 0; cp < c; ++cp) {
      float wgt = expf(Gv[bh*NB_S + cp*CL + CL - 1] - Gcm1);
      const float4* dl4 = (const float4*)(Dloc + ((size_t)bh*NCH + cp)*8192);
      #pragma unroll
      for (int p = 0; p < 8; ++p) {
        float4 d = dl4[p*256 + tid];
        cbacc[p].x += wgt*d.x; cbacc[p].y += wgt*d.y;
        cbacc[p].z += wgt*d.z; cbacc[p].w += wgt*d.w;
      }
    }
    #pragma unroll
    for (int p = 0; p < 8; ++p) {
      int lin = p*256 + tid;
      int i = lin >> 5, j0 = (lin & 31) * 4;
      float vv[4] = { cbacc[p].x, cbacc[p].y, cbacc[p].z, cbacc[p].w };
      #pragma unroll
      for (int w = 0; w < 4; ++w) {
        int jj = j0 + w;
        int off = (jj*128 + i*2) ^ ((jj & 7) << 4);
        unsigned short hh = f2bf(vv[w]);
        *(unsigned short*)(smem + CBH + off) = hh;
        *(unsigned short*)(smem + CBL + off) = f2bf(vv[w] - bf2f(hh));
      }
    }
  }
  __syncthreads();   // also drains the global_load_lds queue

  const f32x4 z4 = { 0.f, 0.f, 0.f, 0.f };
  const int trow = wid*16 + lrow;

  // ---- phase 1a: S = q k^T (split-bf16), weight+mask -> att (bf16) ----
  f32x4 sacc[8];
  #pragma unroll
  for (int n = 0; n < 8; ++n) sacc[n] = z4;
  #pragma unroll
  for (int kk = 0; kk < 2; ++kk) {
    int qb = kk*64 + lkB;
    int ab = (trow*128 + qb) ^ ((trow & 7) << 4);
    short8v aqh = *(const short8v*)(smem + QHo + ab);
    short8v aql = *(const short8v*)(smem + QLo + ab);
    #pragma unroll
    for (int n = 0; n < 8; ++n) {
      int srw = n*16 + lrow;
      int bb = (srw*128 + qb) ^ ((srw & 7) << 4);
      short8v bkh = *(const short8v*)(smem + KHo + bb);
      short8v bkl = *(const short8v*)(smem + KLo + bb);
      sacc[n] = MFMA_BF16(aqh, bkh, sacc[n]);
      sacc[n] = MFMA_BF16(aql, bkh, sacc[n]);
      sacc[n] = MFMA_BF16(aqh, bkl, sacc[n]);
    }
  }
  {
    int td[4]; float gt[4];
    #pragma unroll
    for (int r = 0; r < 4; ++r) {
      td[r] = wid*16 + ((lane >> 4) << 2) + r;
      gt[r] = Gsh[half*64 + td[r]];
    }
    #pragma unroll
    for (int n = 0; n < 8; ++n) {
      int s = n*16 + lrow;
      float gs = gsh[s];
      #pragma unroll
      for (int r = 0; r < 4; ++r) {
        float w = 0.125f * expf(gs - gt[r]);
        float val = (s <= half*64 + td[r]) ? sacc[n][r]*w : 0.f;
        int off = (td[r]*256 + s*2) ^ ((td[r] & 7) << 4);
        *(unsigned short*)(smem + ATT + off) = f2bf(val);
      }
    }
  }

  // ---- phase 1b: state term h2 = q * Cbef (split-bf16) ----
  f32x4 h2[8];
  #pragma unroll
  for (int n = 0; n < 8; ++n) h2[n] = z4;
  #pragma unroll
  for (int kk = 0; kk < 2; ++kk) {
    int qb = kk*64 + lkB;
    int ab = (trow*128 + qb) ^ ((trow & 7) << 4);
    short8v aqh = *(const short8v*)(smem + QHo + ab);
    short8v aql = *(const short8v*)(smem + QLo + ab);
    #pragma unroll
    for (int n = 0; n < 8; ++n) {
      int jrw = n*16 + lrow;
      int bb = (jrw*128 + qb) ^ ((jrw & 7) << 4);
      short8v bch = *(const short8v*)(smem + CBH + bb);
      short8v bcl = *(const short8v*)(smem + CBL + bb);
      h2[n] = MFMA_BF16(aqh, bch, h2[n]);
      h2[n] = MFMA_BF16(aql, bch, h2[n]);
      h2[n] = MFMA_BF16(aqh, bcl, h2[n]);
    }
  }
  __syncthreads();

  // ---- phase 2: PV: h1 = att * V ----
  f32x4 h1[8];
  #pragma unroll
  for (int n = 0; n < 8; ++n) h1[n] = z4;
  #pragma unroll
  for (int kk = 0; kk < 4; ++kk) {
    int ab = (trow*256 + kk*64 + lkB) ^ ((trow & 7) << 4);
    short8v aat = *(const short8v*)(smem + ATT + ab);
    #pragma unroll
    for (int n = 0; n < 8; ++n) {
      int jrw = n*16 + lrow;
      int bb = (jrw*256 + kk*64 + lkB) ^ ((jrw & 7) << 4);
      short8v bvt = *(const short8v*)(smem + VT + bb);
      h1[n] = MFMA_BF16(aat, bvt, h1[n]);
    }
  }
  __syncthreads();

  // ---- phase 3: combine, stage H in LDS, epilogue ----
  float* Hb = (float*)smem;
  {
    #pragma unroll
    for (int r = 0; r < 4; ++r) {
      int tl = wid*16 + ((lane >> 4) << 2) + r;
      float rr = rsh[half*64 + tl];
      #pragma unroll
      for (int n = 0; n < 8; ++n)
        Hb[tl*132 + n*16 + lrow] = h1[n][r] + rr*h2[n][r];
    }
  }
  __syncthreads();

  const int tr = tid >> 4, tc = tid & 15;
  float lw[8], lb[8];
  {
    float4 a0 = *(const float4*)(lnw + h*NB_DH + tc*4);
    float4 a1 = *(const float4*)(lnw + h*NB_DH + tc*4 + 64);
    lw[0]=a0.x; lw[1]=a0.y; lw[2]=a0.z; lw[3]=a0.w;
    lw[4]=a1.x; lw[5]=a1.y; lw[6]=a1.z; lw[7]=a1.w;
    float4 b0 = *(const float4*)(lnb + h*NB_DH + tc*4);
    float4 b1 = *(const float4*)(lnb + h*NB_DH + tc*4 + 64);
    lb[0]=b0.x; lb[1]=b0.y; lb[2]=b0.z; lb[3]=b0.w;
    lb[4]=b1.x; lb[5]=b1.y; lb[6]=b1.z; lb[7]=b1.w;
  }
  #pragma unroll
  for (int u = 0; u < 4; ++u) {
    int tl = tr*4 + u;
    int t  = half*64 + tl;
    float hrow[8];
    float4 hl0 = *(const float4*)(&Hb[tl*132 + tc*4]);
    float4 hl1 = *(const float4*)(&Hb[tl*132 + tc*4 + 64]);
    hrow[0]=hl0.x; hrow[1]=hl0.y; hrow[2]=hl0.z; hrow[3]=hl0.w;
    hrow[4]=hl1.x; hrow[5]=hl1.y; hrow[6]=hl1.z; hrow[7]=hl1.w;
    float sum = 0.f, ssq = 0.f;
    #pragma unroll
    for (int x = 0; x < 8; ++x) { sum += hrow[x]; ssq += hrow[x]*hrow[x]; }
    #pragma unroll
    for (int off = 1; off < 16; off <<= 1) {
      sum += __shfl_xor(sum, off);
      ssq += __shfl_xor(ssq, off);
    }
    float mean = sum * (1.f/NB_DH);
    float var  = ssq * (1.f/NB_DH) - mean*mean;
    float rstd = rsqrtf(var + 1e-6f);
    #pragma unroll
    for (int m = 0; m < 2; ++m) {
      ushort4v xo4 = *(const ushort4v*)(Pvx + (rowbase + t)*2048 + 1024 + h*NB_DH + tc*4 + m*64);
      float xov[4] = { bf2f(xo4[0]), bf2f(xo4[1]), bf2f(xo4[2]), bf2f(xo4[3]) };
      unsigned short res[4];
      #pragma unroll
      for (int w = 0; w < 4; ++w) {
        int x = m*4 + w;
        float hn = (hrow[x] - mean)*rstd*lw[x] + lb[x];
        float tt = tanhf(xov[w]*(1.f/15.f))*15.f;
        float o = 1.f/(1.f + expf(-tt));
        res[w] = f2bf(hn*o);
      }
      ushort4v r4 = { res[0], res[1], res[2], res[3] };
      *(ushort4v*)(hng + (rowbase + t)*1024 + h*NB_DH + tc*4 + m*64) = r4;
    }
  }
}

extern "C" void kernel_launch(void* const* d_in, const int* in_sizes, int n_in,
                              void* d_out, int out_size, void* d_ws, size_t ws_size,
                              hipStream_t stream)
{
  (void)in_sizes; (void)n_in; (void)out_size; (void)ws_size;
  const float* x   = (const float*)d_in[0];
  const float* Wq  = (const float*)d_in[1];
  const float* Wk  = (const float*)d_in[2];
  const float* Wv  = (const float*)d_in[3];
  const float* Wi  = (const float*)d_in[4];
  const float* bi  = (const float*)d_in[5];
  const float* Wf  = (const float*)d_in[6];
  const float* bf  = (const float*)d_in[7];
  const float* Wog = (const float*)d_in[8];
  const float* lnw = (const float*)d_in[9];
  const float* lnb = (const float*)d_in[10];
  const float* Wout= (const float*)d_in[11];
  float* out = (float*)d_out;
  float* ws  = (float*)d_ws;

  unsigned short* Qh  = (unsigned short*)(ws + OFF_QH);
  unsigned short* Ql  = (unsigned short*)(ws + OFF_QL);
  unsigned short* Kh  = (unsigned short*)(ws + OFF_KH);
  unsigned short* Kl  = (unsigned short*)(ws + OFF_KL);
  unsigned short* Pvx = (unsigned short*)(ws + OFF_PVX);
  unsigned short* xh  = (unsigned short*)(ws + OFF_XH);
  unsigned short* xl  = (unsigned short*)(ws + OFF_XL);
  unsigned short* Whi = (unsigned short*)(ws + OFF_WHI);
  unsigned short* Wlo = (unsigned short*)(ws + OFF_WLO);
  unsigned short* WtO = (unsigned short*)(ws + OFF_WTO);
  float*          iv  = ws + OFF_IV;
  float*          fv  = ws + OFF_FV;
  float*          g   = ws + OFF_G;
  float*          G   = ws + OFF_GM;
  float*          Dl  = ws + OFF_DL;
  unsigned short* hng = (unsigned short*)(ws + OFF_HNG);

  prep     <<<1536, 256, 0, stream>>>(x, Wi, bi, Wf, bf, Wq, Wk, Wv, Wog, Wout,
                                      xh, xl, iv, fv, Whi, Wlo, WtO);

  // gate_scan (blocks 0..15, retire early) + GEMM (blocks 16..527)
  gemm_proj<<<528, 256, 0, stream>>>(xh, xl, Whi, Wlo, Qh, Ql, Kh, Kl, Pvx,
                                     iv, fv, g, G);

  chunk_local<<<256, 128, 0, stream>>>(Kh, Pvx, g, G, Dl);
  chunk_out  <<<256, 256, 0, stream>>>(Qh, Ql, Kh, Kl, Pvx, g, G, Dl, lnw, lnb, hng);

  gemm_out64 <<<256, 256, 0, stream>>>(hng, WtO, out, 1024);
}